// Round 5
// baseline (574.249 us; speedup 1.0000x reference)
//
#include <hip/hip_runtime.h>
#include <cstdint>

#define LYR 2
#define DM  256
#define DFFN 1024
#define CINC 512
#define BBATCH 8
#define HWTOT 4096
#define EPSV 1e-5f

using u16 = unsigned short;
typedef __attribute__((ext_vector_type(8))) short bf16x8;
typedef __attribute__((ext_vector_type(4))) float f32x4;

__device__ inline u16 f2b(float v) {
    union { float f; uint32_t u; } x; x.f = v;
    uint32_t r = x.u + 0x7fffu + ((x.u >> 16) & 1u);
    return (u16)(r >> 16);
}
__device__ inline uint32_t pk2(float a, float b) {
    return (uint32_t)f2b(a) | ((uint32_t)f2b(b) << 16);
}
__device__ inline float blo(uint32_t d) {
    union { uint32_t i; float f; } x; x.i = d << 16; return x.f;
}
__device__ inline float bhi(uint32_t d) {
    union { uint32_t i; float f; } x; x.i = d & 0xffff0000u; return x.f;
}

// ============ bf16 MFMA GEMM: C = A(M,K) @ Bt(N,K)^T, 128x128 tile, BK=32 ============
// Counted-vmcnt pipeline: 4 LDS buffers, 2-group-deep prefetch, raw s_barrier.
// MODE 0: bf16 out, x+shift[col]                   (val)
// MODE 1: bf16 out, relu(x*scale[col]+shift[col])  (proj_in)
// MODE 2: fp32 out, x+shift[col]                   (offattn)
// MODE 3: fp32 out, relu(x*scale[row]+shift[row])  (proj_out)
template<int MODE>
__global__ __launch_bounds__(256) void mfma_gemm(
    const u16* __restrict__ A, const u16* __restrict__ Bt,
    const float* __restrict__ scale, const float* __restrict__ shift,
    void* __restrict__ Cv, int M, int N, int K, int ldc,
    long long a_zs, long long b_zs, long long c_zs, int swz, int gxlog)
{
    __shared__ u16 As[4][4096];
    __shared__ u16 Bs[4][4096];
    const int tid = threadIdx.x;
    const int lane = tid & 63;
    const int wid = tid >> 6;
    const int wm = (wid & 1) << 6, wn = (wid >> 1) << 6;
    const int quad = lane >> 4, r = lane & 15;

    int bx = blockIdx.x, by = blockIdx.y;
    if (swz) {  // XCD-band swizzle: XCD k owns a contiguous band of row-tiles
        int linear = by * gridDim.x + bx;
        int xcd = linear & 7;
        int s = linear >> 3;
        bx = s & (gridDim.x - 1);
        by = xcd * (gridDim.y >> 3) + (s >> gxlog);
    }
    const int m0 = by << 7, n0 = bx << 7;
    const u16* Ab = A + (long long)blockIdx.z * a_zs + (long long)m0 * K;
    const u16* Bb = Bt + (long long)blockIdx.z * b_zs + (long long)n0 * K;

    // staging (BK=32): unit u (16B): row m=u>>2, pos p=u&3, chunk c=p^((m>>1)&3)
    const int u0 = tid, u1 = tid + 256;
    const int mu0 = u0 >> 2, cu0 = (u0 & 3) ^ ((mu0 >> 1) & 3);
    const int mu1 = u1 >> 2, cu1 = (u1 & 3) ^ ((mu1 >> 1) & 3);
    const long long ga0 = (long long)mu0 * K + cu0 * 8;
    const long long ga1 = (long long)mu1 * K + cu1 * 8;

    int aoff[4], boff[4];
#pragma unroll
    for (int t = 0; t < 4; ++t) {
        int m = wm + t * 16 + r;
        aoff[t] = (m * 4 + (quad ^ ((m >> 1) & 3))) * 8;
        int n = wn + t * 16 + r;
        boff[t] = (n * 4 + (quad ^ ((n >> 1) & 3))) * 8;
    }

    f32x4 acc[4][4];
#pragma unroll
    for (int i = 0; i < 4; ++i)
#pragma unroll
        for (int j = 0; j < 4; ++j) acc[i][j] = (f32x4){0.f, 0.f, 0.f, 0.f};

    const int NT = K >> 5;   // >= 3 for all call sites (8 or 16)

#define GSTAGE(g, b) do {                                                                       \
    const long long kk = (long long)(g) << 5;                                                   \
    __builtin_amdgcn_global_load_lds((const __attribute__((address_space(1))) void*)(Ab + ga0 + kk), \
        (__attribute__((address_space(3))) void*)(&As[b][u0 * 8]), 16, 0, 0);                   \
    __builtin_amdgcn_global_load_lds((const __attribute__((address_space(1))) void*)(Ab + ga1 + kk), \
        (__attribute__((address_space(3))) void*)(&As[b][u1 * 8]), 16, 0, 0);                   \
    __builtin_amdgcn_global_load_lds((const __attribute__((address_space(1))) void*)(Bb + ga0 + kk), \
        (__attribute__((address_space(3))) void*)(&Bs[b][u0 * 8]), 16, 0, 0);                   \
    __builtin_amdgcn_global_load_lds((const __attribute__((address_space(1))) void*)(Bb + ga1 + kk), \
        (__attribute__((address_space(3))) void*)(&Bs[b][u1 * 8]), 16, 0, 0);                   \
} while (0)

    // prologue: stage tiles 0,1,2 (12 loads outstanding)
    GSTAGE(0, 0);
    GSTAGE(1, 1);
    GSTAGE(2, 2);

    for (int t = 0; t < NT; ++t) {
        // wait for tile t's group; keep up to 2 future groups (8 loads) in flight
        if (t < NT - 2)       asm volatile("s_waitcnt vmcnt(8)" ::: "memory");
        else if (t == NT - 2) asm volatile("s_waitcnt vmcnt(4)" ::: "memory");
        else                  asm volatile("s_waitcnt vmcnt(0)" ::: "memory");
        __builtin_amdgcn_s_barrier();
        __builtin_amdgcn_sched_barrier(0);   // pin: no motion across the barrier
        if (t + 3 < NT) GSTAGE(t + 3, (t + 3) & 3);
        const u16* Ap = As[t & 3];
        const u16* Bp = Bs[t & 3];
        bf16x8 af[4], bf[4];
#pragma unroll
        for (int tt = 0; tt < 4; ++tt) af[tt] = *(const bf16x8*)(Ap + aoff[tt]);
#pragma unroll
        for (int tt = 0; tt < 4; ++tt) bf[tt] = *(const bf16x8*)(Bp + boff[tt]);
#pragma unroll
        for (int i = 0; i < 4; ++i)
#pragma unroll
            for (int j = 0; j < 4; ++j)
                acc[i][j] = __builtin_amdgcn_mfma_f32_16x16x32_bf16(bf[j], af[i], acc[i][j], 0, 0, 0);
    }
#undef GSTAGE

    const long long zc = (long long)blockIdx.z * c_zs;
    float4 sh4[4], sc4[4];
    if (MODE != 3) {
#pragma unroll
        for (int j = 0; j < 4; ++j) {
            int colb = n0 + wn + j * 16 + quad * 4;
            sh4[j] = *(const float4*)&shift[colb];
            if (MODE == 1) sc4[j] = *(const float4*)&scale[colb];
        }
    }
#pragma unroll
    for (int i = 0; i < 4; ++i) {
        const int row = m0 + wm + i * 16 + r;
        float rsc = 0.f, rsh = 0.f;
        if (MODE == 3) { rsc = scale[row]; rsh = shift[row]; }
#pragma unroll
        for (int j = 0; j < 4; ++j) {
            const int colb = n0 + wn + j * 16 + quad * 4;
            f32x4 v = acc[i][j];
            if (MODE == 0) {
                uint2 o;
                o.x = pk2(v[0] + sh4[j].x, v[1] + sh4[j].y);
                o.y = pk2(v[2] + sh4[j].z, v[3] + sh4[j].w);
                *(uint2*)((u16*)Cv + zc + (long long)row * ldc + colb) = o;
            } else if (MODE == 1) {
                uint2 o;
                o.x = pk2(fmaxf(v[0] * sc4[j].x + sh4[j].x, 0.f), fmaxf(v[1] * sc4[j].y + sh4[j].y, 0.f));
                o.y = pk2(fmaxf(v[2] * sc4[j].z + sh4[j].z, 0.f), fmaxf(v[3] * sc4[j].w + sh4[j].w, 0.f));
                *(uint2*)((u16*)Cv + zc + (long long)row * ldc + colb) = o;
            } else if (MODE == 2) {
                float4 o = {v[0] + sh4[j].x, v[1] + sh4[j].y, v[2] + sh4[j].z, v[3] + sh4[j].w};
                *(float4*)((float*)Cv + zc + (long long)row * ldc + colb) = o;
            } else {
                float4 o = {fmaxf(v[0] * rsc + rsh, 0.f), fmaxf(v[1] * rsc + rsh, 0.f),
                            fmaxf(v[2] * rsc + rsh, 0.f), fmaxf(v[3] * rsc + rsh, 0.f)};
                *(float4*)((float*)Cv + zc + (long long)row * ldc + colb) = o;
            }
        }
    }
}

// ============ Fused deform-sample + Wo GEMM + bias + residual + LN1 ============
// Block = 64 queries, 512 threads. Sampling: thread = (query qi=tid>>3, head h=tid&7),
// computes the 32-dim sampled output for its head (identical FP order to the old
// sample_kernel) and writes it DIRECTLY into LDS in MFMA A-fragment layout (head = k-slice).
// h-XOR swizzle on the chunk bits avoids 8-way write conflicts; consumer mirrors it with
// a compile-time (ks&3) XOR. Then a barrier-free K=256 MFMA loop + residual-LN epilogue.
__global__ __launch_bounds__(512) void attn_out_ln(
    const u16* __restrict__ val,      // (B*HW, 256) bf16
    const float* __restrict__ oa,     // (B*HW, 128): [0..63]=off, [64..95]=attn logits
    const u16* __restrict__ Bf,       // Wo fragments
    const float* __restrict__ bias,
    float* __restrict__ q, u16* __restrict__ q16,
    const float* __restrict__ g, const float* __restrict__ beta)
{
    __shared__ u16 Aq[16384];
    __shared__ float red_s[8][64], red_ss[8][64];
    const int tid = threadIdx.x;
    const int lane = tid & 63;
    const int w = tid >> 6;
    const int quad = lane >> 4, r = lane & 15;
    const int m0 = blockIdx.x << 6;

    // ======== sampling phase ========
    {
        const int qi = tid >> 3, h = tid & 7;
        const int bq = m0 + qi;
        const int b = m0 >> 12;
        const float* row = oa + (size_t)bq * 128;
        float4 o01 = *(const float4*)(row + h * 8);
        float4 o23 = *(const float4*)(row + h * 8 + 4);
        float4 lg  = *(const float4*)(row + 64 + h * 4);
        float mx = fmaxf(fmaxf(lg.x, lg.y), fmaxf(lg.z, lg.w));
        float e0 = __expf(lg.x - mx), e1 = __expf(lg.y - mx);
        float e2 = __expf(lg.z - mx), e3 = __expf(lg.w - mx);
        float inv = 1.0f / (e0 + e1 + e2 + e3);
        const float aw[4] = {e0 * inv, e1 * inv, e2 * inv, e3 * inv};
        const float offx[4] = {o01.x, o01.z, o23.x, o23.z};
        const float offy[4] = {o01.y, o01.w, o23.y, o23.w};
        const float fx = (float)(bq & 63), fy = (float)((bq >> 6) & 63);
        const u16* vb = val + ((size_t)b << 20) + h * 32;
        float a[32];
#pragma unroll
        for (int d = 0; d < 32; ++d) a[d] = 0.f;
#pragma unroll
        for (int p = 0; p < 4; ++p) {
            float gx = fx + offx[p], gy = fy + offy[p];
            float x0f = floorf(gx), y0f = floorf(gy);
            float wx = gx - x0f, wy = gy - y0f;
            int x0 = (int)x0f, y0 = (int)y0f;
#pragma unroll
            for (int c = 0; c < 4; ++c) {
                int xi = x0 + (c & 1), yi = y0 + (c >> 1);
                bool ok = (xi >= 0) && (xi < 64) && (yi >= 0) && (yi < 64);
                float wgt = ((c & 1) ? wx : 1.0f - wx) * ((c >> 1) ? wy : 1.0f - wy);
                wgt = ok ? aw[p] * wgt : 0.f;
                int eo = ok ? ((yi * 64 + xi) << 8) : 0;
                const uint4* s4 = (const uint4*)(vb + eo);
#pragma unroll
                for (int d4 = 0; d4 < 4; ++d4) {
                    uint4 v = s4[d4];
                    a[d4 * 8 + 0] += wgt * blo(v.x); a[d4 * 8 + 1] += wgt * bhi(v.x);
                    a[d4 * 8 + 2] += wgt * blo(v.y); a[d4 * 8 + 3] += wgt * bhi(v.y);
                    a[d4 * 8 + 4] += wgt * blo(v.z); a[d4 * 8 + 5] += wgt * bhi(v.z);
                    a[d4 * 8 + 6] += wgt * blo(v.w); a[d4 * 8 + 7] += wgt * bhi(v.w);
                }
            }
        }
        const int sw = (qi >> 1) & 3;
        const int hx = (h & 3) << 3;      // XOR on u16 offset chunk bits [3:4]
        u16* dst = Aq + h * 2048;
#pragma unroll
        for (int qd = 0; qd < 4; ++qd) {
            uint4 o4;
            o4.x = pk2(a[qd * 8 + 0], a[qd * 8 + 1]);
            o4.y = pk2(a[qd * 8 + 2], a[qd * 8 + 3]);
            o4.z = pk2(a[qd * 8 + 4], a[qd * 8 + 5]);
            o4.w = pk2(a[qd * 8 + 6], a[qd * 8 + 7]);
            *(uint4*)(dst + (((qi * 4 + (qd ^ sw)) * 8) ^ hx)) = o4;
        }
    }
    __syncthreads();

    // ======== GEMM: Aq(64x256) @ Wo^T, K fully in LDS, no barriers ========
    int aoff0[4];
#pragma unroll
    for (int t = 0; t < 4; ++t) {
        int m = t * 16 + r;
        aoff0[t] = (m * 4 + (quad ^ ((m >> 1) & 3))) * 8;
    }
    const u16* Bw = Bf + ((size_t)(2 * w) * 64 + lane) * 8;
    f32x4 acc[4][2];
#pragma unroll
    for (int i = 0; i < 4; ++i)
#pragma unroll
        for (int j = 0; j < 2; ++j) acc[i][j] = (f32x4){0.f, 0.f, 0.f, 0.f};

#pragma unroll
    for (int ks = 0; ks < 8; ++ks) {
        const u16* bp = Bw + (size_t)ks * 8192;
        bf16x8 bf0 = *(const bf16x8*)bp;
        bf16x8 bf1 = *(const bf16x8*)(bp + 512);
        const int kx = (ks & 3) << 3;
        bf16x8 af[4];
#pragma unroll
        for (int t = 0; t < 4; ++t)
            af[t] = *(const bf16x8*)(Aq + ks * 2048 + (aoff0[t] ^ kx));
#pragma unroll
        for (int i = 0; i < 4; ++i) {
            acc[i][0] = __builtin_amdgcn_mfma_f32_16x16x32_bf16(bf0, af[i], acc[i][0], 0, 0, 0);
            acc[i][1] = __builtin_amdgcn_mfma_f32_16x16x32_bf16(bf1, af[i], acc[i][1], 0, 0, 0);
        }
    }

    // ======== epilogue: bias + residual + LN ========
    float4 sh2[2];
#pragma unroll
    for (int j = 0; j < 2; ++j)
        sh2[j] = *(const float4*)&bias[w * 32 + j * 16 + quad * 4];

    float s_[4] = {0.f, 0.f, 0.f, 0.f}, ss_[4] = {0.f, 0.f, 0.f, 0.f};
#pragma unroll
    for (int i = 0; i < 4; ++i) {
        const int row = m0 + i * 16 + r;
#pragma unroll
        for (int j = 0; j < 2; ++j) {
            const int colb = w * 32 + j * 16 + quad * 4;
            float4 qo = *(const float4*)&q[(size_t)row * DM + colb];
            acc[i][j][0] += sh2[j].x + qo.x;
            acc[i][j][1] += sh2[j].y + qo.y;
            acc[i][j][2] += sh2[j].z + qo.z;
            acc[i][j][3] += sh2[j].w + qo.w;
#pragma unroll
            for (int e = 0; e < 4; ++e) {
                s_[i] += acc[i][j][e];
                ss_[i] += acc[i][j][e] * acc[i][j][e];
            }
        }
    }
#pragma unroll
    for (int i = 0; i < 4; ++i) {
        s_[i] += __shfl_xor(s_[i], 16);  ss_[i] += __shfl_xor(ss_[i], 16);
        s_[i] += __shfl_xor(s_[i], 32);  ss_[i] += __shfl_xor(ss_[i], 32);
    }
    if (quad == 0) {
#pragma unroll
        for (int i = 0; i < 4; ++i) {
            red_s[w][i * 16 + r] = s_[i];
            red_ss[w][i * 16 + r] = ss_[i];
        }
    }
    __syncthreads();

    float mean[4], rstd[4];
#pragma unroll
    for (int i = 0; i < 4; ++i) {
        float S = 0.f, SS = 0.f;
#pragma unroll
        for (int w2 = 0; w2 < 8; ++w2) { S += red_s[w2][i * 16 + r]; SS += red_ss[w2][i * 16 + r]; }
        mean[i] = S * (1.0f / 256.0f);
        rstd[i] = rsqrtf(SS * (1.0f / 256.0f) - mean[i] * mean[i] + EPSV);
    }

    float4 g4[2], bt4[2];
#pragma unroll
    for (int j = 0; j < 2; ++j) {
        int colb = w * 32 + j * 16 + quad * 4;
        g4[j] = *(const float4*)&g[colb];
        bt4[j] = *(const float4*)&beta[colb];
    }
#pragma unroll
    for (int i = 0; i < 4; ++i) {
        const int row = m0 + i * 16 + r;
#pragma unroll
        for (int j = 0; j < 2; ++j) {
            const int colb = w * 32 + j * 16 + quad * 4;
            float o0 = (acc[i][j][0] - mean[i]) * rstd[i] * g4[j].x + bt4[j].x;
            float o1 = (acc[i][j][1] - mean[i]) * rstd[i] * g4[j].y + bt4[j].y;
            float o2 = (acc[i][j][2] - mean[i]) * rstd[i] * g4[j].z + bt4[j].z;
            float o3 = (acc[i][j][3] - mean[i]) * rstd[i] * g4[j].w + bt4[j].w;
            *(float4*)&q[(size_t)row * DM + colb] = make_float4(o0, o1, o2, o3);
            *(uint2*)(q16 + (size_t)row * DM + colb) = make_uint2(pk2(o0, o1), pk2(o2, o3));
        }
    }
}

// ============ Fused FFN: q = LN2(q + relu(q16@W1+b1)@W2 + b2) ============
// Block = 64 rows, 512 threads (8 waves). 8 chunks of 128 H-cols; hF = 16 KB single
// buffer -> LDS 52 KB -> 3 blocks/CU. Raw barriers (lgkm-only drain) keep w1F/w2F
// global loads in flight; phase1(c+1) shares a barrier epoch with phase2(c).
// Accumulation order over global ks2 unchanged -> bit-identical results.
__global__ __launch_bounds__(512, 6) void ffn_fused(
    const u16* __restrict__ q16in, const u16* __restrict__ w1F, const u16* __restrict__ w2F,
    const float* __restrict__ b1, const float* __restrict__ b2,
    float* __restrict__ q, u16* __restrict__ q16,
    const float* __restrict__ g, const float* __restrict__ beta)
{
    __shared__ u16 Aq[16384];                 // 64 rows x K=256 (swizzled chunks)
    __shared__ u16 hF[8192];                  // one 64x128 H chunk in A-frag layout
    __shared__ float red_s[8][64], red_ss[8][64];
    const int tid = threadIdx.x;
    const int lane = tid & 63;
    const int w = tid >> 6;
    const int quad = lane >> 4, r = lane & 15;
    const int m0 = blockIdx.x << 6;

    // stage entire A (64x256 q16) once: 2048 16B units, 4 per thread
    const u16* Ab = q16in + (long long)m0 * DM;
#pragma unroll
    for (int i = 0; i < 4; ++i) {
        int u = tid + i * 512;
        int ks = u >> 8, v = u & 255;
        int m = v >> 2, c = (v & 3) ^ ((m >> 1) & 3);
        __builtin_amdgcn_global_load_lds((const __attribute__((address_space(1))) void*)(Ab + (long long)m * DM + ks * 32 + c * 8),
                                         (__attribute__((address_space(3))) void*)(Aq + u * 8), 16, 0, 0);
    }

    int aoff[4];
#pragma unroll
    for (int t = 0; t < 4; ++t) {
        int m = t * 16 + r;
        aoff[t] = (m * 4 + (quad ^ ((m >> 1) & 3))) * 8;
    }

    // pack destination: X = 4w+quad selects (ksl, quad', eo) within the chunk
    const int X = 4 * w + quad;
    const int packbase = (X >> 3) * 2048 + ((X & 7) >> 1) * 128 + r * 8 + (X & 1) * 4;

    f32x4 acc2[4][2];
#pragma unroll
    for (int i = 0; i < 4; ++i)
#pragma unroll
        for (int j = 0; j < 2; ++j) acc2[i][j] = (f32x4){0.f, 0.f, 0.f, 0.f};

    __syncthreads();

    for (int cch = 0; cch < 8; ++cch) {
        // ---- phase 1: H cols [cch*128 + w*16, +16) = A @ W1 (registers)
        f32x4 acc1[4];
#pragma unroll
        for (int i = 0; i < 4; ++i) acc1[i] = (f32x4){0.f, 0.f, 0.f, 0.f};
        __builtin_amdgcn_s_setprio(1);
#pragma unroll
        for (int ks = 0; ks < 8; ++ks) {
            const u16* bp = w1F + ((size_t)(ks * 64 + cch * 8 + w) * 64 + lane) * 8;
            bf16x8 bf = *(const bf16x8*)bp;
            bf16x8 af[4];
#pragma unroll
            for (int t = 0; t < 4; ++t) af[t] = *(const bf16x8*)(Aq + ks * 2048 + aoff[t]);
#pragma unroll
            for (int i = 0; i < 4; ++i)
                acc1[i] = __builtin_amdgcn_mfma_f32_16x16x32_bf16(bf, af[i], acc1[i], 0, 0, 0);
        }
        __builtin_amdgcn_s_setprio(0);
        __builtin_amdgcn_sched_barrier(0);
        __builtin_amdgcn_s_barrier();          // prev phase2's hF reads complete

        // pack: bias + relu + bf16 into hF
        {
            const int cb = cch * 128 + w * 16 + quad * 4;
            const float4 b14 = *(const float4*)&b1[cb];
#pragma unroll
            for (int i = 0; i < 4; ++i) {
                f32x4 v = acc1[i];
                uint2 o;
                o.x = pk2(fmaxf(v[0] + b14.x, 0.f), fmaxf(v[1] + b14.y, 0.f));
                o.y = pk2(fmaxf(v[2] + b14.z, 0.f), fmaxf(v[3] + b14.w, 0.f));
                *(uint2*)(hF + packbase + i * 512) = o;
            }
        }
        asm volatile("s_waitcnt lgkmcnt(0)" ::: "memory");
        __builtin_amdgcn_s_barrier();          // hF chunk complete
        __builtin_amdgcn_sched_barrier(0);

        // ---- phase 2: acc2 += H_chunk @ W2[cch*128 .. +128, :]
        __builtin_amdgcn_s_setprio(1);
#pragma unroll
        for (int ks = 0; ks < 4; ++ks) {
            const u16* bp = w2F + ((size_t)((cch * 4 + ks) * 16 + w * 2) * 64 + lane) * 8;
            bf16x8 bf0 = *(const bf16x8*)bp;
            bf16x8 bf1 = *(const bf16x8*)(bp + 512);
            bf16x8 af[4];
#pragma unroll
            for (int t = 0; t < 4; ++t) af[t] = *(const bf16x8*)(hF + ((ks * 4 + t) * 64 + lane) * 8);
#pragma unroll
            for (int i = 0; i < 4; ++i) {
                acc2[i][0] = __builtin_amdgcn_mfma_f32_16x16x32_bf16(bf0, af[i], acc2[i][0], 0, 0, 0);
                acc2[i][1] = __builtin_amdgcn_mfma_f32_16x16x32_bf16(bf1, af[i], acc2[i][1], 0, 0, 0);
            }
        }
        __builtin_amdgcn_s_setprio(0);
    }

    // epilogue: bias b2 + residual + LN2, write q (fp32) and q16
    float4 sh2[2];
#pragma unroll
    for (int j = 0; j < 2; ++j)
        sh2[j] = *(const float4*)&b2[w * 32 + j * 16 + quad * 4];

    float s_[4] = {0.f, 0.f, 0.f, 0.f}, ss_[4] = {0.f, 0.f, 0.f, 0.f};
#pragma unroll
    for (int i = 0; i < 4; ++i) {
        const int row = m0 + i * 16 + r;
#pragma unroll
        for (int j = 0; j < 2; ++j) {
            const int colb = w * 32 + j * 16 + quad * 4;
            float4 qo = *(const float4*)&q[(size_t)row * DM + colb];
            acc2[i][j][0] += sh2[j].x + qo.x;
            acc2[i][j][1] += sh2[j].y + qo.y;
            acc2[i][j][2] += sh2[j].z + qo.z;
            acc2[i][j][3] += sh2[j].w + qo.w;
#pragma unroll
            for (int e = 0; e < 4; ++e) {
                s_[i] += acc2[i][j][e];
                ss_[i] += acc2[i][j][e] * acc2[i][j][e];
            }
        }
    }
#pragma unroll
    for (int i = 0; i < 4; ++i) {
        s_[i] += __shfl_xor(s_[i], 16);  ss_[i] += __shfl_xor(ss_[i], 16);
        s_[i] += __shfl_xor(s_[i], 32);  ss_[i] += __shfl_xor(ss_[i], 32);
    }
    if (quad == 0) {
#pragma unroll
        for (int i = 0; i < 4; ++i) {
            red_s[w][i * 16 + r] = s_[i];
            red_ss[w][i * 16 + r] = ss_[i];
        }
    }
    __syncthreads();

    float mean[4], rstd[4];
#pragma unroll
    for (int i = 0; i < 4; ++i) {
        float S = 0.f, SS = 0.f;
#pragma unroll
        for (int w2 = 0; w2 < 8; ++w2) { S += red_s[w2][i * 16 + r]; SS += red_ss[w2][i * 16 + r]; }
        mean[i] = S * (1.0f / 256.0f);
        rstd[i] = rsqrtf(SS * (1.0f / 256.0f) - mean[i] * mean[i] + EPSV);
    }

    float4 g4[2], bt4[2];
#pragma unroll
    for (int j = 0; j < 2; ++j) {
        int colb = w * 32 + j * 16 + quad * 4;
        g4[j] = *(const float4*)&g[colb];
        bt4[j] = *(const float4*)&beta[colb];
    }
#pragma unroll
    for (int i = 0; i < 4; ++i) {
        const int row = m0 + i * 16 + r;
#pragma unroll
        for (int j = 0; j < 2; ++j) {
            const int colb = w * 32 + j * 16 + quad * 4;
            float o0 = (acc2[i][j][0] - mean[i]) * rstd[i] * g4[j].x + bt4[j].x;
            float o1 = (acc2[i][j][1] - mean[i]) * rstd[i] * g4[j].y + bt4[j].y;
            float o2 = (acc2[i][j][2] - mean[i]) * rstd[i] * g4[j].z + bt4[j].z;
            float o3 = (acc2[i][j][3] - mean[i]) * rstd[i] * g4[j].w + bt4[j].w;
            *(float4*)&q[(size_t)row * DM + colb] = make_float4(o0, o1, o2, o3);
            *(uint2*)(q16 + (size_t)row * DM + colb) = make_uint2(pk2(o0, o1), pk2(o2, o3));
        }
    }
}

// ================= weight prep =================
__device__ __attribute__((noinline)) void tconv(const float* src, u16* dst, int K, int N, int tk, int tn)
{
    __shared__ float t[32][33];
    const int tx = threadIdx.x & 31, ty = threadIdx.x >> 5;
#pragma unroll
    for (int i = 0; i < 4; ++i)
        t[ty + i * 8][tx] = src[(size_t)(tk * 32 + ty + i * 8) * N + tn * 32 + tx];
    __syncthreads();
#pragma unroll
    for (int i = 0; i < 4; ++i)
        dst[(size_t)(tn * 32 + ty + i * 8) * K + tk * 32 + tx] = f2b(t[tx][ty + i * 8]);
}

__device__ __attribute__((noinline)) void tconv_oa(const float* Woff, const float* Wattn, u16* dst, int tk, int tn)
{
    __shared__ float t[32][33];
    const int tx = threadIdx.x & 31, ty = threadIdx.x >> 5;
#pragma unroll
    for (int i = 0; i < 4; ++i) {
        int k = tk * 32 + ty + i * 8, n = tn * 32 + tx;
        float v = (n < 64) ? Woff[k * 64 + n] : ((n < 96) ? Wattn[k * 32 + n - 64] : 0.f);
        t[ty + i * 8][tx] = v;
    }
    __syncthreads();
#pragma unroll
    for (int i = 0; i < 4; ++i)
        dst[(size_t)(tn * 32 + ty + i * 8) * 256 + tk * 32 + tx] = f2b(t[tx][ty + i * 8]);
}

// W (K,N) fp32 -> fragment-ordered bf16:
// F[ks][nt][lane][e] = W[ks*32 + (lane>>4)*8 + e][nt*16 + (lane&15)]
__device__ __attribute__((noinline)) void frag_prep(const float* W, u16* dst, int ks, int nc, int N)
{
    __shared__ float t[32][256];
    const int tid = threadIdx.x;
#pragma unroll
    for (int kk = 0; kk < 32; ++kk)
        t[kk][tid] = W[(size_t)(ks * 32 + kk) * N + nc * 256 + tid];
    __syncthreads();
    const int NT16 = N >> 4;
#pragma unroll
    for (int i = 0; i < 4; ++i) {
        int idx = tid + i * 256;          // local nt*64 + lane
        int nt = idx >> 6, l = idx & 63;
        int n = nt * 16 + (l & 15);
        int kb = (l >> 4) * 8;
        u16 o[8];
#pragma unroll
        for (int e = 0; e < 8; ++e) o[e] = f2b(t[kb + e][n]);
        *(uint4*)(dst + ((size_t)(ks * NT16 + nc * 16 + nt) * 64 + l) * 8) = *(const uint4*)o;
    }
}

__global__ __launch_bounds__(256) void prep_weights(
    const float* __restrict__ Wval, const float* __restrict__ Wo,
    const float* __restrict__ W1, const float* __restrict__ W2,
    const float* __restrict__ Woff, const float* __restrict__ Wattn,
    const float* __restrict__ boff, const float* __restrict__ battn,
    const float* __restrict__ W_in, const float* __restrict__ W_out,
    const float* __restrict__ bn1g, const float* __restrict__ bn1b,
    const float* __restrict__ bn1m, const float* __restrict__ bn1v,
    const float* __restrict__ bn2g, const float* __restrict__ bn2b,
    const float* __restrict__ bn2m, const float* __restrict__ bn2v,
    u16* __restrict__ wvalT, u16* __restrict__ woF, u16* __restrict__ w1F,
    u16* __restrict__ w2F, u16* __restrict__ woaT,
    u16* __restrict__ winC, u16* __restrict__ woutC,
    float* __restrict__ bn1sc, float* __restrict__ bn1sh,
    float* __restrict__ bn2sc, float* __restrict__ bn2sh, float* __restrict__ boa)
{
    int bid = blockIdx.x;
    if (bid < 128) {                          // Wval transpose: 2 layers x 64
        int l = bid >> 6, r2 = bid & 63;
        tconv(Wval + l * 65536, wvalT + l * 65536, 256, 256, r2 & 7, r2 >> 3);
    } else if (bid < 192) {                   // Woff|Wattn transpose: 2 x 32
        int i2 = bid - 128, l = i2 >> 5, r2 = i2 & 31;
        tconv_oa(Woff + l * 16384, Wattn + l * 8192, woaT + l * 32768, r2 & 7, r2 >> 3);
    } else if (bid < 208) {                   // Wo fragments: 2 x 8 ks
        int i2 = bid - 192;
        frag_prep(Wo + (i2 >> 3) * 65536, woF + (i2 >> 3) * 65536, i2 & 7, 0, 256);
    } else if (bid < 272) {                   // W1 fragments: 2 x (8 ks x 4 nc)
        int i2 = bid - 208, l = i2 >> 5, r2 = i2 & 31;
        frag_prep(W1 + l * 262144, w1F + l * 262144, r2 >> 2, r2 & 3, 1024);
    } else if (bid < 336) {                   // W2 fragments: 2 x 32 ks
        int i2 = bid - 272;
        frag_prep(W2 + (i2 >> 5) * 262144, w2F + (i2 >> 5) * 262144, i2 & 31, 0, 256);
    } else if (bid < 368) {
        int g2 = bid - 336, base = g2 * 4096, t = threadIdx.x;
#pragma unroll
        for (int k = 0; k < 16; ++k) winC[base + k * 256 + t] = f2b(W_in[base + k * 256 + t]);
    } else if (bid < 400) {
        int g2 = bid - 368, base = g2 * 4096, t = threadIdx.x;
#pragma unroll
        for (int k = 0; k < 16; ++k) woutC[base + k * 256 + t] = f2b(W_out[base + k * 256 + t]);
    } else {
        int t = threadIdx.x;
        { float s = bn1g[t] * rsqrtf(bn1v[t] + EPSV); bn1sc[t] = s; bn1sh[t] = bn1b[t] - bn1m[t] * s; }
        for (int c = 0; c < 2; ++c) {
            int i = c * 256 + t;
            float s = bn2g[i] * rsqrtf(bn2v[i] + EPSV);
            bn2sc[i] = s; bn2sh[i] = bn2b[i] - bn2m[i] * s;
        }
        if (t < 128)
            for (int l = 0; l < 2; ++l)
                boa[l * 128 + t] = (t < 64) ? boff[l * 64 + t]
                                 : ((t < 96) ? battn[l * 32 + t - 64] : 0.f);
    }
}

// ================= x (B,C,HW) -> xT (B,HW,C) bf16 =================
__global__ __launch_bounds__(256) void transpose_x(const float* __restrict__ x, u16* __restrict__ xT)
{
    __shared__ float t[64][65];
    const int b = blockIdx.z, p0 = blockIdx.y << 6, c0 = blockIdx.x << 6;
    const int tx = threadIdx.x & 63, ty = threadIdx.x >> 6;
    const float* xb = x + ((size_t)b * CINC + c0) * HWTOT + p0;
#pragma unroll
    for (int i = 0; i < 16; ++i)
        t[ty + i * 4][tx] = xb[(size_t)(ty + i * 4) * HWTOT + tx];
    __syncthreads();
    u16* xo = xT + ((size_t)b * HWTOT + p0) * CINC + c0;
#pragma unroll
    for (int i = 0; i < 16; ++i)
        xo[(size_t)(ty + i * 4) * CINC + tx] = f2b(t[tx][ty + i * 4]);
}

__global__ __launch_bounds__(256) void bcast_q(
    const float4* __restrict__ qe, float4* __restrict__ q, u16* __restrict__ q16)
{
    const int i = blockIdx.x * 256 + threadIdx.x;
    float4 v = qe[i];
    uint2 pk = make_uint2(pk2(v.x, v.y), pk2(v.z, v.w));
#pragma unroll
    for (int b = 0; b < BBATCH; ++b) {
        q[(size_t)b * 262144 + i] = v;
        ((uint2*)q16)[(size_t)b * 262144 + i] = pk;
    }
}

extern "C" void kernel_launch(void* const* d_in, const int* in_sizes, int n_in,
                              void* d_out, int out_size, void* d_ws, size_t ws_size,
                              hipStream_t stream)
{
    (void)in_sizes; (void)n_in; (void)out_size; (void)ws_size;
    const float* x     = (const float*)d_in[0];
    const float* W_in  = (const float*)d_in[1];
    const float* bn1_g = (const float*)d_in[2];
    const float* bn1_b = (const float*)d_in[3];
    const float* bn1_m = (const float*)d_in[4];
    const float* bn1_v = (const float*)d_in[5];
    const float* qe    = (const float*)d_in[6];
    const float* Woff  = (const float*)d_in[7];
    const float* boff  = (const float*)d_in[8];
    const float* Wattn = (const float*)d_in[9];
    const float* battn = (const float*)d_in[10];
    const float* Wval  = (const float*)d_in[11];
    const float* bval  = (const float*)d_in[12];
    const float* Wo    = (const float*)d_in[13];
    const float* bo    = (const float*)d_in[14];
    const float* ln1_g = (const float*)d_in[15];
    const float* ln1_b = (const float*)d_in[16];
    const float* W1    = (const float*)d_in[17];
    const float* b1    = (const float*)d_in[18];
    const float* W2    = (const float*)d_in[19];
    const float* b2    = (const float*)d_in[20];
    const float* ln2_g = (const float*)d_in[21];
    const float* ln2_b = (const float*)d_in[22];
    const float* W_out = (const float*)d_in[23];
    const float* bn2_g = (const float*)d_in[24];
    const float* bn2_b = (const float*)d_in[25];
    const float* bn2_m = (const float*)d_in[26];
    const float* bn2_v = (const float*)d_in[27];
    float* out = (float*)d_out;

    char* w = (char*)d_ws;
    // pool (time-disjoint): xT (33.5MB) | val16+offat (33.5MB)
    char* pool    = w;          w += 67108864;
    float* q      = (float*)w;  w += 33554432;
    u16*  q16     = (u16*)w;    w += 16777216;
    u16*  src16   = (u16*)w;    w += 16777216;
    u16*  wvalT   = (u16*)w;    w += 262144;
    u16*  woF     = (u16*)w;    w += 262144;
    u16*  w1F     = (u16*)w;    w += 1048576;
    u16*  w2F     = (u16*)w;    w += 1048576;
    u16*  woaT    = (u16*)w;    w += 131072;
    u16*  winC    = (u16*)w;    w += 262144;
    u16*  woutC   = (u16*)w;    w += 262144;
    float* bn1sc  = (float*)w;  w += 1024;
    float* bn1sh  = (float*)w;  w += 1024;
    float* bn2sc  = (float*)w;  w += 2048;
    float* bn2sh  = (float*)w;  w += 2048;
    float* boa    = (float*)w;  w += 1024;

    u16*  xT     = (u16*)pool;
    u16*  val16  = (u16*)pool;
    float* offat = (float*)(pool + 16777216);

    prep_weights<<<dim3(401), 256, 0, stream>>>(
        Wval, Wo, W1, W2, Woff, Wattn, boff, battn, W_in, W_out,
        bn1_g, bn1_b, bn1_m, bn1_v, bn2_g, bn2_b, bn2_m, bn2_v,
        wvalT, woF, w1F, w2F, woaT, winC, woutC, bn1sc, bn1sh, bn2sc, bn2sh, boa);
    transpose_x<<<dim3(CINC / 64, HWTOT / 64, BBATCH), 256, 0, stream>>>(x, xT);
    bcast_q<<<dim3(1024), 256, 0, stream>>>((const float4*)qe, (float4*)q, q16);

    // proj_in: (32768,512)@(256,512)^T -> bf16 src
    mfma_gemm<1><<<dim3(2, 256, 1), 256, 0, stream>>>(
        xT, winC, bn1sc, bn1sh, src16, 32768, 256, 512, 256, 0, 0, 0, 1, 1);

    for (int l = 0; l < LYR; ++l) {
        mfma_gemm<0><<<dim3(2, 256, 1), 256, 0, stream>>>(
            src16, wvalT + l * 65536, nullptr, bval + l * 256, val16,
            32768, 256, 256, 256, 0, 0, 0, 1, 1);
        mfma_gemm<2><<<dim3(1, 256, 1), 256, 0, stream>>>(
            q16, woaT + l * 32768, nullptr, boa + l * 128, offat,
            32768, 128, 256, 128, 0, 0, 0, 1, 0);
        // sampling + Wo GEMM + bias + residual + LN1 in one kernel (oms never in HBM)
        attn_out_ln<<<dim3(512), 512, 0, stream>>>(
            val16, offat, woF + l * 65536, bo + l * 256, q, q16,
            ln1_g + l * 256, ln1_b + l * 256);
        // FFN1 + FFN2 + bias + residual + LN2, H stays on-chip
        ffn_fused<<<dim3(512), 512, 0, stream>>>(
            q16, w1F + l * 262144, w2F + l * 262144,
            b1 + l * 1024, b2 + l * 256, q, q16,
            ln2_g + l * 256, ln2_b + l * 256);
    }

    // proj_out: per-batch (512,256)@(4096,256)^T -> fp32 out (B,C,HW)
    mfma_gemm<3><<<dim3(32, 4, BBATCH), 256, 0, stream>>>(
        woutC, q16, bn2sc, bn2sh, out, 512, 4096, 256, 4096,
        0, (long long)HWTOT * DM, (long long)CINC * HWTOT, 0, 0);
}

// Round 6
// 504.849 us; speedup vs baseline: 1.1375x; 1.1375x over previous
//
#include <hip/hip_runtime.h>
#include <cstdint>

#define LYR 2
#define DM  256
#define DFFN 1024
#define CINC 512
#define BBATCH 8
#define HWTOT 4096
#define EPSV 1e-5f

using u16 = unsigned short;
typedef __attribute__((ext_vector_type(8))) short bf16x8;
typedef __attribute__((ext_vector_type(4))) float f32x4;

__device__ inline u16 f2b(float v) {
    union { float f; uint32_t u; } x; x.f = v;
    uint32_t r = x.u + 0x7fffu + ((x.u >> 16) & 1u);
    return (u16)(r >> 16);
}
__device__ inline uint32_t pk2(float a, float b) {
    return (uint32_t)f2b(a) | ((uint32_t)f2b(b) << 16);
}
__device__ inline float blo(uint32_t d) {
    union { uint32_t i; float f; } x; x.i = d << 16; return x.f;
}
__device__ inline float bhi(uint32_t d) {
    union { uint32_t i; float f; } x; x.i = d & 0xffff0000u; return x.f;
}

// ============ bf16 MFMA GEMM: C = A(M,K) @ Bt(N,K)^T, 128x128 tile, BK=32 ============
// Counted-vmcnt pipeline: 4 LDS buffers, 2-group-deep prefetch, raw s_barrier.
// MODE 0: bf16 out, x+shift[col]                   (val)
// MODE 1: bf16 out, relu(x*scale[col]+shift[col])  (proj_in)
// MODE 2: fp32 out, x+shift[col]                   (offattn)
// MODE 3: fp32 out, relu(x*scale[row]+shift[row])  (proj_out)
template<int MODE>
__global__ __launch_bounds__(256) void mfma_gemm(
    const u16* __restrict__ A, const u16* __restrict__ Bt,
    const float* __restrict__ scale, const float* __restrict__ shift,
    void* __restrict__ Cv, int M, int N, int K, int ldc,
    long long a_zs, long long b_zs, long long c_zs, int swz, int gxlog)
{
    __shared__ u16 As[4][4096];
    __shared__ u16 Bs[4][4096];
    const int tid = threadIdx.x;
    const int lane = tid & 63;
    const int wid = tid >> 6;
    const int wm = (wid & 1) << 6, wn = (wid >> 1) << 6;
    const int quad = lane >> 4, r = lane & 15;

    int bx = blockIdx.x, by = blockIdx.y;
    if (swz) {  // XCD-band swizzle: XCD k owns a contiguous band of row-tiles
        int linear = by * gridDim.x + bx;
        int xcd = linear & 7;
        int s = linear >> 3;
        bx = s & (gridDim.x - 1);
        by = xcd * (gridDim.y >> 3) + (s >> gxlog);
    }
    const int m0 = by << 7, n0 = bx << 7;
    const u16* Ab = A + (long long)blockIdx.z * a_zs + (long long)m0 * K;
    const u16* Bb = Bt + (long long)blockIdx.z * b_zs + (long long)n0 * K;

    // staging (BK=32): unit u (16B): row m=u>>2, pos p=u&3, chunk c=p^((m>>1)&3)
    const int u0 = tid, u1 = tid + 256;
    const int mu0 = u0 >> 2, cu0 = (u0 & 3) ^ ((mu0 >> 1) & 3);
    const int mu1 = u1 >> 2, cu1 = (u1 & 3) ^ ((mu1 >> 1) & 3);
    const long long ga0 = (long long)mu0 * K + cu0 * 8;
    const long long ga1 = (long long)mu1 * K + cu1 * 8;

    int aoff[4], boff[4];
#pragma unroll
    for (int t = 0; t < 4; ++t) {
        int m = wm + t * 16 + r;
        aoff[t] = (m * 4 + (quad ^ ((m >> 1) & 3))) * 8;
        int n = wn + t * 16 + r;
        boff[t] = (n * 4 + (quad ^ ((n >> 1) & 3))) * 8;
    }

    f32x4 acc[4][4];
#pragma unroll
    for (int i = 0; i < 4; ++i)
#pragma unroll
        for (int j = 0; j < 4; ++j) acc[i][j] = (f32x4){0.f, 0.f, 0.f, 0.f};

    const int NT = K >> 5;   // >= 3 for all call sites (8 or 16)

#define GSTAGE(g, b) do {                                                                       \
    const long long kk = (long long)(g) << 5;                                                   \
    __builtin_amdgcn_global_load_lds((const __attribute__((address_space(1))) void*)(Ab + ga0 + kk), \
        (__attribute__((address_space(3))) void*)(&As[b][u0 * 8]), 16, 0, 0);                   \
    __builtin_amdgcn_global_load_lds((const __attribute__((address_space(1))) void*)(Ab + ga1 + kk), \
        (__attribute__((address_space(3))) void*)(&As[b][u1 * 8]), 16, 0, 0);                   \
    __builtin_amdgcn_global_load_lds((const __attribute__((address_space(1))) void*)(Bb + ga0 + kk), \
        (__attribute__((address_space(3))) void*)(&Bs[b][u0 * 8]), 16, 0, 0);                   \
    __builtin_amdgcn_global_load_lds((const __attribute__((address_space(1))) void*)(Bb + ga1 + kk), \
        (__attribute__((address_space(3))) void*)(&Bs[b][u1 * 8]), 16, 0, 0);                   \
} while (0)

    // prologue: stage tiles 0,1,2 (12 loads outstanding)
    GSTAGE(0, 0);
    GSTAGE(1, 1);
    GSTAGE(2, 2);

    for (int t = 0; t < NT; ++t) {
        // wait for tile t's group; keep up to 2 future groups (8 loads) in flight
        if (t < NT - 2)       asm volatile("s_waitcnt vmcnt(8)" ::: "memory");
        else if (t == NT - 2) asm volatile("s_waitcnt vmcnt(4)" ::: "memory");
        else                  asm volatile("s_waitcnt vmcnt(0)" ::: "memory");
        __builtin_amdgcn_s_barrier();
        __builtin_amdgcn_sched_barrier(0);   // pin: no motion across the barrier
        if (t + 3 < NT) GSTAGE(t + 3, (t + 3) & 3);
        const u16* Ap = As[t & 3];
        const u16* Bp = Bs[t & 3];
        bf16x8 af[4], bf[4];
#pragma unroll
        for (int tt = 0; tt < 4; ++tt) af[tt] = *(const bf16x8*)(Ap + aoff[tt]);
#pragma unroll
        for (int tt = 0; tt < 4; ++tt) bf[tt] = *(const bf16x8*)(Bp + boff[tt]);
#pragma unroll
        for (int i = 0; i < 4; ++i)
#pragma unroll
            for (int j = 0; j < 4; ++j)
                acc[i][j] = __builtin_amdgcn_mfma_f32_16x16x32_bf16(bf[j], af[i], acc[i][j], 0, 0, 0);
    }
#undef GSTAGE

    const long long zc = (long long)blockIdx.z * c_zs;
    float4 sh4[4], sc4[4];
    if (MODE != 3) {
#pragma unroll
        for (int j = 0; j < 4; ++j) {
            int colb = n0 + wn + j * 16 + quad * 4;
            sh4[j] = *(const float4*)&shift[colb];
            if (MODE == 1) sc4[j] = *(const float4*)&scale[colb];
        }
    }
#pragma unroll
    for (int i = 0; i < 4; ++i) {
        const int row = m0 + wm + i * 16 + r;
        float rsc = 0.f, rsh = 0.f;
        if (MODE == 3) { rsc = scale[row]; rsh = shift[row]; }
#pragma unroll
        for (int j = 0; j < 4; ++j) {
            const int colb = n0 + wn + j * 16 + quad * 4;
            f32x4 v = acc[i][j];
            if (MODE == 0) {
                uint2 o;
                o.x = pk2(v[0] + sh4[j].x, v[1] + sh4[j].y);
                o.y = pk2(v[2] + sh4[j].z, v[3] + sh4[j].w);
                *(uint2*)((u16*)Cv + zc + (long long)row * ldc + colb) = o;
            } else if (MODE == 1) {
                uint2 o;
                o.x = pk2(fmaxf(v[0] * sc4[j].x + sh4[j].x, 0.f), fmaxf(v[1] * sc4[j].y + sh4[j].y, 0.f));
                o.y = pk2(fmaxf(v[2] * sc4[j].z + sh4[j].z, 0.f), fmaxf(v[3] * sc4[j].w + sh4[j].w, 0.f));
                *(uint2*)((u16*)Cv + zc + (long long)row * ldc + colb) = o;
            } else if (MODE == 2) {
                float4 o = {v[0] + sh4[j].x, v[1] + sh4[j].y, v[2] + sh4[j].z, v[3] + sh4[j].w};
                *(float4*)((float*)Cv + zc + (long long)row * ldc + colb) = o;
            } else {
                float4 o = {fmaxf(v[0] * rsc + rsh, 0.f), fmaxf(v[1] * rsc + rsh, 0.f),
                            fmaxf(v[2] * rsc + rsh, 0.f), fmaxf(v[3] * rsc + rsh, 0.f)};
                *(float4*)((float*)Cv + zc + (long long)row * ldc + colb) = o;
            }
        }
    }
}

// ============ GEMM (64 rows x full N=256) + bias + residual + LayerNorm fused ============
// 512 threads (8 waves), wave owns a 32-col slice. B direct from global in MFMA-frag
// order; A-tile via 3-buffer counted-vmcnt pipeline (stager region = exactly 3 VMEM
// ops: 1 LDS-DMA + 2 B-frag b128 -> uniform vmcnt(3) waits the current tile's DMA
// while next DMA + next B-frags stay in flight across the raw barrier).
// Bf layout: F[ks][nt][lane] of 8 bf16, F = Bt[nt*16 + (lane&15)][ks*32 + (lane>>4)*8 + e]
__global__ __launch_bounds__(512, 4) void mfma_gemm_ln(
    const u16* __restrict__ A, const u16* __restrict__ Bf,
    const float* __restrict__ bias,
    float* __restrict__ q, u16* __restrict__ q16,
    const float* __restrict__ g, const float* __restrict__ beta, int K)
{
    __shared__ u16 As[3][2048];               // 3-buffered 64x32 A tile
    __shared__ float red_s[8][64], red_ss[8][64];
    const int tid = threadIdx.x;
    const int lane = tid & 63;
    const int w = tid >> 6;                   // 8 waves, wave w -> cols [32w, 32w+32)
    const int quad = lane >> 4, r = lane & 15;
    const int m0 = blockIdx.x << 6;
    const u16* Ab = A + (long long)m0 * K;

    // A staging: 256 x 16B units, threads 0..255 stage one each (swizzled chunks)
    const int mA = tid >> 2, cA = (tid & 3) ^ ((mA >> 1) & 3);
    const long long gaA = (long long)mA * K + cA * 8;
    const bool stager = tid < 256;

    int aoff[4];
#pragma unroll
    for (int t = 0; t < 4; ++t) {
        int m = t * 16 + r;
        aoff[t] = (m * 4 + (quad ^ ((m >> 1) & 3))) * 8;
    }

    // B fragment base: tiles nt0 = 2w, nt1 = 2w+1; per-ks stride = 16*64*8 = 8192 u16
    const u16* Bw = Bf + ((size_t)(2 * w) * 64 + lane) * 8;

    f32x4 acc[4][2];
#pragma unroll
    for (int i = 0; i < 4; ++i)
#pragma unroll
        for (int j = 0; j < 2; ++j) acc[i][j] = (f32x4){0.f, 0.f, 0.f, 0.f};

    const int NT = K >> 5;   // 8 or 32

    // prologue: DMAs for tiles 0,1 FIRST (order pinned vs bc loads by sched_barrier)
    if (stager) {
        __builtin_amdgcn_global_load_lds((const __attribute__((address_space(1))) void*)(Ab + gaA),
                                         (__attribute__((address_space(3))) void*)(&As[0][tid * 8]), 16, 0, 0);
        __builtin_amdgcn_global_load_lds((const __attribute__((address_space(1))) void*)(Ab + gaA + 32),
                                         (__attribute__((address_space(3))) void*)(&As[1][tid * 8]), 16, 0, 0);
    }
    __builtin_amdgcn_sched_barrier(0);
    bf16x8 bc0 = *(const bf16x8*)(Bw);
    bf16x8 bc1 = *(const bf16x8*)(Bw + 512);

    int cb = 0;                               // buffer holding tile t
    for (int t = 0; t < NT; ++t) {
        asm volatile("s_waitcnt vmcnt(3)" ::: "memory");
        __builtin_amdgcn_s_barrier();
        __builtin_amdgcn_sched_barrier(0);
        int nb = cb + 2; if (nb >= 3) nb -= 3;
        if (stager && t + 2 < NT)
            __builtin_amdgcn_global_load_lds((const __attribute__((address_space(1))) void*)(Ab + gaA + (long long)(t + 2) * 32),
                                             (__attribute__((address_space(3))) void*)(&As[nb][tid * 8]), 16, 0, 0);
        bf16x8 bn0, bn1;
        if (t + 1 < NT) {
            const u16* Bn = Bw + (size_t)(t + 1) * 8192;
            bn0 = *(const bf16x8*)(Bn);
            bn1 = *(const bf16x8*)(Bn + 512);
        } else { bn0 = bc0; bn1 = bc1; }

        const u16* Ac = As[cb];
        bf16x8 af[4];
#pragma unroll
        for (int tt = 0; tt < 4; ++tt) af[tt] = *(const bf16x8*)(Ac + aoff[tt]);
#pragma unroll
        for (int i = 0; i < 4; ++i) {
            acc[i][0] = __builtin_amdgcn_mfma_f32_16x16x32_bf16(bc0, af[i], acc[i][0], 0, 0, 0);
            acc[i][1] = __builtin_amdgcn_mfma_f32_16x16x32_bf16(bc1, af[i], acc[i][1], 0, 0, 0);
        }
        bc0 = bn0; bc1 = bn1;
        cb = (cb + 1 == 3) ? 0 : cb + 1;
    }

    // epilogue: add bias + residual, then per-row LN over all 256 cols
    float4 sh2[2];
#pragma unroll
    for (int j = 0; j < 2; ++j)
        sh2[j] = *(const float4*)&bias[w * 32 + j * 16 + quad * 4];

    float s_[4] = {0.f, 0.f, 0.f, 0.f}, ss_[4] = {0.f, 0.f, 0.f, 0.f};
#pragma unroll
    for (int i = 0; i < 4; ++i) {
        const int row = m0 + i * 16 + r;
#pragma unroll
        for (int j = 0; j < 2; ++j) {
            const int colb = w * 32 + j * 16 + quad * 4;
            float4 qo = *(const float4*)&q[(size_t)row * DM + colb];
            acc[i][j][0] += sh2[j].x + qo.x;
            acc[i][j][1] += sh2[j].y + qo.y;
            acc[i][j][2] += sh2[j].z + qo.z;
            acc[i][j][3] += sh2[j].w + qo.w;
#pragma unroll
            for (int e = 0; e < 4; ++e) {
                s_[i] += acc[i][j][e];
                ss_[i] += acc[i][j][e] * acc[i][j][e];
            }
        }
    }
#pragma unroll
    for (int i = 0; i < 4; ++i) {
        s_[i] += __shfl_xor(s_[i], 16);  ss_[i] += __shfl_xor(ss_[i], 16);
        s_[i] += __shfl_xor(s_[i], 32);  ss_[i] += __shfl_xor(ss_[i], 32);
    }
    if (quad == 0) {
#pragma unroll
        for (int i = 0; i < 4; ++i) {
            red_s[w][i * 16 + r] = s_[i];
            red_ss[w][i * 16 + r] = ss_[i];
        }
    }
    __syncthreads();

    float mean[4], rstd[4];
#pragma unroll
    for (int i = 0; i < 4; ++i) {
        float S = 0.f, SS = 0.f;
#pragma unroll
        for (int w2 = 0; w2 < 8; ++w2) { S += red_s[w2][i * 16 + r]; SS += red_ss[w2][i * 16 + r]; }
        mean[i] = S * (1.0f / 256.0f);
        rstd[i] = rsqrtf(SS * (1.0f / 256.0f) - mean[i] * mean[i] + EPSV);
    }

    float4 g4[2], bt4[2];
#pragma unroll
    for (int j = 0; j < 2; ++j) {
        int colb = w * 32 + j * 16 + quad * 4;
        g4[j] = *(const float4*)&g[colb];
        bt4[j] = *(const float4*)&beta[colb];
    }
#pragma unroll
    for (int i = 0; i < 4; ++i) {
        const int row = m0 + i * 16 + r;
#pragma unroll
        for (int j = 0; j < 2; ++j) {
            const int colb = w * 32 + j * 16 + quad * 4;
            float o0 = (acc[i][j][0] - mean[i]) * rstd[i] * g4[j].x + bt4[j].x;
            float o1 = (acc[i][j][1] - mean[i]) * rstd[i] * g4[j].y + bt4[j].y;
            float o2 = (acc[i][j][2] - mean[i]) * rstd[i] * g4[j].z + bt4[j].z;
            float o3 = (acc[i][j][3] - mean[i]) * rstd[i] * g4[j].w + bt4[j].w;
            *(float4*)&q[(size_t)row * DM + colb] = make_float4(o0, o1, o2, o3);
            *(uint2*)(q16 + (size_t)row * DM + colb) = make_uint2(pk2(o0, o1), pk2(o2, o3));
        }
    }
}

// ============ Fused FFN: q = LN2(q + relu(q16@W1+b1)@W2 + b2) ============
// Block = 64 rows, 512 threads (8 waves). 8 chunks of 128 H-cols; hF = 16 KB single
// buffer -> LDS 52 KB -> 3 blocks/CU. Raw barriers (lgkm-only drain) keep w1F/w2F
// global loads in flight; phase1(c+1) shares a barrier epoch with phase2(c).
// Accumulation order over global ks2 unchanged -> bit-identical results.
// (Verified correct in round 5; perf delta was masked by the attn regression.)
__global__ __launch_bounds__(512, 6) void ffn_fused(
    const u16* __restrict__ q16in, const u16* __restrict__ w1F, const u16* __restrict__ w2F,
    const float* __restrict__ b1, const float* __restrict__ b2,
    float* __restrict__ q, u16* __restrict__ q16,
    const float* __restrict__ g, const float* __restrict__ beta)
{
    __shared__ u16 Aq[16384];                 // 64 rows x K=256 (swizzled chunks)
    __shared__ u16 hF[8192];                  // one 64x128 H chunk in A-frag layout
    __shared__ float red_s[8][64], red_ss[8][64];
    const int tid = threadIdx.x;
    const int lane = tid & 63;
    const int w = tid >> 6;
    const int quad = lane >> 4, r = lane & 15;
    const int m0 = blockIdx.x << 6;

    // stage entire A (64x256 q16) once: 2048 16B units, 4 per thread
    const u16* Ab = q16in + (long long)m0 * DM;
#pragma unroll
    for (int i = 0; i < 4; ++i) {
        int u = tid + i * 512;
        int ks = u >> 8, v = u & 255;
        int m = v >> 2, c = (v & 3) ^ ((m >> 1) & 3);
        __builtin_amdgcn_global_load_lds((const __attribute__((address_space(1))) void*)(Ab + (long long)m * DM + ks * 32 + c * 8),
                                         (__attribute__((address_space(3))) void*)(Aq + u * 8), 16, 0, 0);
    }

    int aoff[4];
#pragma unroll
    for (int t = 0; t < 4; ++t) {
        int m = t * 16 + r;
        aoff[t] = (m * 4 + (quad ^ ((m >> 1) & 3))) * 8;
    }

    // pack destination: X = 4w+quad selects (ksl, quad', eo) within the chunk
    const int X = 4 * w + quad;
    const int packbase = (X >> 3) * 2048 + ((X & 7) >> 1) * 128 + r * 8 + (X & 1) * 4;

    f32x4 acc2[4][2];
#pragma unroll
    for (int i = 0; i < 4; ++i)
#pragma unroll
        for (int j = 0; j < 2; ++j) acc2[i][j] = (f32x4){0.f, 0.f, 0.f, 0.f};

    __syncthreads();

    for (int cch = 0; cch < 8; ++cch) {
        // ---- phase 1: H cols [cch*128 + w*16, +16) = A @ W1 (registers)
        f32x4 acc1[4];
#pragma unroll
        for (int i = 0; i < 4; ++i) acc1[i] = (f32x4){0.f, 0.f, 0.f, 0.f};
        __builtin_amdgcn_s_setprio(1);
#pragma unroll
        for (int ks = 0; ks < 8; ++ks) {
            const u16* bp = w1F + ((size_t)(ks * 64 + cch * 8 + w) * 64 + lane) * 8;
            bf16x8 bf = *(const bf16x8*)bp;
            bf16x8 af[4];
#pragma unroll
            for (int t = 0; t < 4; ++t) af[t] = *(const bf16x8*)(Aq + ks * 2048 + aoff[t]);
#pragma unroll
            for (int i = 0; i < 4; ++i)
                acc1[i] = __builtin_amdgcn_mfma_f32_16x16x32_bf16(bf, af[i], acc1[i], 0, 0, 0);
        }
        __builtin_amdgcn_s_setprio(0);
        __builtin_amdgcn_sched_barrier(0);
        __builtin_amdgcn_s_barrier();          // prev phase2's hF reads complete

        // pack: bias + relu + bf16 into hF
        {
            const int cb = cch * 128 + w * 16 + quad * 4;
            const float4 b14 = *(const float4*)&b1[cb];
#pragma unroll
            for (int i = 0; i < 4; ++i) {
                f32x4 v = acc1[i];
                uint2 o;
                o.x = pk2(fmaxf(v[0] + b14.x, 0.f), fmaxf(v[1] + b14.y, 0.f));
                o.y = pk2(fmaxf(v[2] + b14.z, 0.f), fmaxf(v[3] + b14.w, 0.f));
                *(uint2*)(hF + packbase + i * 512) = o;
            }
        }
        asm volatile("s_waitcnt lgkmcnt(0)" ::: "memory");
        __builtin_amdgcn_s_barrier();          // hF chunk complete
        __builtin_amdgcn_sched_barrier(0);

        // ---- phase 2: acc2 += H_chunk @ W2[cch*128 .. +128, :]
        __builtin_amdgcn_s_setprio(1);
#pragma unroll
        for (int ks = 0; ks < 4; ++ks) {
            const u16* bp = w2F + ((size_t)((cch * 4 + ks) * 16 + w * 2) * 64 + lane) * 8;
            bf16x8 bf0 = *(const bf16x8*)bp;
            bf16x8 bf1 = *(const bf16x8*)(bp + 512);
            bf16x8 af[4];
#pragma unroll
            for (int t = 0; t < 4; ++t) af[t] = *(const bf16x8*)(hF + ((ks * 4 + t) * 64 + lane) * 8);
#pragma unroll
            for (int i = 0; i < 4; ++i) {
                acc2[i][0] = __builtin_amdgcn_mfma_f32_16x16x32_bf16(bf0, af[i], acc2[i][0], 0, 0, 0);
                acc2[i][1] = __builtin_amdgcn_mfma_f32_16x16x32_bf16(bf1, af[i], acc2[i][1], 0, 0, 0);
            }
        }
        __builtin_amdgcn_s_setprio(0);
    }

    // epilogue: bias b2 + residual + LN2, write q (fp32) and q16
    float4 sh2[2];
#pragma unroll
    for (int j = 0; j < 2; ++j)
        sh2[j] = *(const float4*)&b2[w * 32 + j * 16 + quad * 4];

    float s_[4] = {0.f, 0.f, 0.f, 0.f}, ss_[4] = {0.f, 0.f, 0.f, 0.f};
#pragma unroll
    for (int i = 0; i < 4; ++i) {
        const int row = m0 + i * 16 + r;
#pragma unroll
        for (int j = 0; j < 2; ++j) {
            const int colb = w * 32 + j * 16 + quad * 4;
            float4 qo = *(const float4*)&q[(size_t)row * DM + colb];
            acc2[i][j][0] += sh2[j].x + qo.x;
            acc2[i][j][1] += sh2[j].y + qo.y;
            acc2[i][j][2] += sh2[j].z + qo.z;
            acc2[i][j][3] += sh2[j].w + qo.w;
#pragma unroll
            for (int e = 0; e < 4; ++e) {
                s_[i] += acc2[i][j][e];
                ss_[i] += acc2[i][j][e] * acc2[i][j][e];
            }
        }
    }
#pragma unroll
    for (int i = 0; i < 4; ++i) {
        s_[i] += __shfl_xor(s_[i], 16);  ss_[i] += __shfl_xor(ss_[i], 16);
        s_[i] += __shfl_xor(s_[i], 32);  ss_[i] += __shfl_xor(ss_[i], 32);
    }
    if (quad == 0) {
#pragma unroll
        for (int i = 0; i < 4; ++i) {
            red_s[w][i * 16 + r] = s_[i];
            red_ss[w][i * 16 + r] = ss_[i];
        }
    }
    __syncthreads();

    float mean[4], rstd[4];
#pragma unroll
    for (int i = 0; i < 4; ++i) {
        float S = 0.f, SS = 0.f;
#pragma unroll
        for (int w2 = 0; w2 < 8; ++w2) { S += red_s[w2][i * 16 + r]; SS += red_ss[w2][i * 16 + r]; }
        mean[i] = S * (1.0f / 256.0f);
        rstd[i] = rsqrtf(SS * (1.0f / 256.0f) - mean[i] * mean[i] + EPSV);
    }

    float4 g4[2], bt4[2];
#pragma unroll
    for (int j = 0; j < 2; ++j) {
        int colb = w * 32 + j * 16 + quad * 4;
        g4[j] = *(const float4*)&g[colb];
        bt4[j] = *(const float4*)&beta[colb];
    }
#pragma unroll
    for (int i = 0; i < 4; ++i) {
        const int row = m0 + i * 16 + r;
#pragma unroll
        for (int j = 0; j < 2; ++j) {
            const int colb = w * 32 + j * 16 + quad * 4;
            float o0 = (acc2[i][j][0] - mean[i]) * rstd[i] * g4[j].x + bt4[j].x;
            float o1 = (acc2[i][j][1] - mean[i]) * rstd[i] * g4[j].y + bt4[j].y;
            float o2 = (acc2[i][j][2] - mean[i]) * rstd[i] * g4[j].z + bt4[j].z;
            float o3 = (acc2[i][j][3] - mean[i]) * rstd[i] * g4[j].w + bt4[j].w;
            *(float4*)&q[(size_t)row * DM + colb] = make_float4(o0, o1, o2, o3);
            *(uint2*)(q16 + (size_t)row * DM + colb) = make_uint2(pk2(o0, o1), pk2(o2, o3));
        }
    }
}

// ================= weight prep =================
__device__ __attribute__((noinline)) void tconv(const float* src, u16* dst, int K, int N, int tk, int tn)
{
    __shared__ float t[32][33];
    const int tx = threadIdx.x & 31, ty = threadIdx.x >> 5;
#pragma unroll
    for (int i = 0; i < 4; ++i)
        t[ty + i * 8][tx] = src[(size_t)(tk * 32 + ty + i * 8) * N + tn * 32 + tx];
    __syncthreads();
#pragma unroll
    for (int i = 0; i < 4; ++i)
        dst[(size_t)(tn * 32 + ty + i * 8) * K + tk * 32 + tx] = f2b(t[tx][ty + i * 8]);
}

__device__ __attribute__((noinline)) void tconv_oa(const float* Woff, const float* Wattn, u16* dst, int tk, int tn)
{
    __shared__ float t[32][33];
    const int tx = threadIdx.x & 31, ty = threadIdx.x >> 5;
#pragma unroll
    for (int i = 0; i < 4; ++i) {
        int k = tk * 32 + ty + i * 8, n = tn * 32 + tx;
        float v = (n < 64) ? Woff[k * 64 + n] : ((n < 96) ? Wattn[k * 32 + n - 64] : 0.f);
        t[ty + i * 8][tx] = v;
    }
    __syncthreads();
#pragma unroll
    for (int i = 0; i < 4; ++i)
        dst[(size_t)(tn * 32 + ty + i * 8) * 256 + tk * 32 + tx] = f2b(t[tx][ty + i * 8]);
}

// W (K,N) fp32 -> fragment-ordered bf16:
// F[ks][nt][lane][e] = W[ks*32 + (lane>>4)*8 + e][nt*16 + (lane&15)]
__device__ __attribute__((noinline)) void frag_prep(const float* W, u16* dst, int ks, int nc, int N)
{
    __shared__ float t[32][256];
    const int tid = threadIdx.x;
#pragma unroll
    for (int kk = 0; kk < 32; ++kk)
        t[kk][tid] = W[(size_t)(ks * 32 + kk) * N + nc * 256 + tid];
    __syncthreads();
    const int NT16 = N >> 4;
#pragma unroll
    for (int i = 0; i < 4; ++i) {
        int idx = tid + i * 256;          // local nt*64 + lane
        int nt = idx >> 6, l = idx & 63;
        int n = nt * 16 + (l & 15);
        int kb = (l >> 4) * 8;
        u16 o[8];
#pragma unroll
        for (int e = 0; e < 8; ++e) o[e] = f2b(t[kb + e][n]);
        *(uint4*)(dst + ((size_t)(ks * NT16 + nc * 16 + nt) * 64 + l) * 8) = *(const uint4*)o;
    }
}

__global__ __launch_bounds__(256) void prep_weights(
    const float* __restrict__ Wval, const float* __restrict__ Wo,
    const float* __restrict__ W1, const float* __restrict__ W2,
    const float* __restrict__ Woff, const float* __restrict__ Wattn,
    const float* __restrict__ boff, const float* __restrict__ battn,
    const float* __restrict__ W_in, const float* __restrict__ W_out,
    const float* __restrict__ bn1g, const float* __restrict__ bn1b,
    const float* __restrict__ bn1m, const float* __restrict__ bn1v,
    const float* __restrict__ bn2g, const float* __restrict__ bn2b,
    const float* __restrict__ bn2m, const float* __restrict__ bn2v,
    u16* __restrict__ wvalT, u16* __restrict__ woF, u16* __restrict__ w1F,
    u16* __restrict__ w2F, u16* __restrict__ woaT,
    u16* __restrict__ winC, u16* __restrict__ woutC,
    float* __restrict__ bn1sc, float* __restrict__ bn1sh,
    float* __restrict__ bn2sc, float* __restrict__ bn2sh, float* __restrict__ boa)
{
    int bid = blockIdx.x;
    if (bid < 128) {                          // Wval transpose: 2 layers x 64
        int l = bid >> 6, r2 = bid & 63;
        tconv(Wval + l * 65536, wvalT + l * 65536, 256, 256, r2 & 7, r2 >> 3);
    } else if (bid < 192) {                   // Woff|Wattn transpose: 2 x 32
        int i2 = bid - 128, l = i2 >> 5, r2 = i2 & 31;
        tconv_oa(Woff + l * 16384, Wattn + l * 8192, woaT + l * 32768, r2 & 7, r2 >> 3);
    } else if (bid < 208) {                   // Wo fragments: 2 x 8 ks
        int i2 = bid - 192;
        frag_prep(Wo + (i2 >> 3) * 65536, woF + (i2 >> 3) * 65536, i2 & 7, 0, 256);
    } else if (bid < 272) {                   // W1 fragments: 2 x (8 ks x 4 nc)
        int i2 = bid - 208, l = i2 >> 5, r2 = i2 & 31;
        frag_prep(W1 + l * 262144, w1F + l * 262144, r2 >> 2, r2 & 3, 1024);
    } else if (bid < 336) {                   // W2 fragments: 2 x 32 ks
        int i2 = bid - 272;
        frag_prep(W2 + (i2 >> 5) * 262144, w2F + (i2 >> 5) * 262144, i2 & 31, 0, 256);
    } else if (bid < 368) {
        int g2 = bid - 336, base = g2 * 4096, t = threadIdx.x;
#pragma unroll
        for (int k = 0; k < 16; ++k) winC[base + k * 256 + t] = f2b(W_in[base + k * 256 + t]);
    } else if (bid < 400) {
        int g2 = bid - 368, base = g2 * 4096, t = threadIdx.x;
#pragma unroll
        for (int k = 0; k < 16; ++k) woutC[base + k * 256 + t] = f2b(W_out[base + k * 256 + t]);
    } else {
        int t = threadIdx.x;
        { float s = bn1g[t] * rsqrtf(bn1v[t] + EPSV); bn1sc[t] = s; bn1sh[t] = bn1b[t] - bn1m[t] * s; }
        for (int c = 0; c < 2; ++c) {
            int i = c * 256 + t;
            float s = bn2g[i] * rsqrtf(bn2v[i] + EPSV);
            bn2sc[i] = s; bn2sh[i] = bn2b[i] - bn2m[i] * s;
        }
        if (t < 128)
            for (int l = 0; l < 2; ++l)
                boa[l * 128 + t] = (t < 64) ? boff[l * 64 + t]
                                 : ((t < 96) ? battn[l * 32 + t - 64] : 0.f);
    }
}

// ================= x (B,C,HW) -> xT (B,HW,C) bf16 =================
__global__ __launch_bounds__(256) void transpose_x(const float* __restrict__ x, u16* __restrict__ xT)
{
    __shared__ float t[64][65];
    const int b = blockIdx.z, p0 = blockIdx.y << 6, c0 = blockIdx.x << 6;
    const int tx = threadIdx.x & 63, ty = threadIdx.x >> 6;
    const float* xb = x + ((size_t)b * CINC + c0) * HWTOT + p0;
#pragma unroll
    for (int i = 0; i < 16; ++i)
        t[ty + i * 4][tx] = xb[(size_t)(ty + i * 4) * HWTOT + tx];
    __syncthreads();
    u16* xo = xT + ((size_t)b * HWTOT + p0) * CINC + c0;
#pragma unroll
    for (int i = 0; i < 16; ++i)
        xo[(size_t)(ty + i * 4) * CINC + tx] = f2b(t[tx][ty + i * 4]);
}

// ================= deformable sampling: 8 queries/block, 32 lanes/query =================
struct IW { int eo; float w; };

__global__ __launch_bounds__(256) void sample_kernel(
    const u16* __restrict__ val,      // (B*HW, D) bf16
    const float* __restrict__ oa,     // (B*HW, 128): [0..63]=off, [64..95]=attn logits
    u16* __restrict__ oms)            // (B*HW, D) bf16
{
    __shared__ float s_oa[8][96];
    __shared__ IW s_iw[8][32][5];
    const int t = threadIdx.x;
    const int bq0 = blockIdx.x << 3;
    const int b = blockIdx.x >> 9;

    {
        int qi = t >> 5, j = t & 31;
        if (j < 24)
            ((float4*)s_oa[qi])[j] = ((const float4*)oa)[((size_t)(bq0 + qi)) * 32 + j];
    }
    __syncthreads();

    {
        const int qi = t >> 5, hp = t & 31, h = hp >> 2, p = hp & 3;
        const float* so = s_oa[qi];
        float l0 = so[64 + h * 4 + 0], l1 = so[64 + h * 4 + 1];
        float l2 = so[64 + h * 4 + 2], l3 = so[64 + h * 4 + 3];
        float mx = fmaxf(fmaxf(l0, l1), fmaxf(l2, l3));
        float e0 = __expf(l0 - mx), e1 = __expf(l1 - mx), e2 = __expf(l2 - mx), e3 = __expf(l3 - mx);
        float inv = 1.0f / (e0 + e1 + e2 + e3);
        float aw = ((p == 0) ? e0 : (p == 1) ? e1 : (p == 2) ? e2 : e3) * inv;
        const int bq = bq0 + qi;
        float gx = (float)(bq & 63) + so[hp * 2 + 0];
        float gy = (float)((bq >> 6) & 63) + so[hp * 2 + 1];
        float x0f = floorf(gx), y0f = floorf(gy);
        float wx = gx - x0f, wy = gy - y0f;
        int x0 = (int)x0f, y0 = (int)y0f;
#pragma unroll
        for (int c = 0; c < 4; ++c) {
            int xi = x0 + (c & 1), yi = y0 + (c >> 1);
            bool ok = (xi >= 0) && (xi < 64) && (yi >= 0) && (yi < 64);
            float wgt = ((c & 1) ? wx : 1.0f - wx) * ((c >> 1) ? wy : 1.0f - wy);
            s_iw[qi][hp][c].eo = ok ? ((yi * 64 + xi) << 8) : 0;
            s_iw[qi][hp][c].w = ok ? aw * wgt : 0.f;
        }
    }
    __syncthreads();

    {
        const int qi = t >> 5, l = t & 31, h = l >> 2, cc = l & 3;
        const u16* base = val + ((size_t)b << 20) + (h << 5) + (cc << 3);
        float a[8] = {0.f, 0.f, 0.f, 0.f, 0.f, 0.f, 0.f, 0.f};
#pragma unroll
        for (int p = 0; p < 4; ++p)
#pragma unroll
            for (int c = 0; c < 4; ++c) {
                IW iw = s_iw[qi][(h << 2) + p][c];
                uint4 v = *(const uint4*)(base + iw.eo);
                a[0] += iw.w * blo(v.x); a[1] += iw.w * bhi(v.x);
                a[2] += iw.w * blo(v.y); a[3] += iw.w * bhi(v.y);
                a[4] += iw.w * blo(v.z); a[5] += iw.w * bhi(v.z);
                a[6] += iw.w * blo(v.w); a[7] += iw.w * bhi(v.w);
            }
        uint4 o;
        o.x = (uint32_t)f2b(a[0]) | ((uint32_t)f2b(a[1]) << 16);
        o.y = (uint32_t)f2b(a[2]) | ((uint32_t)f2b(a[3]) << 16);
        o.z = (uint32_t)f2b(a[4]) | ((uint32_t)f2b(a[5]) << 16);
        o.w = (uint32_t)f2b(a[6]) | ((uint32_t)f2b(a[7]) << 16);
        *(uint4*)(oms + (size_t)(bq0 + qi) * 256 + (h << 5) + (cc << 3)) = o;
    }
}

__global__ __launch_bounds__(256) void bcast_q(
    const float4* __restrict__ qe, float4* __restrict__ q, u16* __restrict__ q16)
{
    const int i = blockIdx.x * 256 + threadIdx.x;
    float4 v = qe[i];
    uint2 pk = make_uint2(pk2(v.x, v.y), pk2(v.z, v.w));
#pragma unroll
    for (int b = 0; b < BBATCH; ++b) {
        q[(size_t)b * 262144 + i] = v;
        ((uint2*)q16)[(size_t)b * 262144 + i] = pk;
    }
}

extern "C" void kernel_launch(void* const* d_in, const int* in_sizes, int n_in,
                              void* d_out, int out_size, void* d_ws, size_t ws_size,
                              hipStream_t stream)
{
    (void)in_sizes; (void)n_in; (void)out_size; (void)ws_size;
    const float* x     = (const float*)d_in[0];
    const float* W_in  = (const float*)d_in[1];
    const float* bn1_g = (const float*)d_in[2];
    const float* bn1_b = (const float*)d_in[3];
    const float* bn1_m = (const float*)d_in[4];
    const float* bn1_v = (const float*)d_in[5];
    const float* qe    = (const float*)d_in[6];
    const float* Woff  = (const float*)d_in[7];
    const float* boff  = (const float*)d_in[8];
    const float* Wattn = (const float*)d_in[9];
    const float* battn = (const float*)d_in[10];
    const float* Wval  = (const float*)d_in[11];
    const float* bval  = (const float*)d_in[12];
    const float* Wo    = (const float*)d_in[13];
    const float* bo    = (const float*)d_in[14];
    const float* ln1_g = (const float*)d_in[15];
    const float* ln1_b = (const float*)d_in[16];
    const float* W1    = (const float*)d_in[17];
    const float* b1    = (const float*)d_in[18];
    const float* W2    = (const float*)d_in[19];
    const float* b2    = (const float*)d_in[20];
    const float* ln2_g = (const float*)d_in[21];
    const float* ln2_b = (const float*)d_in[22];
    const float* W_out = (const float*)d_in[23];
    const float* bn2_g = (const float*)d_in[24];
    const float* bn2_b = (const float*)d_in[25];
    const float* bn2_m = (const float*)d_in[26];
    const float* bn2_v = (const float*)d_in[27];
    float* out = (float*)d_out;

    char* w = (char*)d_ws;
    // pool (time-disjoint): xT (33.5MB) | val16+offat+oms16 (50MB)
    char* pool    = w;          w += 67108864;
    float* q      = (float*)w;  w += 33554432;
    u16*  q16     = (u16*)w;    w += 16777216;
    u16*  src16   = (u16*)w;    w += 16777216;
    u16*  wvalT   = (u16*)w;    w += 262144;
    u16*  woF     = (u16*)w;    w += 262144;
    u16*  w1F     = (u16*)w;    w += 1048576;
    u16*  w2F     = (u16*)w;    w += 1048576;
    u16*  woaT    = (u16*)w;    w += 131072;
    u16*  winC    = (u16*)w;    w += 262144;
    u16*  woutC   = (u16*)w;    w += 262144;
    float* bn1sc  = (float*)w;  w += 1024;
    float* bn1sh  = (float*)w;  w += 1024;
    float* bn2sc  = (float*)w;  w += 2048;
    float* bn2sh  = (float*)w;  w += 2048;
    float* boa    = (float*)w;  w += 1024;

    u16*  xT     = (u16*)pool;
    u16*  val16  = (u16*)pool;
    float* offat = (float*)(pool + 16777216);
    u16*  oms16  = (u16*)(pool + 33554432);

    prep_weights<<<dim3(401), 256, 0, stream>>>(
        Wval, Wo, W1, W2, Woff, Wattn, boff, battn, W_in, W_out,
        bn1_g, bn1_b, bn1_m, bn1_v, bn2_g, bn2_b, bn2_m, bn2_v,
        wvalT, woF, w1F, w2F, woaT, winC, woutC, bn1sc, bn1sh, bn2sc, bn2sh, boa);
    transpose_x<<<dim3(CINC / 64, HWTOT / 64, BBATCH), 256, 0, stream>>>(x, xT);
    bcast_q<<<dim3(1024), 256, 0, stream>>>((const float4*)qe, (float4*)q, q16);

    // proj_in: (32768,512)@(256,512)^T -> bf16 src
    mfma_gemm<1><<<dim3(2, 256, 1), 256, 0, stream>>>(
        xT, winC, bn1sc, bn1sh, src16, 32768, 256, 512, 256, 0, 0, 0, 1, 1);

    for (int l = 0; l < LYR; ++l) {
        mfma_gemm<0><<<dim3(2, 256, 1), 256, 0, stream>>>(
            src16, wvalT + l * 65536, nullptr, bval + l * 256, val16,
            32768, 256, 256, 256, 0, 0, 0, 1, 1);
        mfma_gemm<2><<<dim3(1, 256, 1), 256, 0, stream>>>(
            q16, woaT + l * 32768, nullptr, boa + l * 128, offat,
            32768, 128, 256, 128, 0, 0, 0, 1, 0);
        sample_kernel<<<dim3(4096), 256, 0, stream>>>(val16, offat, oms16);
        // Wo GEMM + bias + residual + LN1 fused
        mfma_gemm_ln<<<dim3(512), 512, 0, stream>>>(
            oms16, woF + l * 65536, bo + l * 256, q, q16,
            ln1_g + l * 256, ln1_b + l * 256, 256);
        // FFN1 + FFN2 + bias + residual + LN2, H stays on-chip (3 blocks/CU variant)
        ffn_fused<<<dim3(512), 512, 0, stream>>>(
            q16, w1F + l * 262144, w2F + l * 262144,
            b1 + l * 1024, b2 + l * 256, q, q16,
            ln2_g + l * 256, ln2_b + l * 256);
    }

    // proj_out: per-batch (512,256)@(4096,256)^T -> fp32 out (B,C,HW)
    mfma_gemm<3><<<dim3(32, 4, BBATCH), 256, 0, stream>>>(
        woutC, q16, bn2sc, bn2sh, out, 512, 4096, 256, 4096,
        0, (long long)HWTOT * DM, (long long)CINC * HWTOT, 0, 0);
}

// Round 7
// 461.347 us; speedup vs baseline: 1.2447x; 1.0943x over previous
//
#include <hip/hip_runtime.h>
#include <cstdint>

#define LYR 2
#define DM  256
#define DFFN 1024
#define CINC 512
#define BBATCH 8
#define HWTOT 4096
#define EPSV 1e-5f

using u16 = unsigned short;
typedef __attribute__((ext_vector_type(8))) short bf16x8;
typedef __attribute__((ext_vector_type(4))) float f32x4;

__device__ inline u16 f2b(float v) {
    union { float f; uint32_t u; } x; x.f = v;
    uint32_t r = x.u + 0x7fffu + ((x.u >> 16) & 1u);
    return (u16)(r >> 16);
}
__device__ inline uint32_t pk2(float a, float b) {
    return (uint32_t)f2b(a) | ((uint32_t)f2b(b) << 16);
}
__device__ inline float blo(uint32_t d) {
    union { uint32_t i; float f; } x; x.i = d << 16; return x.f;
}
__device__ inline float bhi(uint32_t d) {
    union { uint32_t i; float f; } x; x.i = d & 0xffff0000u; return x.f;
}

// ============ bf16 MFMA GEMM: C = A(M,K) @ Bt(N,K)^T, 128x128 tile, BK=32 ============
// Counted-vmcnt pipeline: 4 LDS buffers, 2-group-deep prefetch, raw s_barrier.
// MODE 0: bf16 out, x+shift[col]                   (val)
// MODE 1: bf16 out, relu(x*scale[col]+shift[col])  (proj_in)
// MODE 2: fp32 out, x+shift[col]                   (offattn)
// MODE 3: fp32 out, relu(x*scale[row]+shift[row])  (proj_out)
template<int MODE>
__global__ __launch_bounds__(256) void mfma_gemm(
    const u16* __restrict__ A, const u16* __restrict__ Bt,
    const float* __restrict__ scale, const float* __restrict__ shift,
    void* __restrict__ Cv, int M, int N, int K, int ldc,
    long long a_zs, long long b_zs, long long c_zs, int swz, int gxlog)
{
    __shared__ u16 As[4][4096];
    __shared__ u16 Bs[4][4096];
    const int tid = threadIdx.x;
    const int lane = tid & 63;
    const int wid = tid >> 6;
    const int wm = (wid & 1) << 6, wn = (wid >> 1) << 6;
    const int quad = lane >> 4, r = lane & 15;

    int bx = blockIdx.x, by = blockIdx.y;
    if (swz) {  // XCD-band swizzle: XCD k owns a contiguous band of row-tiles
        int linear = by * gridDim.x + bx;
        int xcd = linear & 7;
        int s = linear >> 3;
        bx = s & (gridDim.x - 1);
        by = xcd * (gridDim.y >> 3) + (s >> gxlog);
    }
    const int m0 = by << 7, n0 = bx << 7;
    const u16* Ab = A + (long long)blockIdx.z * a_zs + (long long)m0 * K;
    const u16* Bb = Bt + (long long)blockIdx.z * b_zs + (long long)n0 * K;

    // staging (BK=32): unit u (16B): row m=u>>2, pos p=u&3, chunk c=p^((m>>1)&3)
    const int u0 = tid, u1 = tid + 256;
    const int mu0 = u0 >> 2, cu0 = (u0 & 3) ^ ((mu0 >> 1) & 3);
    const int mu1 = u1 >> 2, cu1 = (u1 & 3) ^ ((mu1 >> 1) & 3);
    const long long ga0 = (long long)mu0 * K + cu0 * 8;
    const long long ga1 = (long long)mu1 * K + cu1 * 8;

    int aoff[4], boff[4];
#pragma unroll
    for (int t = 0; t < 4; ++t) {
        int m = wm + t * 16 + r;
        aoff[t] = (m * 4 + (quad ^ ((m >> 1) & 3))) * 8;
        int n = wn + t * 16 + r;
        boff[t] = (n * 4 + (quad ^ ((n >> 1) & 3))) * 8;
    }

    f32x4 acc[4][4];
#pragma unroll
    for (int i = 0; i < 4; ++i)
#pragma unroll
        for (int j = 0; j < 4; ++j) acc[i][j] = (f32x4){0.f, 0.f, 0.f, 0.f};

    const int NT = K >> 5;   // >= 3 for all call sites (8 or 16)

#define GSTAGE(g, b) do {                                                                       \
    const long long kk = (long long)(g) << 5;                                                   \
    __builtin_amdgcn_global_load_lds((const __attribute__((address_space(1))) void*)(Ab + ga0 + kk), \
        (__attribute__((address_space(3))) void*)(&As[b][u0 * 8]), 16, 0, 0);                   \
    __builtin_amdgcn_global_load_lds((const __attribute__((address_space(1))) void*)(Ab + ga1 + kk), \
        (__attribute__((address_space(3))) void*)(&As[b][u1 * 8]), 16, 0, 0);                   \
    __builtin_amdgcn_global_load_lds((const __attribute__((address_space(1))) void*)(Bb + ga0 + kk), \
        (__attribute__((address_space(3))) void*)(&Bs[b][u0 * 8]), 16, 0, 0);                   \
    __builtin_amdgcn_global_load_lds((const __attribute__((address_space(1))) void*)(Bb + ga1 + kk), \
        (__attribute__((address_space(3))) void*)(&Bs[b][u1 * 8]), 16, 0, 0);                   \
} while (0)

    // prologue: stage tiles 0,1,2 (12 loads outstanding)
    GSTAGE(0, 0);
    GSTAGE(1, 1);
    GSTAGE(2, 2);

    for (int t = 0; t < NT; ++t) {
        // wait for tile t's group; keep up to 2 future groups (8 loads) in flight
        if (t < NT - 2)       asm volatile("s_waitcnt vmcnt(8)" ::: "memory");
        else if (t == NT - 2) asm volatile("s_waitcnt vmcnt(4)" ::: "memory");
        else                  asm volatile("s_waitcnt vmcnt(0)" ::: "memory");
        __builtin_amdgcn_s_barrier();
        __builtin_amdgcn_sched_barrier(0);   // pin: no motion across the barrier
        if (t + 3 < NT) GSTAGE(t + 3, (t + 3) & 3);
        const u16* Ap = As[t & 3];
        const u16* Bp = Bs[t & 3];
        bf16x8 af[4], bf[4];
#pragma unroll
        for (int tt = 0; tt < 4; ++tt) af[tt] = *(const bf16x8*)(Ap + aoff[tt]);
#pragma unroll
        for (int tt = 0; tt < 4; ++tt) bf[tt] = *(const bf16x8*)(Bp + boff[tt]);
#pragma unroll
        for (int i = 0; i < 4; ++i)
#pragma unroll
            for (int j = 0; j < 4; ++j)
                acc[i][j] = __builtin_amdgcn_mfma_f32_16x16x32_bf16(bf[j], af[i], acc[i][j], 0, 0, 0);
    }
#undef GSTAGE

    const long long zc = (long long)blockIdx.z * c_zs;
    float4 sh4[4], sc4[4];
    if (MODE != 3) {
#pragma unroll
        for (int j = 0; j < 4; ++j) {
            int colb = n0 + wn + j * 16 + quad * 4;
            sh4[j] = *(const float4*)&shift[colb];
            if (MODE == 1) sc4[j] = *(const float4*)&scale[colb];
        }
    }
#pragma unroll
    for (int i = 0; i < 4; ++i) {
        const int row = m0 + wm + i * 16 + r;
        float rsc = 0.f, rsh = 0.f;
        if (MODE == 3) { rsc = scale[row]; rsh = shift[row]; }
#pragma unroll
        for (int j = 0; j < 4; ++j) {
            const int colb = n0 + wn + j * 16 + quad * 4;
            f32x4 v = acc[i][j];
            if (MODE == 0) {
                uint2 o;
                o.x = pk2(v[0] + sh4[j].x, v[1] + sh4[j].y);
                o.y = pk2(v[2] + sh4[j].z, v[3] + sh4[j].w);
                *(uint2*)((u16*)Cv + zc + (long long)row * ldc + colb) = o;
            } else if (MODE == 1) {
                uint2 o;
                o.x = pk2(fmaxf(v[0] * sc4[j].x + sh4[j].x, 0.f), fmaxf(v[1] * sc4[j].y + sh4[j].y, 0.f));
                o.y = pk2(fmaxf(v[2] * sc4[j].z + sh4[j].z, 0.f), fmaxf(v[3] * sc4[j].w + sh4[j].w, 0.f));
                *(uint2*)((u16*)Cv + zc + (long long)row * ldc + colb) = o;
            } else if (MODE == 2) {
                float4 o = {v[0] + sh4[j].x, v[1] + sh4[j].y, v[2] + sh4[j].z, v[3] + sh4[j].w};
                *(float4*)((float*)Cv + zc + (long long)row * ldc + colb) = o;
            } else {
                float4 o = {fmaxf(v[0] * rsc + rsh, 0.f), fmaxf(v[1] * rsc + rsh, 0.f),
                            fmaxf(v[2] * rsc + rsh, 0.f), fmaxf(v[3] * rsc + rsh, 0.f)};
                *(float4*)((float*)Cv + zc + (long long)row * ldc + colb) = o;
            }
        }
    }
}

// ============ Fused layer: q = LN2(qn1 + FFN(qn1)),  qn1 = LN1(q + oms@Wo + bo) ============
// One kernel per layer after sampling. Block = 64 rows, 512 threads (8 waves).
// - Wo GEMM: oms A-tile fully staged in LDS (AqO, 32KB), woF fragments from global.
// - LN1 output (qn1) kept in REGISTERS (oreg, exact fp32 values previously round-tripped
//   via q in HBM) and packed as bf16 (pk2, identical to old q16 values) into AqQ in
//   standard A-fragment layout -> FFN1's A operand. q fp32/q16 for qn1 never touch HBM.
// - FFN: round-4 verified structure (4 quarters of 256 H-cols, hF := AqO reuse),
//   FFN1 computed in two j-halves to cap register pressure.
// - LN2 residual = oreg (registers). Writes q + q16 once per layer.
// All accumulation orders and rounding points identical to the split kernels.
__global__ __launch_bounds__(512, 4) void fused_layer(
    const u16* __restrict__ oms, const u16* __restrict__ woF,
    const u16* __restrict__ w1F, const u16* __restrict__ w2F,
    const float* __restrict__ bo, const float* __restrict__ b1, const float* __restrict__ b2,
    float* __restrict__ q, u16* __restrict__ q16,
    const float* __restrict__ g1, const float* __restrict__ be1,
    const float* __restrict__ g2, const float* __restrict__ be2)
{
    __shared__ u16 AqO[16384];                // oms A-tile (32KB); reused as hF in FFN
    __shared__ u16 AqQ[16384];                // qn1 bf16 in A-frag layout (32KB)
    __shared__ float red_s[8][64], red_ss[8][64];
    const int tid = threadIdx.x;
    const int lane = tid & 63;
    const int w = tid >> 6;
    const int quad = lane >> 4, r = lane & 15;
    const int m0 = blockIdx.x << 6;

    // stage oms tile (64x256): 2048 16B units, 4/thread (swizzled chunks)
    const u16* Ab = oms + (long long)m0 * DM;
#pragma unroll
    for (int i = 0; i < 4; ++i) {
        int u = tid + i * 512;
        int ks = u >> 8, v = u & 255;
        int m = v >> 2, c = (v & 3) ^ ((m >> 1) & 3);
        __builtin_amdgcn_global_load_lds((const __attribute__((address_space(1))) void*)(Ab + (long long)m * DM + ks * 32 + c * 8),
                                         (__attribute__((address_space(3))) void*)(AqO + u * 8), 16, 0, 0);
    }

    int aoff[4];
#pragma unroll
    for (int t = 0; t < 4; ++t) {
        int m = t * 16 + r;
        aoff[t] = (m * 4 + (quad ^ ((m >> 1) & 3))) * 8;
    }

    f32x4 acc[4][2];
#pragma unroll
    for (int i = 0; i < 4; ++i)
#pragma unroll
        for (int j = 0; j < 2; ++j) acc[i][j] = (f32x4){0.f, 0.f, 0.f, 0.f};

    __syncthreads();

    // ======== Wo GEMM: acc = oms @ Wo^T (wave w -> cols [32w, 32w+32)) ========
#pragma unroll
    for (int ks = 0; ks < 8; ++ks) {
        const u16* bp = woF + ((size_t)(ks * 16 + 2 * w) * 64 + lane) * 8;
        bf16x8 bf0 = *(const bf16x8*)bp;
        bf16x8 bf1 = *(const bf16x8*)(bp + 512);
        bf16x8 af[4];
#pragma unroll
        for (int t = 0; t < 4; ++t) af[t] = *(const bf16x8*)(AqO + ks * 2048 + aoff[t]);
#pragma unroll
        for (int i = 0; i < 4; ++i) {
            acc[i][0] = __builtin_amdgcn_mfma_f32_16x16x32_bf16(bf0, af[i], acc[i][0], 0, 0, 0);
            acc[i][1] = __builtin_amdgcn_mfma_f32_16x16x32_bf16(bf1, af[i], acc[i][1], 0, 0, 0);
        }
    }

    // ======== LN1: bias bo + residual q, reduce over 256 cols ========
    float4 sh2[2];
#pragma unroll
    for (int j = 0; j < 2; ++j)
        sh2[j] = *(const float4*)&bo[w * 32 + j * 16 + quad * 4];

    float s_[4] = {0.f, 0.f, 0.f, 0.f}, ss_[4] = {0.f, 0.f, 0.f, 0.f};
#pragma unroll
    for (int i = 0; i < 4; ++i) {
        const int row = m0 + i * 16 + r;
#pragma unroll
        for (int j = 0; j < 2; ++j) {
            const int colb = w * 32 + j * 16 + quad * 4;
            float4 qo = *(const float4*)&q[(size_t)row * DM + colb];
            acc[i][j][0] += sh2[j].x + qo.x;
            acc[i][j][1] += sh2[j].y + qo.y;
            acc[i][j][2] += sh2[j].z + qo.z;
            acc[i][j][3] += sh2[j].w + qo.w;
#pragma unroll
            for (int e = 0; e < 4; ++e) {
                s_[i] += acc[i][j][e];
                ss_[i] += acc[i][j][e] * acc[i][j][e];
            }
        }
    }
#pragma unroll
    for (int i = 0; i < 4; ++i) {
        s_[i] += __shfl_xor(s_[i], 16);  ss_[i] += __shfl_xor(ss_[i], 16);
        s_[i] += __shfl_xor(s_[i], 32);  ss_[i] += __shfl_xor(ss_[i], 32);
    }
    if (quad == 0) {
#pragma unroll
        for (int i = 0; i < 4; ++i) {
            red_s[w][i * 16 + r] = s_[i];
            red_ss[w][i * 16 + r] = ss_[i];
        }
    }
    __syncthreads();

    float mean[4], rstd[4];
#pragma unroll
    for (int i = 0; i < 4; ++i) {
        float S = 0.f, SS = 0.f;
#pragma unroll
        for (int w2 = 0; w2 < 8; ++w2) { S += red_s[w2][i * 16 + r]; SS += red_ss[w2][i * 16 + r]; }
        mean[i] = S * (1.0f / 256.0f);
        rstd[i] = rsqrtf(SS * (1.0f / 256.0f) - mean[i] * mean[i] + EPSV);
    }

    // qn1 = LN1 out: keep fp32 in oreg, pack bf16 into AqQ (A-frag layout, ks-slice = w).
    // Mapping (derived & element-checked): value at (m=i*16+r, kk=j*16+quad*4+e2) lives at
    // AqQ[w*2048 + (m*4 + ((j*2+(quad>>1)) ^ ((r>>1)&3)))*8 + (quad&1)*4 + e2].
    f32x4 oreg[4][2];
    {
        float4 g4[2], bt4[2];
#pragma unroll
        for (int j = 0; j < 2; ++j) {
            int colb = w * 32 + j * 16 + quad * 4;
            g4[j] = *(const float4*)&g1[colb];
            bt4[j] = *(const float4*)&be1[colb];
        }
#pragma unroll
        for (int i = 0; i < 4; ++i) {
            const int mm = i * 16 + r;
#pragma unroll
            for (int j = 0; j < 2; ++j) {
                float o0 = (acc[i][j][0] - mean[i]) * rstd[i] * g4[j].x + bt4[j].x;
                float o1 = (acc[i][j][1] - mean[i]) * rstd[i] * g4[j].y + bt4[j].y;
                float o2 = (acc[i][j][2] - mean[i]) * rstd[i] * g4[j].z + bt4[j].z;
                float o3 = (acc[i][j][3] - mean[i]) * rstd[i] * g4[j].w + bt4[j].w;
                oreg[i][j] = (f32x4){o0, o1, o2, o3};
                const int pp = (j * 2 + (quad >> 1)) ^ ((r >> 1) & 3);
                *(uint2*)(AqQ + w * 2048 + (mm * 4 + pp) * 8 + (quad & 1) * 4) =
                    make_uint2(pk2(o0, o1), pk2(o2, o3));
            }
        }
    }
    __syncthreads();   // AqQ complete; all AqO (oms) reads + red_s reads done

    // ======== FFN: 4 quarters of 256 H-cols, hF := AqO ========
    f32x4 acc2[4][2];
#pragma unroll
    for (int i = 0; i < 4; ++i)
#pragma unroll
        for (int j = 0; j < 2; ++j) acc2[i][j] = (f32x4){0.f, 0.f, 0.f, 0.f};

    for (int qq = 0; qq < 4; ++qq) {
        if (qq) __syncthreads();     // prev quarter's phase2 done reading AqO
        // phase 1 in two j-halves (caps register pressure); pack each half into AqO
#pragma unroll
        for (int j = 0; j < 2; ++j) {
            f32x4 a1[4];
#pragma unroll
            for (int i = 0; i < 4; ++i) a1[i] = (f32x4){0.f, 0.f, 0.f, 0.f};
            __builtin_amdgcn_s_setprio(1);
#pragma unroll
            for (int ks = 0; ks < 8; ++ks) {
                const u16* bp = w1F + ((size_t)(ks * 64 + qq * 16 + w * 2 + j) * 64 + lane) * 8;
                bf16x8 bf = *(const bf16x8*)bp;
                bf16x8 af[4];
#pragma unroll
                for (int t = 0; t < 4; ++t) af[t] = *(const bf16x8*)(AqQ + ks * 2048 + aoff[t]);
#pragma unroll
                for (int i = 0; i < 4; ++i)
                    a1[i] = __builtin_amdgcn_mfma_f32_16x16x32_bf16(bf, af[i], a1[i], 0, 0, 0);
            }
            __builtin_amdgcn_s_setprio(0);
            // pack: bias + relu + bf16 into hF (AqO), round-4 verified mapping
            const int cb = qq * 256 + w * 32 + j * 16 + quad * 4;
            const float4 b14 = *(const float4*)&b1[cb];
            const int lane2 = r | (((j * 2 + (quad >> 1)) & 3) << 4);
            const int eo = (quad & 1) * 4;
#pragma unroll
            for (int i = 0; i < 4; ++i) {
                f32x4 v = a1[i];
                uint2 o;
                o.x = pk2(fmaxf(v[0] + b14.x, 0.f), fmaxf(v[1] + b14.y, 0.f));
                o.y = pk2(fmaxf(v[2] + b14.z, 0.f), fmaxf(v[3] + b14.w, 0.f));
                *(uint2*)(AqO + ((w * 4 + i) * 64 + lane2) * 8 + eo) = o;
            }
        }
        __syncthreads();   // hF quarter complete

        // phase 2: acc2 += H_quarter @ W2[qq*256 .. +256, :]
        __builtin_amdgcn_s_setprio(1);
#pragma unroll
        for (int ks = 0; ks < 8; ++ks) {
            const u16* bp = w2F + ((size_t)((qq * 8 + ks) * 16 + w * 2) * 64 + lane) * 8;
            bf16x8 bf0 = *(const bf16x8*)bp;
            bf16x8 bf1 = *(const bf16x8*)(bp + 512);
            bf16x8 af[4];
#pragma unroll
            for (int t = 0; t < 4; ++t) af[t] = *(const bf16x8*)(AqO + ((ks * 4 + t) * 64 + lane) * 8);
#pragma unroll
            for (int i = 0; i < 4; ++i) {
                acc2[i][0] = __builtin_amdgcn_mfma_f32_16x16x32_bf16(bf0, af[i], acc2[i][0], 0, 0, 0);
                acc2[i][1] = __builtin_amdgcn_mfma_f32_16x16x32_bf16(bf1, af[i], acc2[i][1], 0, 0, 0);
            }
        }
        __builtin_amdgcn_s_setprio(0);
    }

    // ======== LN2: bias b2 + residual oreg (registers), write q + q16 ========
#pragma unroll
    for (int j = 0; j < 2; ++j)
        sh2[j] = *(const float4*)&b2[w * 32 + j * 16 + quad * 4];

#pragma unroll
    for (int i = 0; i < 4; ++i) { s_[i] = 0.f; ss_[i] = 0.f; }
#pragma unroll
    for (int i = 0; i < 4; ++i) {
#pragma unroll
        for (int j = 0; j < 2; ++j) {
            acc2[i][j][0] += sh2[j].x + oreg[i][j][0];
            acc2[i][j][1] += sh2[j].y + oreg[i][j][1];
            acc2[i][j][2] += sh2[j].z + oreg[i][j][2];
            acc2[i][j][3] += sh2[j].w + oreg[i][j][3];
#pragma unroll
            for (int e = 0; e < 4; ++e) {
                s_[i] += acc2[i][j][e];
                ss_[i] += acc2[i][j][e] * acc2[i][j][e];
            }
        }
    }
#pragma unroll
    for (int i = 0; i < 4; ++i) {
        s_[i] += __shfl_xor(s_[i], 16);  ss_[i] += __shfl_xor(ss_[i], 16);
        s_[i] += __shfl_xor(s_[i], 32);  ss_[i] += __shfl_xor(ss_[i], 32);
    }
    if (quad == 0) {
#pragma unroll
        for (int i = 0; i < 4; ++i) {
            red_s[w][i * 16 + r] = s_[i];
            red_ss[w][i * 16 + r] = ss_[i];
        }
    }
    __syncthreads();

#pragma unroll
    for (int i = 0; i < 4; ++i) {
        float S = 0.f, SS = 0.f;
#pragma unroll
        for (int w2 = 0; w2 < 8; ++w2) { S += red_s[w2][i * 16 + r]; SS += red_ss[w2][i * 16 + r]; }
        mean[i] = S * (1.0f / 256.0f);
        rstd[i] = rsqrtf(SS * (1.0f / 256.0f) - mean[i] * mean[i] + EPSV);
    }

    float4 g4[2], bt4[2];
#pragma unroll
    for (int j = 0; j < 2; ++j) {
        int colb = w * 32 + j * 16 + quad * 4;
        g4[j] = *(const float4*)&g2[colb];
        bt4[j] = *(const float4*)&be2[colb];
    }
#pragma unroll
    for (int i = 0; i < 4; ++i) {
        const int row = m0 + i * 16 + r;
#pragma unroll
        for (int j = 0; j < 2; ++j) {
            const int colb = w * 32 + j * 16 + quad * 4;
            float o0 = (acc2[i][j][0] - mean[i]) * rstd[i] * g4[j].x + bt4[j].x;
            float o1 = (acc2[i][j][1] - mean[i]) * rstd[i] * g4[j].y + bt4[j].y;
            float o2 = (acc2[i][j][2] - mean[i]) * rstd[i] * g4[j].z + bt4[j].z;
            float o3 = (acc2[i][j][3] - mean[i]) * rstd[i] * g4[j].w + bt4[j].w;
            *(float4*)&q[(size_t)row * DM + colb] = make_float4(o0, o1, o2, o3);
            *(uint2*)(q16 + (size_t)row * DM + colb) = make_uint2(pk2(o0, o1), pk2(o2, o3));
        }
    }
}

// ================= weight prep =================
__device__ __attribute__((noinline)) void tconv(const float* src, u16* dst, int K, int N, int tk, int tn)
{
    __shared__ float t[32][33];
    const int tx = threadIdx.x & 31, ty = threadIdx.x >> 5;
#pragma unroll
    for (int i = 0; i < 4; ++i)
        t[ty + i * 8][tx] = src[(size_t)(tk * 32 + ty + i * 8) * N + tn * 32 + tx];
    __syncthreads();
#pragma unroll
    for (int i = 0; i < 4; ++i)
        dst[(size_t)(tn * 32 + ty + i * 8) * K + tk * 32 + tx] = f2b(t[tx][ty + i * 8]);
}

__device__ __attribute__((noinline)) void tconv_oa(const float* Woff, const float* Wattn, u16* dst, int tk, int tn)
{
    __shared__ float t[32][33];
    const int tx = threadIdx.x & 31, ty = threadIdx.x >> 5;
#pragma unroll
    for (int i = 0; i < 4; ++i) {
        int k = tk * 32 + ty + i * 8, n = tn * 32 + tx;
        float v = (n < 64) ? Woff[k * 64 + n] : ((n < 96) ? Wattn[k * 32 + n - 64] : 0.f);
        t[ty + i * 8][tx] = v;
    }
    __syncthreads();
#pragma unroll
    for (int i = 0; i < 4; ++i)
        dst[(size_t)(tn * 32 + ty + i * 8) * 256 + tk * 32 + tx] = f2b(t[tx][ty + i * 8]);
}

// W (K,N) fp32 -> fragment-ordered bf16:
// F[ks][nt][lane][e] = W[ks*32 + (lane>>4)*8 + e][nt*16 + (lane&15)]
__device__ __attribute__((noinline)) void frag_prep(const float* W, u16* dst, int ks, int nc, int N)
{
    __shared__ float t[32][256];
    const int tid = threadIdx.x;
#pragma unroll
    for (int kk = 0; kk < 32; ++kk)
        t[kk][tid] = W[(size_t)(ks * 32 + kk) * N + nc * 256 + tid];
    __syncthreads();
    const int NT16 = N >> 4;
#pragma unroll
    for (int i = 0; i < 4; ++i) {
        int idx = tid + i * 256;          // local nt*64 + lane
        int nt = idx >> 6, l = idx & 63;
        int n = nt * 16 + (l & 15);
        int kb = (l >> 4) * 8;
        u16 o[8];
#pragma unroll
        for (int e = 0; e < 8; ++e) o[e] = f2b(t[kb + e][n]);
        *(uint4*)(dst + ((size_t)(ks * NT16 + nc * 16 + nt) * 64 + l) * 8) = *(const uint4*)o;
    }
}

__global__ __launch_bounds__(256) void prep_weights(
    const float* __restrict__ Wval, const float* __restrict__ Wo,
    const float* __restrict__ W1, const float* __restrict__ W2,
    const float* __restrict__ Woff, const float* __restrict__ Wattn,
    const float* __restrict__ boff, const float* __restrict__ battn,
    const float* __restrict__ W_in, const float* __restrict__ W_out,
    const float* __restrict__ bn1g, const float* __restrict__ bn1b,
    const float* __restrict__ bn1m, const float* __restrict__ bn1v,
    const float* __restrict__ bn2g, const float* __restrict__ bn2b,
    const float* __restrict__ bn2m, const float* __restrict__ bn2v,
    u16* __restrict__ wvalT, u16* __restrict__ woF, u16* __restrict__ w1F,
    u16* __restrict__ w2F, u16* __restrict__ woaT,
    u16* __restrict__ winC, u16* __restrict__ woutC,
    float* __restrict__ bn1sc, float* __restrict__ bn1sh,
    float* __restrict__ bn2sc, float* __restrict__ bn2sh, float* __restrict__ boa)
{
    int bid = blockIdx.x;
    if (bid < 128) {                          // Wval transpose: 2 layers x 64
        int l = bid >> 6, r2 = bid & 63;
        tconv(Wval + l * 65536, wvalT + l * 65536, 256, 256, r2 & 7, r2 >> 3);
    } else if (bid < 192) {                   // Woff|Wattn transpose: 2 x 32
        int i2 = bid - 128, l = i2 >> 5, r2 = i2 & 31;
        tconv_oa(Woff + l * 16384, Wattn + l * 8192, woaT + l * 32768, r2 & 7, r2 >> 3);
    } else if (bid < 208) {                   // Wo fragments: 2 x 8 ks
        int i2 = bid - 192;
        frag_prep(Wo + (i2 >> 3) * 65536, woF + (i2 >> 3) * 65536, i2 & 7, 0, 256);
    } else if (bid < 272) {                   // W1 fragments: 2 x (8 ks x 4 nc)
        int i2 = bid - 208, l = i2 >> 5, r2 = i2 & 31;
        frag_prep(W1 + l * 262144, w1F + l * 262144, r2 >> 2, r2 & 3, 1024);
    } else if (bid < 336) {                   // W2 fragments: 2 x 32 ks
        int i2 = bid - 272;
        frag_prep(W2 + (i2 >> 5) * 262144, w2F + (i2 >> 5) * 262144, i2 & 31, 0, 256);
    } else if (bid < 368) {
        int g2 = bid - 336, base = g2 * 4096, t = threadIdx.x;
#pragma unroll
        for (int k = 0; k < 16; ++k) winC[base + k * 256 + t] = f2b(W_in[base + k * 256 + t]);
    } else if (bid < 400) {
        int g2 = bid - 368, base = g2 * 4096, t = threadIdx.x;
#pragma unroll
        for (int k = 0; k < 16; ++k) woutC[base + k * 256 + t] = f2b(W_out[base + k * 256 + t]);
    } else {
        int t = threadIdx.x;
        { float s = bn1g[t] * rsqrtf(bn1v[t] + EPSV); bn1sc[t] = s; bn1sh[t] = bn1b[t] - bn1m[t] * s; }
        for (int c = 0; c < 2; ++c) {
            int i = c * 256 + t;
            float s = bn2g[i] * rsqrtf(bn2v[i] + EPSV);
            bn2sc[i] = s; bn2sh[i] = bn2b[i] - bn2m[i] * s;
        }
        if (t < 128)
            for (int l = 0; l < 2; ++l)
                boa[l * 128 + t] = (t < 64) ? boff[l * 64 + t]
                                 : ((t < 96) ? battn[l * 32 + t - 64] : 0.f);
    }
}

// ================= x (B,C,HW) -> xT (B,HW,C) bf16 =================
__global__ __launch_bounds__(256) void transpose_x(const float* __restrict__ x, u16* __restrict__ xT)
{
    __shared__ float t[64][65];
    const int b = blockIdx.z, p0 = blockIdx.y << 6, c0 = blockIdx.x << 6;
    const int tx = threadIdx.x & 63, ty = threadIdx.x >> 6;
    const float* xb = x + ((size_t)b * CINC + c0) * HWTOT + p0;
#pragma unroll
    for (int i = 0; i < 16; ++i)
        t[ty + i * 4][tx] = xb[(size_t)(ty + i * 4) * HWTOT + tx];
    __syncthreads();
    u16* xo = xT + ((size_t)b * HWTOT + p0) * CINC + c0;
#pragma unroll
    for (int i = 0; i < 16; ++i)
        xo[(size_t)(ty + i * 4) * CINC + tx] = f2b(t[tx][ty + i * 4]);
}

// ================= deformable sampling: 8 queries/block, 32 lanes/query =================
struct IW { int eo; float w; };

__global__ __launch_bounds__(256) void sample_kernel(
    const u16* __restrict__ val,      // (B*HW, D) bf16
    const float* __restrict__ oa,     // (B*HW, 128): [0..63]=off, [64..95]=attn logits
    u16* __restrict__ oms)            // (B*HW, D) bf16
{
    __shared__ float s_oa[8][96];
    __shared__ IW s_iw[8][32][5];
    const int t = threadIdx.x;
    const int bq0 = blockIdx.x << 3;
    const int b = blockIdx.x >> 9;

    {
        int qi = t >> 5, j = t & 31;
        if (j < 24)
            ((float4*)s_oa[qi])[j] = ((const float4*)oa)[((size_t)(bq0 + qi)) * 32 + j];
    }
    __syncthreads();

    {
        const int qi = t >> 5, hp = t & 31, h = hp >> 2, p = hp & 3;
        const float* so = s_oa[qi];
        float l0 = so[64 + h * 4 + 0], l1 = so[64 + h * 4 + 1];
        float l2 = so[64 + h * 4 + 2], l3 = so[64 + h * 4 + 3];
        float mx = fmaxf(fmaxf(l0, l1), fmaxf(l2, l3));
        float e0 = __expf(l0 - mx), e1 = __expf(l1 - mx), e2 = __expf(l2 - mx), e3 = __expf(l3 - mx);
        float inv = 1.0f / (e0 + e1 + e2 + e3);
        float aw = ((p == 0) ? e0 : (p == 1) ? e1 : (p == 2) ? e2 : e3) * inv;
        const int bq = bq0 + qi;
        float gx = (float)(bq & 63) + so[hp * 2 + 0];
        float gy = (float)((bq >> 6) & 63) + so[hp * 2 + 1];
        float x0f = floorf(gx), y0f = floorf(gy);
        float wx = gx - x0f, wy = gy - y0f;
        int x0 = (int)x0f, y0 = (int)y0f;
#pragma unroll
        for (int c = 0; c < 4; ++c) {
            int xi = x0 + (c & 1), yi = y0 + (c >> 1);
            bool ok = (xi >= 0) && (xi < 64) && (yi >= 0) && (yi < 64);
            float wgt = ((c & 1) ? wx : 1.0f - wx) * ((c >> 1) ? wy : 1.0f - wy);
            s_iw[qi][hp][c].eo = ok ? ((yi * 64 + xi) << 8) : 0;
            s_iw[qi][hp][c].w = ok ? aw * wgt : 0.f;
        }
    }
    __syncthreads();

    {
        const int qi = t >> 5, l = t & 31, h = l >> 2, cc = l & 3;
        const u16* base = val + ((size_t)b << 20) + (h << 5) + (cc << 3);
        float a[8] = {0.f, 0.f, 0.f, 0.f, 0.f, 0.f, 0.f, 0.f};
#pragma unroll
        for (int p = 0; p < 4; ++p)
#pragma unroll
            for (int c = 0; c < 4; ++c) {
                IW iw = s_iw[qi][(h << 2) + p][c];
                uint4 v = *(const uint4*)(base + iw.eo);
                a[0] += iw.w * blo(v.x); a[1] += iw.w * bhi(v.x);
                a[2] += iw.w * blo(v.y); a[3] += iw.w * bhi(v.y);
                a[4] += iw.w * blo(v.z); a[5] += iw.w * bhi(v.z);
                a[6] += iw.w * blo(v.w); a[7] += iw.w * bhi(v.w);
            }
        uint4 o;
        o.x = (uint32_t)f2b(a[0]) | ((uint32_t)f2b(a[1]) << 16);
        o.y = (uint32_t)f2b(a[2]) | ((uint32_t)f2b(a[3]) << 16);
        o.z = (uint32_t)f2b(a[4]) | ((uint32_t)f2b(a[5]) << 16);
        o.w = (uint32_t)f2b(a[6]) | ((uint32_t)f2b(a[7]) << 16);
        *(uint4*)(oms + (size_t)(bq0 + qi) * 256 + (h << 5) + (cc << 3)) = o;
    }
}

__global__ __launch_bounds__(256) void bcast_q(
    const float4* __restrict__ qe, float4* __restrict__ q, u16* __restrict__ q16)
{
    const int i = blockIdx.x * 256 + threadIdx.x;
    float4 v = qe[i];
    uint2 pk = make_uint2(pk2(v.x, v.y), pk2(v.z, v.w));
#pragma unroll
    for (int b = 0; b < BBATCH; ++b) {
        q[(size_t)b * 262144 + i] = v;
        ((uint2*)q16)[(size_t)b * 262144 + i] = pk;
    }
}

extern "C" void kernel_launch(void* const* d_in, const int* in_sizes, int n_in,
                              void* d_out, int out_size, void* d_ws, size_t ws_size,
                              hipStream_t stream)
{
    (void)in_sizes; (void)n_in; (void)out_size; (void)ws_size;
    const float* x     = (const float*)d_in[0];
    const float* W_in  = (const float*)d_in[1];
    const float* bn1_g = (const float*)d_in[2];
    const float* bn1_b = (const float*)d_in[3];
    const float* bn1_m = (const float*)d_in[4];
    const float* bn1_v = (const float*)d_in[5];
    const float* qe    = (const float*)d_in[6];
    const float* Woff  = (const float*)d_in[7];
    const float* boff  = (const float*)d_in[8];
    const float* Wattn = (const float*)d_in[9];
    const float* battn = (const float*)d_in[10];
    const float* Wval  = (const float*)d_in[11];
    const float* bval  = (const float*)d_in[12];
    const float* Wo    = (const float*)d_in[13];
    const float* bo    = (const float*)d_in[14];
    const float* ln1_g = (const float*)d_in[15];
    const float* ln1_b = (const float*)d_in[16];
    const float* W1    = (const float*)d_in[17];
    const float* b1    = (const float*)d_in[18];
    const float* W2    = (const float*)d_in[19];
    const float* b2    = (const float*)d_in[20];
    const float* ln2_g = (const float*)d_in[21];
    const float* ln2_b = (const float*)d_in[22];
    const float* W_out = (const float*)d_in[23];
    const float* bn2_g = (const float*)d_in[24];
    const float* bn2_b = (const float*)d_in[25];
    const float* bn2_m = (const float*)d_in[26];
    const float* bn2_v = (const float*)d_in[27];
    float* out = (float*)d_out;

    char* w = (char*)d_ws;
    // pool (time-disjoint): xT (33.5MB) | val16+offat+oms16 (50MB)
    char* pool    = w;          w += 67108864;
    float* q      = (float*)w;  w += 33554432;
    u16*  q16     = (u16*)w;    w += 16777216;
    u16*  src16   = (u16*)w;    w += 16777216;
    u16*  wvalT   = (u16*)w;    w += 262144;
    u16*  woF     = (u16*)w;    w += 262144;
    u16*  w1F     = (u16*)w;    w += 1048576;
    u16*  w2F     = (u16*)w;    w += 1048576;
    u16*  woaT    = (u16*)w;    w += 131072;
    u16*  winC    = (u16*)w;    w += 262144;
    u16*  woutC   = (u16*)w;    w += 262144;
    float* bn1sc  = (float*)w;  w += 1024;
    float* bn1sh  = (float*)w;  w += 1024;
    float* bn2sc  = (float*)w;  w += 2048;
    float* bn2sh  = (float*)w;  w += 2048;
    float* boa    = (float*)w;  w += 1024;

    u16*  xT     = (u16*)pool;
    u16*  val16  = (u16*)pool;
    float* offat = (float*)(pool + 16777216);
    u16*  oms16  = (u16*)(pool + 33554432);

    prep_weights<<<dim3(401), 256, 0, stream>>>(
        Wval, Wo, W1, W2, Woff, Wattn, boff, battn, W_in, W_out,
        bn1_g, bn1_b, bn1_m, bn1_v, bn2_g, bn2_b, bn2_m, bn2_v,
        wvalT, woF, w1F, w2F, woaT, winC, woutC, bn1sc, bn1sh, bn2sc, bn2sh, boa);
    transpose_x<<<dim3(CINC / 64, HWTOT / 64, BBATCH), 256, 0, stream>>>(x, xT);
    bcast_q<<<dim3(1024), 256, 0, stream>>>((const float4*)qe, (float4*)q, q16);

    // proj_in: (32768,512)@(256,512)^T -> bf16 src
    mfma_gemm<1><<<dim3(2, 256, 1), 256, 0, stream>>>(
        xT, winC, bn1sc, bn1sh, src16, 32768, 256, 512, 256, 0, 0, 0, 1, 1);

    for (int l = 0; l < LYR; ++l) {
        mfma_gemm<0><<<dim3(2, 256, 1), 256, 0, stream>>>(
            src16, wvalT + l * 65536, nullptr, bval + l * 256, val16,
            32768, 256, 256, 256, 0, 0, 0, 1, 1);
        mfma_gemm<2><<<dim3(1, 256, 1), 256, 0, stream>>>(
            q16, woaT + l * 32768, nullptr, boa + l * 128, offat,
            32768, 128, 256, 128, 0, 0, 0, 1, 0);
        sample_kernel<<<dim3(4096), 256, 0, stream>>>(val16, offat, oms16);
        // Wo GEMM + LN1 + FFN + LN2, qn1 and H stay on-chip
        fused_layer<<<dim3(512), 512, 0, stream>>>(
            oms16, woF + l * 65536, w1F + l * 262144, w2F + l * 262144,
            bo + l * 256, b1 + l * 1024, b2 + l * 256, q, q16,
            ln1_g + l * 256, ln1_b + l * 256, ln2_g + l * 256, ln2_b + l * 256);
    }

    // proj_out: per-batch (512,256)@(4096,256)^T -> fp32 out (B,C,HW)
    mfma_gemm<3><<<dim3(32, 4, BBATCH), 256, 0, stream>>>(
        woutC, q16, bn2sc, bn2sh, out, 512, 4096, 256, 4096,
        0, (long long)HWTOT * DM, (long long)CINC * HWTOT, 0, 0);
}

// Round 8
// 451.174 us; speedup vs baseline: 1.2728x; 1.0225x over previous
//
#include <hip/hip_runtime.h>
#include <cstdint>

#define LYR 2
#define DM  256
#define DFFN 1024
#define CINC 512
#define BBATCH 8
#define HWTOT 4096
#define EPSV 1e-5f

using u16 = unsigned short;
typedef __attribute__((ext_vector_type(8))) short bf16x8;
typedef __attribute__((ext_vector_type(4))) float f32x4;

__device__ inline u16 f2b(float v) {
    union { float f; uint32_t u; } x; x.f = v;
    uint32_t r = x.u + 0x7fffu + ((x.u >> 16) & 1u);
    return (u16)(r >> 16);
}
__device__ inline uint32_t pk2(float a, float b) {
    return (uint32_t)f2b(a) | ((uint32_t)f2b(b) << 16);
}
__device__ inline float blo(uint32_t d) {
    union { uint32_t i; float f; } x; x.i = d << 16; return x.f;
}
__device__ inline float bhi(uint32_t d) {
    union { uint32_t i; float f; } x; x.i = d & 0xffff0000u; return x.f;
}

// ============ bf16 MFMA GEMM: C = A(M,K) @ Bt(N,K)^T, 128x128 tile, BK=32 ============
// Counted-vmcnt pipeline: 4 LDS buffers, 2-group-deep prefetch, raw s_barrier.
// MODE 0: bf16 out, x+shift[col]                   (val)
// MODE 1: bf16 out, relu(x*scale[col]+shift[col])  (proj_in)
// MODE 2: fp32 out, x+shift[col]                   (offattn)
// MODE 3: fp32 out, relu(x*scale[row]+shift[row])  (proj_out)
template<int MODE>
__global__ __launch_bounds__(256) void mfma_gemm(
    const u16* __restrict__ A, const u16* __restrict__ Bt,
    const float* __restrict__ scale, const float* __restrict__ shift,
    void* __restrict__ Cv, int M, int N, int K, int ldc,
    long long a_zs, long long b_zs, long long c_zs, int swz, int gxlog)
{
    __shared__ u16 As[4][4096];
    __shared__ u16 Bs[4][4096];
    const int tid = threadIdx.x;
    const int lane = tid & 63;
    const int wid = tid >> 6;
    const int wm = (wid & 1) << 6, wn = (wid >> 1) << 6;
    const int quad = lane >> 4, r = lane & 15;

    int bx = blockIdx.x, by = blockIdx.y;
    if (swz) {  // XCD-band swizzle: XCD k owns a contiguous band of row-tiles
        int linear = by * gridDim.x + bx;
        int xcd = linear & 7;
        int s = linear >> 3;
        bx = s & (gridDim.x - 1);
        by = xcd * (gridDim.y >> 3) + (s >> gxlog);
    }
    const int m0 = by << 7, n0 = bx << 7;
    const u16* Ab = A + (long long)blockIdx.z * a_zs + (long long)m0 * K;
    const u16* Bb = Bt + (long long)blockIdx.z * b_zs + (long long)n0 * K;

    // staging (BK=32): unit u (16B): row m=u>>2, pos p=u&3, chunk c=p^((m>>1)&3)
    const int u0 = tid, u1 = tid + 256;
    const int mu0 = u0 >> 2, cu0 = (u0 & 3) ^ ((mu0 >> 1) & 3);
    const int mu1 = u1 >> 2, cu1 = (u1 & 3) ^ ((mu1 >> 1) & 3);
    const long long ga0 = (long long)mu0 * K + cu0 * 8;
    const long long ga1 = (long long)mu1 * K + cu1 * 8;

    int aoff[4], boff[4];
#pragma unroll
    for (int t = 0; t < 4; ++t) {
        int m = wm + t * 16 + r;
        aoff[t] = (m * 4 + (quad ^ ((m >> 1) & 3))) * 8;
        int n = wn + t * 16 + r;
        boff[t] = (n * 4 + (quad ^ ((n >> 1) & 3))) * 8;
    }

    f32x4 acc[4][4];
#pragma unroll
    for (int i = 0; i < 4; ++i)
#pragma unroll
        for (int j = 0; j < 4; ++j) acc[i][j] = (f32x4){0.f, 0.f, 0.f, 0.f};

    const int NT = K >> 5;   // >= 3 for all call sites (8 or 16)

#define GSTAGE(g, b) do {                                                                       \
    const long long kk = (long long)(g) << 5;                                                   \
    __builtin_amdgcn_global_load_lds((const __attribute__((address_space(1))) void*)(Ab + ga0 + kk), \
        (__attribute__((address_space(3))) void*)(&As[b][u0 * 8]), 16, 0, 0);                   \
    __builtin_amdgcn_global_load_lds((const __attribute__((address_space(1))) void*)(Ab + ga1 + kk), \
        (__attribute__((address_space(3))) void*)(&As[b][u1 * 8]), 16, 0, 0);                   \
    __builtin_amdgcn_global_load_lds((const __attribute__((address_space(1))) void*)(Bb + ga0 + kk), \
        (__attribute__((address_space(3))) void*)(&Bs[b][u0 * 8]), 16, 0, 0);                   \
    __builtin_amdgcn_global_load_lds((const __attribute__((address_space(1))) void*)(Bb + ga1 + kk), \
        (__attribute__((address_space(3))) void*)(&Bs[b][u1 * 8]), 16, 0, 0);                   \
} while (0)

    // prologue: stage tiles 0,1,2 (12 loads outstanding)
    GSTAGE(0, 0);
    GSTAGE(1, 1);
    GSTAGE(2, 2);

    for (int t = 0; t < NT; ++t) {
        // wait for tile t's group; keep up to 2 future groups (8 loads) in flight
        if (t < NT - 2)       asm volatile("s_waitcnt vmcnt(8)" ::: "memory");
        else if (t == NT - 2) asm volatile("s_waitcnt vmcnt(4)" ::: "memory");
        else                  asm volatile("s_waitcnt vmcnt(0)" ::: "memory");
        __builtin_amdgcn_s_barrier();
        __builtin_amdgcn_sched_barrier(0);   // pin: no motion across the barrier
        if (t + 3 < NT) GSTAGE(t + 3, (t + 3) & 3);
        const u16* Ap = As[t & 3];
        const u16* Bp = Bs[t & 3];
        bf16x8 af[4], bf[4];
#pragma unroll
        for (int tt = 0; tt < 4; ++tt) af[tt] = *(const bf16x8*)(Ap + aoff[tt]);
#pragma unroll
        for (int tt = 0; tt < 4; ++tt) bf[tt] = *(const bf16x8*)(Bp + boff[tt]);
#pragma unroll
        for (int i = 0; i < 4; ++i)
#pragma unroll
            for (int j = 0; j < 4; ++j)
                acc[i][j] = __builtin_amdgcn_mfma_f32_16x16x32_bf16(bf[j], af[i], acc[i][j], 0, 0, 0);
    }
#undef GSTAGE

    const long long zc = (long long)blockIdx.z * c_zs;
    float4 sh4[4], sc4[4];
    if (MODE != 3) {
#pragma unroll
        for (int j = 0; j < 4; ++j) {
            int colb = n0 + wn + j * 16 + quad * 4;
            sh4[j] = *(const float4*)&shift[colb];
            if (MODE == 1) sc4[j] = *(const float4*)&scale[colb];
        }
    }
#pragma unroll
    for (int i = 0; i < 4; ++i) {
        const int row = m0 + wm + i * 16 + r;
        float rsc = 0.f, rsh = 0.f;
        if (MODE == 3) { rsc = scale[row]; rsh = shift[row]; }
#pragma unroll
        for (int j = 0; j < 4; ++j) {
            const int colb = n0 + wn + j * 16 + quad * 4;
            f32x4 v = acc[i][j];
            if (MODE == 0) {
                uint2 o;
                o.x = pk2(v[0] + sh4[j].x, v[1] + sh4[j].y);
                o.y = pk2(v[2] + sh4[j].z, v[3] + sh4[j].w);
                *(uint2*)((u16*)Cv + zc + (long long)row * ldc + colb) = o;
            } else if (MODE == 1) {
                uint2 o;
                o.x = pk2(fmaxf(v[0] * sc4[j].x + sh4[j].x, 0.f), fmaxf(v[1] * sc4[j].y + sh4[j].y, 0.f));
                o.y = pk2(fmaxf(v[2] * sc4[j].z + sh4[j].z, 0.f), fmaxf(v[3] * sc4[j].w + sh4[j].w, 0.f));
                *(uint2*)((u16*)Cv + zc + (long long)row * ldc + colb) = o;
            } else if (MODE == 2) {
                float4 o = {v[0] + sh4[j].x, v[1] + sh4[j].y, v[2] + sh4[j].z, v[3] + sh4[j].w};
                *(float4*)((float*)Cv + zc + (long long)row * ldc + colb) = o;
            } else {
                float4 o = {fmaxf(v[0] * rsc + rsh, 0.f), fmaxf(v[1] * rsc + rsh, 0.f),
                            fmaxf(v[2] * rsc + rsh, 0.f), fmaxf(v[3] * rsc + rsh, 0.f)};
                *(float4*)((float*)Cv + zc + (long long)row * ldc + colb) = o;
            }
        }
    }
}

// ============ Fused layer: q = LN2(qn1 + FFN(qn1)),  qn1 = LN1(q + oms@Wo + bo) ============
// WRITEQ: write q fp32 (needed only when a later layer reads the residual).
// OA: compute next layer's offset/attn logits offat = qn2 @ Woa + boa in the tail
//     (qn2 repacked from registers into A-frag LDS; identical FP order to the
//     standalone offattn GEMM: same ks accumulation order, same f2b operands).
template<int WRITEQ, int OA>
__global__ __launch_bounds__(512, 4) void fused_layer(
    const u16* __restrict__ oms, const u16* __restrict__ woF,
    const u16* __restrict__ w1F, const u16* __restrict__ w2F,
    const u16* __restrict__ woaF,
    const float* __restrict__ bo, const float* __restrict__ b1, const float* __restrict__ b2,
    const float* __restrict__ boa1,
    float* __restrict__ q, u16* __restrict__ q16, float* __restrict__ offat,
    const float* __restrict__ g1, const float* __restrict__ be1,
    const float* __restrict__ g2, const float* __restrict__ be2)
{
    __shared__ u16 AqO[16384];                // oms A-tile (32KB); reused as hF in FFN
    __shared__ u16 AqQ[16384];                // qn1 (then qn2) bf16 in A-frag layout
    __shared__ float red_s[8][64], red_ss[8][64];
    const int tid = threadIdx.x;
    const int lane = tid & 63;
    const int w = tid >> 6;
    const int quad = lane >> 4, r = lane & 15;
    const int m0 = blockIdx.x << 6;

    // stage oms tile (64x256): 2048 16B units, 4/thread (swizzled chunks)
    const u16* Ab = oms + (long long)m0 * DM;
#pragma unroll
    for (int i = 0; i < 4; ++i) {
        int u = tid + i * 512;
        int ks = u >> 8, v = u & 255;
        int m = v >> 2, c = (v & 3) ^ ((m >> 1) & 3);
        __builtin_amdgcn_global_load_lds((const __attribute__((address_space(1))) void*)(Ab + (long long)m * DM + ks * 32 + c * 8),
                                         (__attribute__((address_space(3))) void*)(AqO + u * 8), 16, 0, 0);
    }

    int aoff[4];
#pragma unroll
    for (int t = 0; t < 4; ++t) {
        int m = t * 16 + r;
        aoff[t] = (m * 4 + (quad ^ ((m >> 1) & 3))) * 8;
    }

    f32x4 acc[4][2];
#pragma unroll
    for (int i = 0; i < 4; ++i)
#pragma unroll
        for (int j = 0; j < 2; ++j) acc[i][j] = (f32x4){0.f, 0.f, 0.f, 0.f};

    __syncthreads();

    // ======== Wo GEMM: acc = oms @ Wo^T (wave w -> cols [32w, 32w+32)) ========
#pragma unroll
    for (int ks = 0; ks < 8; ++ks) {
        const u16* bp = woF + ((size_t)(ks * 16 + 2 * w) * 64 + lane) * 8;
        bf16x8 bf0 = *(const bf16x8*)bp;
        bf16x8 bf1 = *(const bf16x8*)(bp + 512);
        bf16x8 af[4];
#pragma unroll
        for (int t = 0; t < 4; ++t) af[t] = *(const bf16x8*)(AqO + ks * 2048 + aoff[t]);
#pragma unroll
        for (int i = 0; i < 4; ++i) {
            acc[i][0] = __builtin_amdgcn_mfma_f32_16x16x32_bf16(bf0, af[i], acc[i][0], 0, 0, 0);
            acc[i][1] = __builtin_amdgcn_mfma_f32_16x16x32_bf16(bf1, af[i], acc[i][1], 0, 0, 0);
        }
    }

    // ======== LN1: bias bo + residual q, reduce over 256 cols ========
    float4 sh2[2];
#pragma unroll
    for (int j = 0; j < 2; ++j)
        sh2[j] = *(const float4*)&bo[w * 32 + j * 16 + quad * 4];

    float s_[4] = {0.f, 0.f, 0.f, 0.f}, ss_[4] = {0.f, 0.f, 0.f, 0.f};
#pragma unroll
    for (int i = 0; i < 4; ++i) {
        const int row = m0 + i * 16 + r;
#pragma unroll
        for (int j = 0; j < 2; ++j) {
            const int colb = w * 32 + j * 16 + quad * 4;
            float4 qo = *(const float4*)&q[(size_t)row * DM + colb];
            acc[i][j][0] += sh2[j].x + qo.x;
            acc[i][j][1] += sh2[j].y + qo.y;
            acc[i][j][2] += sh2[j].z + qo.z;
            acc[i][j][3] += sh2[j].w + qo.w;
#pragma unroll
            for (int e = 0; e < 4; ++e) {
                s_[i] += acc[i][j][e];
                ss_[i] += acc[i][j][e] * acc[i][j][e];
            }
        }
    }
#pragma unroll
    for (int i = 0; i < 4; ++i) {
        s_[i] += __shfl_xor(s_[i], 16);  ss_[i] += __shfl_xor(ss_[i], 16);
        s_[i] += __shfl_xor(s_[i], 32);  ss_[i] += __shfl_xor(ss_[i], 32);
    }
    if (quad == 0) {
#pragma unroll
        for (int i = 0; i < 4; ++i) {
            red_s[w][i * 16 + r] = s_[i];
            red_ss[w][i * 16 + r] = ss_[i];
        }
    }
    __syncthreads();

    float mean[4], rstd[4];
#pragma unroll
    for (int i = 0; i < 4; ++i) {
        float S = 0.f, SS = 0.f;
#pragma unroll
        for (int w2 = 0; w2 < 8; ++w2) { S += red_s[w2][i * 16 + r]; SS += red_ss[w2][i * 16 + r]; }
        mean[i] = S * (1.0f / 256.0f);
        rstd[i] = rsqrtf(SS * (1.0f / 256.0f) - mean[i] * mean[i] + EPSV);
    }

    // qn1 = LN1 out: keep fp32 in oreg, pack bf16 into AqQ (A-frag layout, ks-slice = w).
    // Mapping: value at (m=i*16+r, kk=j*16+quad*4+e2) ->
    //   AqQ[w*2048 + (m*4 + ((j*2+(quad>>1)) ^ ((r>>1)&3)))*8 + (quad&1)*4 + e2].
    f32x4 oreg[4][2];
    {
        float4 g4[2], bt4[2];
#pragma unroll
        for (int j = 0; j < 2; ++j) {
            int colb = w * 32 + j * 16 + quad * 4;
            g4[j] = *(const float4*)&g1[colb];
            bt4[j] = *(const float4*)&be1[colb];
        }
#pragma unroll
        for (int i = 0; i < 4; ++i) {
            const int mm = i * 16 + r;
#pragma unroll
            for (int j = 0; j < 2; ++j) {
                float o0 = (acc[i][j][0] - mean[i]) * rstd[i] * g4[j].x + bt4[j].x;
                float o1 = (acc[i][j][1] - mean[i]) * rstd[i] * g4[j].y + bt4[j].y;
                float o2 = (acc[i][j][2] - mean[i]) * rstd[i] * g4[j].z + bt4[j].z;
                float o3 = (acc[i][j][3] - mean[i]) * rstd[i] * g4[j].w + bt4[j].w;
                oreg[i][j] = (f32x4){o0, o1, o2, o3};
                const int pp = (j * 2 + (quad >> 1)) ^ ((r >> 1) & 3);
                *(uint2*)(AqQ + w * 2048 + (mm * 4 + pp) * 8 + (quad & 1) * 4) =
                    make_uint2(pk2(o0, o1), pk2(o2, o3));
            }
        }
    }
    __syncthreads();   // AqQ complete; all AqO (oms) reads + red_s reads done

    // ======== FFN: 4 quarters of 256 H-cols, hF := AqO ========
    f32x4 acc2[4][2];
#pragma unroll
    for (int i = 0; i < 4; ++i)
#pragma unroll
        for (int j = 0; j < 2; ++j) acc2[i][j] = (f32x4){0.f, 0.f, 0.f, 0.f};

    for (int qq = 0; qq < 4; ++qq) {
        if (qq) __syncthreads();     // prev quarter's phase2 done reading AqO
        // phase 1 in two j-halves (caps register pressure); pack each half into AqO
#pragma unroll
        for (int j = 0; j < 2; ++j) {
            f32x4 a1[4];
#pragma unroll
            for (int i = 0; i < 4; ++i) a1[i] = (f32x4){0.f, 0.f, 0.f, 0.f};
            __builtin_amdgcn_s_setprio(1);
#pragma unroll
            for (int ks = 0; ks < 8; ++ks) {
                const u16* bp = w1F + ((size_t)(ks * 64 + qq * 16 + w * 2 + j) * 64 + lane) * 8;
                bf16x8 bf = *(const bf16x8*)bp;
                bf16x8 af[4];
#pragma unroll
                for (int t = 0; t < 4; ++t) af[t] = *(const bf16x8*)(AqQ + ks * 2048 + aoff[t]);
#pragma unroll
                for (int i = 0; i < 4; ++i)
                    a1[i] = __builtin_amdgcn_mfma_f32_16x16x32_bf16(bf, af[i], a1[i], 0, 0, 0);
            }
            __builtin_amdgcn_s_setprio(0);
            // pack: bias + relu + bf16 into hF (AqO), round-4 verified mapping
            const int cb = qq * 256 + w * 32 + j * 16 + quad * 4;
            const float4 b14 = *(const float4*)&b1[cb];
            const int lane2 = r | (((j * 2 + (quad >> 1)) & 3) << 4);
            const int eo = (quad & 1) * 4;
#pragma unroll
            for (int i = 0; i < 4; ++i) {
                f32x4 v = a1[i];
                uint2 o;
                o.x = pk2(fmaxf(v[0] + b14.x, 0.f), fmaxf(v[1] + b14.y, 0.f));
                o.y = pk2(fmaxf(v[2] + b14.z, 0.f), fmaxf(v[3] + b14.w, 0.f));
                *(uint2*)(AqO + ((w * 4 + i) * 64 + lane2) * 8 + eo) = o;
            }
        }
        __syncthreads();   // hF quarter complete

        // phase 2: acc2 += H_quarter @ W2[qq*256 .. +256, :]
        __builtin_amdgcn_s_setprio(1);
#pragma unroll
        for (int ks = 0; ks < 8; ++ks) {
            const u16* bp = w2F + ((size_t)((qq * 8 + ks) * 16 + w * 2) * 64 + lane) * 8;
            bf16x8 bf0 = *(const bf16x8*)bp;
            bf16x8 bf1 = *(const bf16x8*)(bp + 512);
            bf16x8 af[4];
#pragma unroll
            for (int t = 0; t < 4; ++t) af[t] = *(const bf16x8*)(AqO + ((ks * 4 + t) * 64 + lane) * 8);
#pragma unroll
            for (int i = 0; i < 4; ++i) {
                acc2[i][0] = __builtin_amdgcn_mfma_f32_16x16x32_bf16(bf0, af[i], acc2[i][0], 0, 0, 0);
                acc2[i][1] = __builtin_amdgcn_mfma_f32_16x16x32_bf16(bf1, af[i], acc2[i][1], 0, 0, 0);
            }
        }
        __builtin_amdgcn_s_setprio(0);
    }

    // ======== LN2: bias b2 + residual oreg (registers), write q16 (+q if WRITEQ) ========
#pragma unroll
    for (int j = 0; j < 2; ++j)
        sh2[j] = *(const float4*)&b2[w * 32 + j * 16 + quad * 4];

#pragma unroll
    for (int i = 0; i < 4; ++i) { s_[i] = 0.f; ss_[i] = 0.f; }
#pragma unroll
    for (int i = 0; i < 4; ++i) {
#pragma unroll
        for (int j = 0; j < 2; ++j) {
            acc2[i][j][0] += sh2[j].x + oreg[i][j][0];
            acc2[i][j][1] += sh2[j].y + oreg[i][j][1];
            acc2[i][j][2] += sh2[j].z + oreg[i][j][2];
            acc2[i][j][3] += sh2[j].w + oreg[i][j][3];
#pragma unroll
            for (int e = 0; e < 4; ++e) {
                s_[i] += acc2[i][j][e];
                ss_[i] += acc2[i][j][e] * acc2[i][j][e];
            }
        }
    }
#pragma unroll
    for (int i = 0; i < 4; ++i) {
        s_[i] += __shfl_xor(s_[i], 16);  ss_[i] += __shfl_xor(ss_[i], 16);
        s_[i] += __shfl_xor(s_[i], 32);  ss_[i] += __shfl_xor(ss_[i], 32);
    }
    if (quad == 0) {
#pragma unroll
        for (int i = 0; i < 4; ++i) {
            red_s[w][i * 16 + r] = s_[i];
            red_ss[w][i * 16 + r] = ss_[i];
        }
    }
    __syncthreads();

#pragma unroll
    for (int i = 0; i < 4; ++i) {
        float S = 0.f, SS = 0.f;
#pragma unroll
        for (int w2 = 0; w2 < 8; ++w2) { S += red_s[w2][i * 16 + r]; SS += red_ss[w2][i * 16 + r]; }
        mean[i] = S * (1.0f / 256.0f);
        rstd[i] = rsqrtf(SS * (1.0f / 256.0f) - mean[i] * mean[i] + EPSV);
    }

    float4 g4[2], bt4[2];
#pragma unroll
    for (int j = 0; j < 2; ++j) {
        int colb = w * 32 + j * 16 + quad * 4;
        g4[j] = *(const float4*)&g2[colb];
        bt4[j] = *(const float4*)&be2[colb];
    }
#pragma unroll
    for (int i = 0; i < 4; ++i) {
        const int row = m0 + i * 16 + r;
#pragma unroll
        for (int j = 0; j < 2; ++j) {
            const int colb = w * 32 + j * 16 + quad * 4;
            float o0 = (acc2[i][j][0] - mean[i]) * rstd[i] * g4[j].x + bt4[j].x;
            float o1 = (acc2[i][j][1] - mean[i]) * rstd[i] * g4[j].y + bt4[j].y;
            float o2 = (acc2[i][j][2] - mean[i]) * rstd[i] * g4[j].z + bt4[j].z;
            float o3 = (acc2[i][j][3] - mean[i]) * rstd[i] * g4[j].w + bt4[j].w;
            oreg[i][j] = (f32x4){o0, o1, o2, o3};   // keep qn2 for the OA tail
            if (WRITEQ)
                *(float4*)&q[(size_t)row * DM + colb] = make_float4(o0, o1, o2, o3);
            *(uint2*)(q16 + (size_t)row * DM + colb) = make_uint2(pk2(o0, o1), pk2(o2, o3));
        }
    }

    // ======== OA tail: offat = qn2 @ Woa + boa (next layer's offsets/logits) ========
    if (OA) {
        // repack qn2 into AqQ (same verified A-frag mapping; AqQ reads all done)
#pragma unroll
        for (int i = 0; i < 4; ++i) {
            const int mm = i * 16 + r;
#pragma unroll
            for (int j = 0; j < 2; ++j) {
                const int pp = (j * 2 + (quad >> 1)) ^ ((r >> 1) & 3);
                *(uint2*)(AqQ + w * 2048 + (mm * 4 + pp) * 8 + (quad & 1) * 4) =
                    make_uint2(pk2(oreg[i][j][0], oreg[i][j][1]),
                               pk2(oreg[i][j][2], oreg[i][j][3]));
            }
        }
        __syncthreads();
        f32x4 aoa[4];
#pragma unroll
        for (int i = 0; i < 4; ++i) aoa[i] = (f32x4){0.f, 0.f, 0.f, 0.f};
#pragma unroll
        for (int ks = 0; ks < 8; ++ks) {
            const u16* bp = woaF + ((size_t)(ks * 8 + w) * 64 + lane) * 8;
            bf16x8 bf = *(const bf16x8*)bp;
            bf16x8 af[4];
#pragma unroll
            for (int t = 0; t < 4; ++t) af[t] = *(const bf16x8*)(AqQ + ks * 2048 + aoff[t]);
#pragma unroll
            for (int i = 0; i < 4; ++i)
                aoa[i] = __builtin_amdgcn_mfma_f32_16x16x32_bf16(bf, af[i], aoa[i], 0, 0, 0);
        }
        const float4 bo4 = *(const float4*)&boa1[w * 16 + quad * 4];
#pragma unroll
        for (int i = 0; i < 4; ++i) {
            const int row = m0 + i * 16 + r;
            float4 o = {aoa[i][0] + bo4.x, aoa[i][1] + bo4.y, aoa[i][2] + bo4.z, aoa[i][3] + bo4.w};
            *(float4*)&offat[(size_t)row * 128 + w * 16 + quad * 4] = o;
        }
    }
}

// ================= weight prep =================
__device__ __attribute__((noinline)) void tconv(const float* src, u16* dst, int K, int N, int tk, int tn)
{
    __shared__ float t[32][33];
    const int tx = threadIdx.x & 31, ty = threadIdx.x >> 5;
#pragma unroll
    for (int i = 0; i < 4; ++i)
        t[ty + i * 8][tx] = src[(size_t)(tk * 32 + ty + i * 8) * N + tn * 32 + tx];
    __syncthreads();
#pragma unroll
    for (int i = 0; i < 4; ++i)
        dst[(size_t)(tn * 32 + ty + i * 8) * K + tk * 32 + tx] = f2b(t[tx][ty + i * 8]);
}

__device__ __attribute__((noinline)) void tconv_oa(const float* Woff, const float* Wattn, u16* dst, int tk, int tn)
{
    __shared__ float t[32][33];
    const int tx = threadIdx.x & 31, ty = threadIdx.x >> 5;
#pragma unroll
    for (int i = 0; i < 4; ++i) {
        int k = tk * 32 + ty + i * 8, n = tn * 32 + tx;
        float v = (n < 64) ? Woff[k * 64 + n] : ((n < 96) ? Wattn[k * 32 + n - 64] : 0.f);
        t[ty + i * 8][tx] = v;
    }
    __syncthreads();
#pragma unroll
    for (int i = 0; i < 4; ++i)
        dst[(size_t)(tn * 32 + ty + i * 8) * 256 + tk * 32 + tx] = f2b(t[tx][ty + i * 8]);
}

// W (K,N) fp32 -> fragment-ordered bf16:
// F[ks][nt][lane][e] = W[ks*32 + (lane>>4)*8 + e][nt*16 + (lane&15)]
__device__ __attribute__((noinline)) void frag_prep(const float* W, u16* dst, int ks, int nc, int N)
{
    __shared__ float t[32][256];
    const int tid = threadIdx.x;
#pragma unroll
    for (int kk = 0; kk < 32; ++kk)
        t[kk][tid] = W[(size_t)(ks * 32 + kk) * N + nc * 256 + tid];
    __syncthreads();
    const int NT16 = N >> 4;
#pragma unroll
    for (int i = 0; i < 4; ++i) {
        int idx = tid + i * 256;          // local nt*64 + lane
        int nt = idx >> 6, l = idx & 63;
        int n = nt * 16 + (l & 15);
        int kb = (l >> 4) * 8;
        u16 o[8];
#pragma unroll
        for (int e = 0; e < 8; ++e) o[e] = f2b(t[kb + e][n]);
        *(uint4*)(dst + ((size_t)(ks * NT16 + nc * 16 + nt) * 64 + l) * 8) = *(const uint4*)o;
    }
}

// Synth offat weight [Woff | Wattn | 0] (K=256, N=128) -> fragment order, one block per ks.
__device__ __attribute__((noinline)) void frag_prep_oa(const float* Woff, const float* Wattn, u16* dst, int ks)
{
    __shared__ float t[32][128];
    const int tid = threadIdx.x;
#pragma unroll
    for (int kk2 = 0; kk2 < 16; ++kk2) {
        int idx = tid + kk2 * 256;
        int row = idx >> 7, col = idx & 127;
        float v = (col < 64) ? Woff[(size_t)(ks * 32 + row) * 64 + col]
                 : ((col < 96) ? Wattn[(size_t)(ks * 32 + row) * 32 + col - 64] : 0.f);
        t[row][col] = v;
    }
    __syncthreads();
#pragma unroll
    for (int u2 = 0; u2 < 2; ++u2) {
        int unit = tid + u2 * 256;
        int nt = unit >> 6, l = unit & 63;
        int n = nt * 16 + (l & 15);
        int kb = (l >> 4) * 8;
        u16 o[8];
#pragma unroll
        for (int e = 0; e < 8; ++e) o[e] = f2b(t[kb + e][n]);
        *(uint4*)(dst + ((size_t)(ks * 8 + nt) * 64 + l) * 8) = *(const uint4*)o;
    }
}

__global__ __launch_bounds__(256) void prep_weights(
    const float* __restrict__ Wval, const float* __restrict__ Wo,
    const float* __restrict__ W1, const float* __restrict__ W2,
    const float* __restrict__ Woff, const float* __restrict__ Wattn,
    const float* __restrict__ boff, const float* __restrict__ battn,
    const float* __restrict__ W_in, const float* __restrict__ W_out,
    const float* __restrict__ bn1g, const float* __restrict__ bn1b,
    const float* __restrict__ bn1m, const float* __restrict__ bn1v,
    const float* __restrict__ bn2g, const float* __restrict__ bn2b,
    const float* __restrict__ bn2m, const float* __restrict__ bn2v,
    u16* __restrict__ wvalT, u16* __restrict__ woF, u16* __restrict__ w1F,
    u16* __restrict__ w2F, u16* __restrict__ woaT, u16* __restrict__ woaF,
    u16* __restrict__ winC, u16* __restrict__ woutC,
    float* __restrict__ bn1sc, float* __restrict__ bn1sh,
    float* __restrict__ bn2sc, float* __restrict__ bn2sh, float* __restrict__ boa)
{
    int bid = blockIdx.x;
    if (bid < 128) {                          // Wval transpose: 2 layers x 64
        int l = bid >> 6, r2 = bid & 63;
        tconv(Wval + l * 65536, wvalT + l * 65536, 256, 256, r2 & 7, r2 >> 3);
    } else if (bid < 160) {                   // Woff|Wattn transpose (layer 0 only): 32
        int r2 = bid - 128;
        tconv_oa(Woff, Wattn, woaT, r2 & 7, r2 >> 3);
    } else if (bid < 176) {                   // Wo fragments: 2 x 8 ks
        int i2 = bid - 160;
        frag_prep(Wo + (i2 >> 3) * 65536, woF + (i2 >> 3) * 65536, i2 & 7, 0, 256);
    } else if (bid < 240) {                   // W1 fragments: 2 x (8 ks x 4 nc)
        int i2 = bid - 176, l = i2 >> 5, r2 = i2 & 31;
        frag_prep(W1 + l * 262144, w1F + l * 262144, r2 >> 2, r2 & 3, 1024);
    } else if (bid < 304) {                   // W2 fragments: 2 x 32 ks
        int i2 = bid - 240;
        frag_prep(W2 + (i2 >> 5) * 262144, w2F + (i2 >> 5) * 262144, i2 & 31, 0, 256);
    } else if (bid < 312) {                   // Woa fragments (layer 1): 8 ks
        frag_prep_oa(Woff + 16384, Wattn + 8192, woaF, bid - 304);
    } else if (bid < 344) {
        int g2 = bid - 312, base = g2 * 4096, t = threadIdx.x;
#pragma unroll
        for (int k = 0; k < 16; ++k) winC[base + k * 256 + t] = f2b(W_in[base + k * 256 + t]);
    } else if (bid < 376) {
        int g2 = bid - 344, base = g2 * 4096, t = threadIdx.x;
#pragma unroll
        for (int k = 0; k < 16; ++k) woutC[base + k * 256 + t] = f2b(W_out[base + k * 256 + t]);
    } else {
        int t = threadIdx.x;
        { float s = bn1g[t] * rsqrtf(bn1v[t] + EPSV); bn1sc[t] = s; bn1sh[t] = bn1b[t] - bn1m[t] * s; }
        for (int c = 0; c < 2; ++c) {
            int i = c * 256 + t;
            float s = bn2g[i] * rsqrtf(bn2v[i] + EPSV);
            bn2sc[i] = s; bn2sh[i] = bn2b[i] - bn2m[i] * s;
        }
        if (t < 128)
            for (int l = 0; l < 2; ++l)
                boa[l * 128 + t] = (t < 64) ? boff[l * 64 + t]
                                 : ((t < 96) ? battn[l * 32 + t - 64] : 0.f);
    }
}

// ================= x (B,C,HW) -> xT (B,HW,C) bf16 =================
__global__ __launch_bounds__(256) void transpose_x(const float* __restrict__ x, u16* __restrict__ xT)
{
    __shared__ float t[64][65];
    const int b = blockIdx.z, p0 = blockIdx.y << 6, c0 = blockIdx.x << 6;
    const int tx = threadIdx.x & 63, ty = threadIdx.x >> 6;
    const float* xb = x + ((size_t)b * CINC + c0) * HWTOT + p0;
#pragma unroll
    for (int i = 0; i < 16; ++i)
        t[ty + i * 4][tx] = xb[(size_t)(ty + i * 4) * HWTOT + tx];
    __syncthreads();
    u16* xo = xT + ((size_t)b * HWTOT + p0) * CINC + c0;
#pragma unroll
    for (int i = 0; i < 16; ++i)
        xo[(size_t)(ty + i * 4) * CINC + tx] = f2b(t[tx][ty + i * 4]);
}

// ================= deformable sampling: 8 queries/block, 32 lanes/query =================
// val row stride is 512 (both layers interleaved); lofs selects the layer's 256 cols.
// oa row index is masked (layer-0 offat is batch-periodic, stored for 4096 rows only).
struct IW { int eo; float w; };

__global__ __launch_bounds__(256) void sample_kernel(
    const u16* __restrict__ val,      // (B*HW, 512) bf16, layer cols [lofs, lofs+256)
    const float* __restrict__ oa,     // (rows, 128): [0..63]=off, [64..95]=attn logits
    u16* __restrict__ oms,            // (B*HW, 256) bf16
    int lofs, unsigned int mask)
{
    __shared__ float s_oa[8][96];
    __shared__ IW s_iw[8][32][5];
    const int t = threadIdx.x;
    const int bq0 = blockIdx.x << 3;
    const int b = blockIdx.x >> 9;

    {
        int qi = t >> 5, j = t & 31;
        if (j < 24)
            ((float4*)s_oa[qi])[j] = ((const float4*)oa)[((size_t)((bq0 + qi) & mask)) * 32 + j];
    }
    __syncthreads();

    {
        const int qi = t >> 5, hp = t & 31, h = hp >> 2, p = hp & 3;
        const float* so = s_oa[qi];
        float l0 = so[64 + h * 4 + 0], l1 = so[64 + h * 4 + 1];
        float l2 = so[64 + h * 4 + 2], l3 = so[64 + h * 4 + 3];
        float mx = fmaxf(fmaxf(l0, l1), fmaxf(l2, l3));
        float e0 = __expf(l0 - mx), e1 = __expf(l1 - mx), e2 = __expf(l2 - mx), e3 = __expf(l3 - mx);
        float inv = 1.0f / (e0 + e1 + e2 + e3);
        float aw = ((p == 0) ? e0 : (p == 1) ? e1 : (p == 2) ? e2 : e3) * inv;
        const int bq = bq0 + qi;
        float gx = (float)(bq & 63) + so[hp * 2 + 0];
        float gy = (float)((bq >> 6) & 63) + so[hp * 2 + 1];
        float x0f = floorf(gx), y0f = floorf(gy);
        float wx = gx - x0f, wy = gy - y0f;
        int x0 = (int)x0f, y0 = (int)y0f;
#pragma unroll
        for (int c = 0; c < 4; ++c) {
            int xi = x0 + (c & 1), yi = y0 + (c >> 1);
            bool ok = (xi >= 0) && (xi < 64) && (yi >= 0) && (yi < 64);
            float wgt = ((c & 1) ? wx : 1.0f - wx) * ((c >> 1) ? wy : 1.0f - wy);
            s_iw[qi][hp][c].eo = ok ? ((yi * 64 + xi) << 9) : 0;   // row stride 512
            s_iw[qi][hp][c].w = ok ? aw * wgt : 0.f;
        }
    }
    __syncthreads();

    {
        const int qi = t >> 5, l = t & 31, h = l >> 2, cc = l & 3;
        const u16* base = val + ((size_t)b << 21) + lofs + (h << 5) + (cc << 3);
        float a[8] = {0.f, 0.f, 0.f, 0.f, 0.f, 0.f, 0.f, 0.f};
#pragma unroll
        for (int p = 0; p < 4; ++p)
#pragma unroll
            for (int c = 0; c < 4; ++c) {
                IW iw = s_iw[qi][(h << 2) + p][c];
                uint4 v = *(const uint4*)(base + iw.eo);
                a[0] += iw.w * blo(v.x); a[1] += iw.w * bhi(v.x);
                a[2] += iw.w * blo(v.y); a[3] += iw.w * bhi(v.y);
                a[4] += iw.w * blo(v.z); a[5] += iw.w * bhi(v.z);
                a[6] += iw.w * blo(v.w); a[7] += iw.w * bhi(v.w);
            }
        uint4 o;
        o.x = (uint32_t)f2b(a[0]) | ((uint32_t)f2b(a[1]) << 16);
        o.y = (uint32_t)f2b(a[2]) | ((uint32_t)f2b(a[3]) << 16);
        o.z = (uint32_t)f2b(a[4]) | ((uint32_t)f2b(a[5]) << 16);
        o.w = (uint32_t)f2b(a[6]) | ((uint32_t)f2b(a[7]) << 16);
        *(uint4*)(oms + (size_t)(bq0 + qi) * 256 + (h << 5) + (cc << 3)) = o;
    }
}

__global__ __launch_bounds__(256) void bcast_q(
    const float4* __restrict__ qe, float4* __restrict__ q, u16* __restrict__ q16)
{
    const int i = blockIdx.x * 256 + threadIdx.x;
    float4 v = qe[i];
    uint2 pk = make_uint2(pk2(v.x, v.y), pk2(v.z, v.w));
#pragma unroll
    for (int b = 0; b < BBATCH; ++b)
        q[(size_t)b * 262144 + i] = v;
    ((uint2*)q16)[i] = pk;    // only rows 0..4095 of q16 are read at layer 0
}

extern "C" void kernel_launch(void* const* d_in, const int* in_sizes, int n_in,
                              void* d_out, int out_size, void* d_ws, size_t ws_size,
                              hipStream_t stream)
{
    (void)in_sizes; (void)n_in; (void)out_size; (void)ws_size;
    const float* x     = (const float*)d_in[0];
    const float* W_in  = (const float*)d_in[1];
    const float* bn1_g = (const float*)d_in[2];
    const float* bn1_b = (const float*)d_in[3];
    const float* bn1_m = (const float*)d_in[4];
    const float* bn1_v = (const float*)d_in[5];
    const float* qe    = (const float*)d_in[6];
    const float* Woff  = (const float*)d_in[7];
    const float* boff  = (const float*)d_in[8];
    const float* Wattn = (const float*)d_in[9];
    const float* battn = (const float*)d_in[10];
    const float* Wval  = (const float*)d_in[11];
    const float* bval  = (const float*)d_in[12];
    const float* Wo    = (const float*)d_in[13];
    const float* bo    = (const float*)d_in[14];
    const float* ln1_g = (const float*)d_in[15];
    const float* ln1_b = (const float*)d_in[16];
    const float* W1    = (const float*)d_in[17];
    const float* b1    = (const float*)d_in[18];
    const float* W2    = (const float*)d_in[19];
    const float* b2    = (const float*)d_in[20];
    const float* ln2_g = (const float*)d_in[21];
    const float* ln2_b = (const float*)d_in[22];
    const float* W_out = (const float*)d_in[23];
    const float* bn2_g = (const float*)d_in[24];
    const float* bn2_b = (const float*)d_in[25];
    const float* bn2_m = (const float*)d_in[26];
    const float* bn2_v = (const float*)d_in[27];
    float* out = (float*)d_out;

    char* w = (char*)d_ws;
    // pool (time-disjoint): xT (33.5MB) aliases val16 (33.5MB); offat (16.8) | oms (16.8)
    char* pool    = w;          w += 67108864;
    float* q      = (float*)w;  w += 33554432;
    u16*  q16     = (u16*)w;    w += 16777216;
    u16*  src16   = (u16*)w;    w += 16777216;
    u16*  wvalT   = (u16*)w;    w += 262144;
    u16*  woF     = (u16*)w;    w += 262144;
    u16*  w1F     = (u16*)w;    w += 1048576;
    u16*  w2F     = (u16*)w;    w += 1048576;
    u16*  woaT    = (u16*)w;    w += 65536;
    u16*  woaF    = (u16*)w;    w += 65536;
    u16*  winC    = (u16*)w;    w += 262144;
    u16*  woutC   = (u16*)w;    w += 262144;
    float* bn1sc  = (float*)w;  w += 1024;
    float* bn1sh  = (float*)w;  w += 1024;
    float* bn2sc  = (float*)w;  w += 2048;
    float* bn2sh  = (float*)w;  w += 2048;
    float* boa    = (float*)w;  w += 1024;

    u16*  xT     = (u16*)pool;                       // dead after proj_in
    u16*  val16  = (u16*)pool;                       // (B*HW, 512) both layers
    float* offat = (float*)(pool + 33554432);
    u16*  oms16  = (u16*)(pool + 50331648);

    prep_weights<<<dim3(377), 256, 0, stream>>>(
        Wval, Wo, W1, W2, Woff, Wattn, boff, battn, W_in, W_out,
        bn1_g, bn1_b, bn1_m, bn1_v, bn2_g, bn2_b, bn2_m, bn2_v,
        wvalT, woF, w1F, w2F, woaT, woaF, winC, woutC, bn1sc, bn1sh, bn2sc, bn2sh, boa);
    transpose_x<<<dim3(CINC / 64, HWTOT / 64, BBATCH), 256, 0, stream>>>(x, xT);
    bcast_q<<<dim3(1024), 256, 0, stream>>>((const float4*)qe, (float4*)q, q16);

    // proj_in: (32768,512)@(256,512)^T -> bf16 src
    mfma_gemm<1><<<dim3(2, 256, 1), 256, 0, stream>>>(
        xT, winC, bn1sc, bn1sh, src16, 32768, 256, 512, 256, 0, 0, 0, 1, 1);

    // layer-0 offat: batch-periodic -> compute only M=4096 rows
    mfma_gemm<2><<<dim3(1, 32, 1), 256, 0, stream>>>(
        q16, woaT, nullptr, boa, offat, 4096, 128, 256, 128, 0, 0, 0, 1, 0);

    // both layers' val in one GEMM: (32768,256)@(512,256)^T -> val16 ldc=512
    mfma_gemm<0><<<dim3(4, 256, 1), 256, 0, stream>>>(
        src16, wvalT, nullptr, bval, val16, 32768, 512, 256, 512, 0, 0, 0, 1, 2);

    // layer 0: sample (periodic offat) -> fused layer (writes q, q16, next offat)
    sample_kernel<<<dim3(4096), 256, 0, stream>>>(val16, offat, oms16, 0, 4095u);
    fused_layer<1, 1><<<dim3(512), 512, 0, stream>>>(
        oms16, woF, w1F, w2F, woaF, bo, b1, b2, boa + 128, q, q16, offat,
        ln1_g, ln1_b, ln2_g, ln2_b);

    // layer 1: sample (full offat) -> fused layer (q16 only; q write dead)
    sample_kernel<<<dim3(4096), 256, 0, stream>>>(val16, offat, oms16, 256, 0xFFFFFFFFu);
    fused_layer<0, 0><<<dim3(512), 512, 0, stream>>>(
        oms16, woF + 65536, w1F + 262144, w2F + 262144, nullptr,
        bo + 256, b1 + 1024, b2 + 256, nullptr, q, q16, nullptr,
        ln1_g + 256, ln1_b + 256, ln2_g + 256, ln2_b + 256);

    // proj_out: per-batch (512,256)@(4096,256)^T -> fp32 out (B,C,HW)
    mfma_gemm<3><<<dim3(32, 4, BBATCH), 256, 0, stream>>>(
        woutC, q16, bn2sc, bn2sh, out, 512, 4096, 256, 4096,
        0, (long long)HWTOT * DM, (long long)CINC * HWTOT, 0, 0);
}

// Round 9
// 422.421 us; speedup vs baseline: 1.3594x; 1.0681x over previous
//
#include <hip/hip_runtime.h>
#include <cstdint>

#define LYR 2
#define DM  256
#define DFFN 1024
#define CINC 512
#define BBATCH 8
#define HWTOT 4096
#define EPSV 1e-5f

using u16 = unsigned short;
typedef __attribute__((ext_vector_type(8))) short bf16x8;
typedef __attribute__((ext_vector_type(4))) float f32x4;

__device__ inline u16 f2b(float v) {
    union { float f; uint32_t u; } x; x.f = v;
    uint32_t r = x.u + 0x7fffu + ((x.u >> 16) & 1u);
    return (u16)(r >> 16);
}
__device__ inline uint32_t pk2(float a, float b) {
    return (uint32_t)f2b(a) | ((uint32_t)f2b(b) << 16);
}
__device__ inline float blo(uint32_t d) {
    union { uint32_t i; float f; } x; x.i = d << 16; return x.f;
}
__device__ inline float bhi(uint32_t d) {
    union { uint32_t i; float f; } x; x.i = d & 0xffff0000u; return x.f;
}

// ============ bf16 MFMA GEMM: C = A(M,K) @ Bt(N,K)^T, 128x128 tile, BK=32 ============
// Counted-vmcnt pipeline: 4 LDS buffers, 2-group-deep prefetch, raw s_barrier.
// MODE 2: fp32 out, x+shift[col]                   (offattn l0)
// MODE 3: fp32 out, relu(x*scale[row]+shift[row])  (proj_out)
template<int MODE>
__global__ __launch_bounds__(256) void mfma_gemm(
    const u16* __restrict__ A, const u16* __restrict__ Bt,
    const float* __restrict__ scale, const float* __restrict__ shift,
    void* __restrict__ Cv, int M, int N, int K, int ldc,
    long long a_zs, long long b_zs, long long c_zs, int swz, int gxlog)
{
    __shared__ u16 As[4][4096];
    __shared__ u16 Bs[4][4096];
    const int tid = threadIdx.x;
    const int lane = tid & 63;
    const int wid = tid >> 6;
    const int wm = (wid & 1) << 6, wn = (wid >> 1) << 6;
    const int quad = lane >> 4, r = lane & 15;

    int bx = blockIdx.x, by = blockIdx.y;
    if (swz) {  // XCD-band swizzle
        int linear = by * gridDim.x + bx;
        int xcd = linear & 7;
        int s = linear >> 3;
        bx = s & (gridDim.x - 1);
        by = xcd * (gridDim.y >> 3) + (s >> gxlog);
    }
    const int m0 = by << 7, n0 = bx << 7;
    const u16* Ab = A + (long long)blockIdx.z * a_zs + (long long)m0 * K;
    const u16* Bb = Bt + (long long)blockIdx.z * b_zs + (long long)n0 * K;

    const int u0 = tid, u1 = tid + 256;
    const int mu0 = u0 >> 2, cu0 = (u0 & 3) ^ ((mu0 >> 1) & 3);
    const int mu1 = u1 >> 2, cu1 = (u1 & 3) ^ ((mu1 >> 1) & 3);
    const long long ga0 = (long long)mu0 * K + cu0 * 8;
    const long long ga1 = (long long)mu1 * K + cu1 * 8;

    int aoff[4], boff[4];
#pragma unroll
    for (int t = 0; t < 4; ++t) {
        int m = wm + t * 16 + r;
        aoff[t] = (m * 4 + (quad ^ ((m >> 1) & 3))) * 8;
        int n = wn + t * 16 + r;
        boff[t] = (n * 4 + (quad ^ ((n >> 1) & 3))) * 8;
    }

    f32x4 acc[4][4];
#pragma unroll
    for (int i = 0; i < 4; ++i)
#pragma unroll
        for (int j = 0; j < 4; ++j) acc[i][j] = (f32x4){0.f, 0.f, 0.f, 0.f};

    const int NT = K >> 5;

#define GSTAGE(g, b) do {                                                                       \
    const long long kk = (long long)(g) << 5;                                                   \
    __builtin_amdgcn_global_load_lds((const __attribute__((address_space(1))) void*)(Ab + ga0 + kk), \
        (__attribute__((address_space(3))) void*)(&As[b][u0 * 8]), 16, 0, 0);                   \
    __builtin_amdgcn_global_load_lds((const __attribute__((address_space(1))) void*)(Ab + ga1 + kk), \
        (__attribute__((address_space(3))) void*)(&As[b][u1 * 8]), 16, 0, 0);                   \
    __builtin_amdgcn_global_load_lds((const __attribute__((address_space(1))) void*)(Bb + ga0 + kk), \
        (__attribute__((address_space(3))) void*)(&Bs[b][u0 * 8]), 16, 0, 0);                   \
    __builtin_amdgcn_global_load_lds((const __attribute__((address_space(1))) void*)(Bb + ga1 + kk), \
        (__attribute__((address_space(3))) void*)(&Bs[b][u1 * 8]), 16, 0, 0);                   \
} while (0)

    GSTAGE(0, 0);
    GSTAGE(1, 1);
    GSTAGE(2, 2);

    for (int t = 0; t < NT; ++t) {
        if (t < NT - 2)       asm volatile("s_waitcnt vmcnt(8)" ::: "memory");
        else if (t == NT - 2) asm volatile("s_waitcnt vmcnt(4)" ::: "memory");
        else                  asm volatile("s_waitcnt vmcnt(0)" ::: "memory");
        __builtin_amdgcn_s_barrier();
        __builtin_amdgcn_sched_barrier(0);
        if (t + 3 < NT) GSTAGE(t + 3, (t + 3) & 3);
        const u16* Ap = As[t & 3];
        const u16* Bp = Bs[t & 3];
        bf16x8 af[4], bf[4];
#pragma unroll
        for (int tt = 0; tt < 4; ++tt) af[tt] = *(const bf16x8*)(Ap + aoff[tt]);
#pragma unroll
        for (int tt = 0; tt < 4; ++tt) bf[tt] = *(const bf16x8*)(Bp + boff[tt]);
#pragma unroll
        for (int i = 0; i < 4; ++i)
#pragma unroll
            for (int j = 0; j < 4; ++j)
                acc[i][j] = __builtin_amdgcn_mfma_f32_16x16x32_bf16(bf[j], af[i], acc[i][j], 0, 0, 0);
    }
#undef GSTAGE

    const long long zc = (long long)blockIdx.z * c_zs;
    float4 sh4[4];
    if (MODE != 3) {
#pragma unroll
        for (int j = 0; j < 4; ++j) {
            int colb = n0 + wn + j * 16 + quad * 4;
            sh4[j] = *(const float4*)&shift[colb];
        }
    }
#pragma unroll
    for (int i = 0; i < 4; ++i) {
        const int row = m0 + wm + i * 16 + r;
        float rsc = 0.f, rsh = 0.f;
        if (MODE == 3) { rsc = scale[row]; rsh = shift[row]; }
#pragma unroll
        for (int j = 0; j < 4; ++j) {
            const int colb = n0 + wn + j * 16 + quad * 4;
            f32x4 v = acc[i][j];
            if (MODE == 2) {
                float4 o = {v[0] + sh4[j].x, v[1] + sh4[j].y, v[2] + sh4[j].z, v[3] + sh4[j].w};
                *(float4*)((float*)Cv + zc + (long long)row * ldc + colb) = o;
            } else {
                float4 o = {fmaxf(v[0] * rsc + rsh, 0.f), fmaxf(v[1] * rsc + rsh, 0.f),
                            fmaxf(v[2] * rsc + rsh, 0.f), fmaxf(v[3] * rsc + rsh, 0.f)};
                *(float4*)((float*)Cv + zc + (long long)row * ldc + colb) = o;
            }
        }
    }
}

// ============ Full-N GEMM: block = 64 rows x N, A read ONCE, B from fragments ============
// Generalized from the verified mfma_gemm_ln pipeline (3-buffer A, counted vmcnt(NTW+1)).
// NTW: column-tiles (16 cols each) per wave; N = NTW*8*16. NT = K/32.
// MODE 0: bf16 out, pk2(x+shift[col])              (val, N=512, lstr=per-layer B stride)
// MODE 1: bf16 out, pk2(relu(x*scale+shift))       (proj_in, N=256, lstr=0)
template<int NTW, int NT, int MODE>
__global__ __launch_bounds__(512, 3) void gemm_fullN(
    const u16* __restrict__ A, const u16* __restrict__ Bf,
    const float* __restrict__ scale, const float* __restrict__ shift,
    u16* __restrict__ out, int ldc, long long lstr)
{
    constexpr int K = NT * 32;
    __shared__ u16 As[3][2048];
    const int tid = threadIdx.x;
    const int lane = tid & 63;
    const int w = tid >> 6;
    const int quad = lane >> 4, r = lane & 15;
    const int m0 = blockIdx.x << 6;
    const u16* Ab = A + (long long)m0 * K;

    const int mA = tid >> 2, cA = (tid & 3) ^ ((mA >> 1) & 3);
    const long long gaA = (long long)mA * K + cA * 8;
    const bool stager = tid < 256;

    int aoff[4];
#pragma unroll
    for (int t = 0; t < 4; ++t) {
        int m = t * 16 + r;
        aoff[t] = (m * 4 + (quad ^ ((m >> 1) & 3))) * 8;
    }

    // B fragment bases: global nt g = w*NTW + t; layer = g>>4 (0 when lstr==0 since g<16)
    size_t bbase[NTW];
#pragma unroll
    for (int t = 0; t < NTW; ++t) {
        int g = w * NTW + t;
        bbase[t] = (size_t)(g >> 4) * lstr + ((size_t)(g & 15) * 64 + lane) * 8;
    }

    f32x4 acc[4][NTW];
#pragma unroll
    for (int i = 0; i < 4; ++i)
#pragma unroll
        for (int t = 0; t < NTW; ++t) acc[i][t] = (f32x4){0.f, 0.f, 0.f, 0.f};

    // prologue: DMAs tiles 0,1 first (order pinned), then ks=0 B-frags
    if (stager) {
        __builtin_amdgcn_global_load_lds((const __attribute__((address_space(1))) void*)(Ab + gaA),
                                         (__attribute__((address_space(3))) void*)(&As[0][tid * 8]), 16, 0, 0);
        __builtin_amdgcn_global_load_lds((const __attribute__((address_space(1))) void*)(Ab + gaA + 32),
                                         (__attribute__((address_space(3))) void*)(&As[1][tid * 8]), 16, 0, 0);
    }
    __builtin_amdgcn_sched_barrier(0);
    bf16x8 bc[NTW];
#pragma unroll
    for (int t = 0; t < NTW; ++t) bc[t] = *(const bf16x8*)(Bf + bbase[t]);

    int cb = 0;
    for (int t = 0; t < NT; ++t) {
        if constexpr (NTW == 2) asm volatile("s_waitcnt vmcnt(3)" ::: "memory");
        else                    asm volatile("s_waitcnt vmcnt(5)" ::: "memory");
        __builtin_amdgcn_s_barrier();
        __builtin_amdgcn_sched_barrier(0);
        int nb = cb + 2; if (nb >= 3) nb -= 3;
        if (stager && t + 2 < NT)
            __builtin_amdgcn_global_load_lds((const __attribute__((address_space(1))) void*)(Ab + gaA + (long long)(t + 2) * 32),
                                             (__attribute__((address_space(3))) void*)(&As[nb][tid * 8]), 16, 0, 0);
        bf16x8 bn[NTW];
        if (t + 1 < NT) {
#pragma unroll
            for (int tt = 0; tt < NTW; ++tt)
                bn[tt] = *(const bf16x8*)(Bf + bbase[tt] + (size_t)(t + 1) * 8192);
        } else {
#pragma unroll
            for (int tt = 0; tt < NTW; ++tt) bn[tt] = bc[tt];
        }

        const u16* Ac = As[cb];
        bf16x8 af[4];
#pragma unroll
        for (int tt = 0; tt < 4; ++tt) af[tt] = *(const bf16x8*)(Ac + aoff[tt]);
#pragma unroll
        for (int i = 0; i < 4; ++i)
#pragma unroll
            for (int tt = 0; tt < NTW; ++tt)
                acc[i][tt] = __builtin_amdgcn_mfma_f32_16x16x32_bf16(bc[tt], af[i], acc[i][tt], 0, 0, 0);
#pragma unroll
        for (int tt = 0; tt < NTW; ++tt) bc[tt] = bn[tt];
        cb = (cb + 1 == 3) ? 0 : cb + 1;
    }

    // epilogue
    float4 sh4[NTW], sc4[NTW];
#pragma unroll
    for (int tt = 0; tt < NTW; ++tt) {
        int colg = (w * NTW + tt) * 16 + quad * 4;
        sh4[tt] = *(const float4*)&shift[colg];
        if (MODE == 1) sc4[tt] = *(const float4*)&scale[colg];
    }
#pragma unroll
    for (int i = 0; i < 4; ++i) {
        const int row = m0 + i * 16 + r;
#pragma unroll
        for (int tt = 0; tt < NTW; ++tt) {
            const int colg = (w * NTW + tt) * 16 + quad * 4;
            f32x4 v = acc[i][tt];
            uint2 o;
            if (MODE == 1) {
                o.x = pk2(fmaxf(v[0] * sc4[tt].x + sh4[tt].x, 0.f), fmaxf(v[1] * sc4[tt].y + sh4[tt].y, 0.f));
                o.y = pk2(fmaxf(v[2] * sc4[tt].z + sh4[tt].z, 0.f), fmaxf(v[3] * sc4[tt].w + sh4[tt].w, 0.f));
            } else {
                o.x = pk2(v[0] + sh4[tt].x, v[1] + sh4[tt].y);
                o.y = pk2(v[2] + sh4[tt].z, v[3] + sh4[tt].w);
            }
            *(uint2*)(out + (size_t)row * ldc + colg) = o;
        }
    }
}

// ============ Fused layer: q = LN2(qn1 + FFN(qn1)),  qn1 = LN1(res + oms@Wo + bo) ============
// WRITEQ: write q fp32; OA: compute next layer's offat in the tail;
// QE: residual = qe[row & 4095] (layer 0; identical floats to the old broadcast q).
template<int WRITEQ, int OA, int QE>
__global__ __launch_bounds__(512, 4) void fused_layer(
    const u16* __restrict__ oms, const u16* __restrict__ woF,
    const u16* __restrict__ w1F, const u16* __restrict__ w2F,
    const u16* __restrict__ woaF,
    const float* __restrict__ bo, const float* __restrict__ b1, const float* __restrict__ b2,
    const float* __restrict__ boa1,
    const float* __restrict__ qe, float* __restrict__ q, u16* __restrict__ q16,
    float* __restrict__ offat,
    const float* __restrict__ g1, const float* __restrict__ be1,
    const float* __restrict__ g2, const float* __restrict__ be2)
{
    __shared__ u16 AqO[16384];                // oms A-tile (32KB); reused as hF in FFN
    __shared__ u16 AqQ[16384];                // qn1 (then qn2) bf16 in A-frag layout
    __shared__ float red_s[8][64], red_ss[8][64];
    const int tid = threadIdx.x;
    const int lane = tid & 63;
    const int w = tid >> 6;
    const int quad = lane >> 4, r = lane & 15;
    const int m0 = blockIdx.x << 6;

    const u16* Ab = oms + (long long)m0 * DM;
#pragma unroll
    for (int i = 0; i < 4; ++i) {
        int u = tid + i * 512;
        int ks = u >> 8, v = u & 255;
        int m = v >> 2, c = (v & 3) ^ ((m >> 1) & 3);
        __builtin_amdgcn_global_load_lds((const __attribute__((address_space(1))) void*)(Ab + (long long)m * DM + ks * 32 + c * 8),
                                         (__attribute__((address_space(3))) void*)(AqO + u * 8), 16, 0, 0);
    }

    int aoff[4];
#pragma unroll
    for (int t = 0; t < 4; ++t) {
        int m = t * 16 + r;
        aoff[t] = (m * 4 + (quad ^ ((m >> 1) & 3))) * 8;
    }

    f32x4 acc[4][2];
#pragma unroll
    for (int i = 0; i < 4; ++i)
#pragma unroll
        for (int j = 0; j < 2; ++j) acc[i][j] = (f32x4){0.f, 0.f, 0.f, 0.f};

    __syncthreads();

    // ======== Wo GEMM ========
#pragma unroll
    for (int ks = 0; ks < 8; ++ks) {
        const u16* bp = woF + ((size_t)(ks * 16 + 2 * w) * 64 + lane) * 8;
        bf16x8 bf0 = *(const bf16x8*)bp;
        bf16x8 bf1 = *(const bf16x8*)(bp + 512);
        bf16x8 af[4];
#pragma unroll
        for (int t = 0; t < 4; ++t) af[t] = *(const bf16x8*)(AqO + ks * 2048 + aoff[t]);
#pragma unroll
        for (int i = 0; i < 4; ++i) {
            acc[i][0] = __builtin_amdgcn_mfma_f32_16x16x32_bf16(bf0, af[i], acc[i][0], 0, 0, 0);
            acc[i][1] = __builtin_amdgcn_mfma_f32_16x16x32_bf16(bf1, af[i], acc[i][1], 0, 0, 0);
        }
    }

    // ======== LN1 ========
    float4 sh2[2];
#pragma unroll
    for (int j = 0; j < 2; ++j)
        sh2[j] = *(const float4*)&bo[w * 32 + j * 16 + quad * 4];

    float s_[4] = {0.f, 0.f, 0.f, 0.f}, ss_[4] = {0.f, 0.f, 0.f, 0.f};
#pragma unroll
    for (int i = 0; i < 4; ++i) {
        const int row = m0 + i * 16 + r;
#pragma unroll
        for (int j = 0; j < 2; ++j) {
            const int colb = w * 32 + j * 16 + quad * 4;
            float4 qo = QE ? *(const float4*)&qe[(size_t)(row & 4095) * DM + colb]
                           : *(const float4*)&q[(size_t)row * DM + colb];
            acc[i][j][0] += sh2[j].x + qo.x;
            acc[i][j][1] += sh2[j].y + qo.y;
            acc[i][j][2] += sh2[j].z + qo.z;
            acc[i][j][3] += sh2[j].w + qo.w;
#pragma unroll
            for (int e = 0; e < 4; ++e) {
                s_[i] += acc[i][j][e];
                ss_[i] += acc[i][j][e] * acc[i][j][e];
            }
        }
    }
#pragma unroll
    for (int i = 0; i < 4; ++i) {
        s_[i] += __shfl_xor(s_[i], 16);  ss_[i] += __shfl_xor(ss_[i], 16);
        s_[i] += __shfl_xor(s_[i], 32);  ss_[i] += __shfl_xor(ss_[i], 32);
    }
    if (quad == 0) {
#pragma unroll
        for (int i = 0; i < 4; ++i) {
            red_s[w][i * 16 + r] = s_[i];
            red_ss[w][i * 16 + r] = ss_[i];
        }
    }
    __syncthreads();

    float mean[4], rstd[4];
#pragma unroll
    for (int i = 0; i < 4; ++i) {
        float S = 0.f, SS = 0.f;
#pragma unroll
        for (int w2 = 0; w2 < 8; ++w2) { S += red_s[w2][i * 16 + r]; SS += red_ss[w2][i * 16 + r]; }
        mean[i] = S * (1.0f / 256.0f);
        rstd[i] = rsqrtf(SS * (1.0f / 256.0f) - mean[i] * mean[i] + EPSV);
    }

    f32x4 oreg[4][2];
    {
        float4 g4[2], bt4[2];
#pragma unroll
        for (int j = 0; j < 2; ++j) {
            int colb = w * 32 + j * 16 + quad * 4;
            g4[j] = *(const float4*)&g1[colb];
            bt4[j] = *(const float4*)&be1[colb];
        }
#pragma unroll
        for (int i = 0; i < 4; ++i) {
            const int mm = i * 16 + r;
#pragma unroll
            for (int j = 0; j < 2; ++j) {
                float o0 = (acc[i][j][0] - mean[i]) * rstd[i] * g4[j].x + bt4[j].x;
                float o1 = (acc[i][j][1] - mean[i]) * rstd[i] * g4[j].y + bt4[j].y;
                float o2 = (acc[i][j][2] - mean[i]) * rstd[i] * g4[j].z + bt4[j].z;
                float o3 = (acc[i][j][3] - mean[i]) * rstd[i] * g4[j].w + bt4[j].w;
                oreg[i][j] = (f32x4){o0, o1, o2, o3};
                const int pp = (j * 2 + (quad >> 1)) ^ ((r >> 1) & 3);
                *(uint2*)(AqQ + w * 2048 + (mm * 4 + pp) * 8 + (quad & 1) * 4) =
                    make_uint2(pk2(o0, o1), pk2(o2, o3));
            }
        }
    }
    __syncthreads();

    // ======== FFN: 4 quarters of 256 H-cols, hF := AqO ========
    f32x4 acc2[4][2];
#pragma unroll
    for (int i = 0; i < 4; ++i)
#pragma unroll
        for (int j = 0; j < 2; ++j) acc2[i][j] = (f32x4){0.f, 0.f, 0.f, 0.f};

    for (int qq = 0; qq < 4; ++qq) {
        if (qq) __syncthreads();
#pragma unroll
        for (int j = 0; j < 2; ++j) {
            f32x4 a1[4];
#pragma unroll
            for (int i = 0; i < 4; ++i) a1[i] = (f32x4){0.f, 0.f, 0.f, 0.f};
            __builtin_amdgcn_s_setprio(1);
#pragma unroll
            for (int ks = 0; ks < 8; ++ks) {
                const u16* bp = w1F + ((size_t)(ks * 64 + qq * 16 + w * 2 + j) * 64 + lane) * 8;
                bf16x8 bf = *(const bf16x8*)bp;
                bf16x8 af[4];
#pragma unroll
                for (int t = 0; t < 4; ++t) af[t] = *(const bf16x8*)(AqQ + ks * 2048 + aoff[t]);
#pragma unroll
                for (int i = 0; i < 4; ++i)
                    a1[i] = __builtin_amdgcn_mfma_f32_16x16x32_bf16(bf, af[i], a1[i], 0, 0, 0);
            }
            __builtin_amdgcn_s_setprio(0);
            const int cb = qq * 256 + w * 32 + j * 16 + quad * 4;
            const float4 b14 = *(const float4*)&b1[cb];
            const int lane2 = r | (((j * 2 + (quad >> 1)) & 3) << 4);
            const int eo = (quad & 1) * 4;
#pragma unroll
            for (int i = 0; i < 4; ++i) {
                f32x4 v = a1[i];
                uint2 o;
                o.x = pk2(fmaxf(v[0] + b14.x, 0.f), fmaxf(v[1] + b14.y, 0.f));
                o.y = pk2(fmaxf(v[2] + b14.z, 0.f), fmaxf(v[3] + b14.w, 0.f));
                *(uint2*)(AqO + ((w * 4 + i) * 64 + lane2) * 8 + eo) = o;
            }
        }
        __syncthreads();

        __builtin_amdgcn_s_setprio(1);
#pragma unroll
        for (int ks = 0; ks < 8; ++ks) {
            const u16* bp = w2F + ((size_t)((qq * 8 + ks) * 16 + w * 2) * 64 + lane) * 8;
            bf16x8 bf0 = *(const bf16x8*)bp;
            bf16x8 bf1 = *(const bf16x8*)(bp + 512);
            bf16x8 af[4];
#pragma unroll
            for (int t = 0; t < 4; ++t) af[t] = *(const bf16x8*)(AqO + ((ks * 4 + t) * 64 + lane) * 8);
#pragma unroll
            for (int i = 0; i < 4; ++i) {
                acc2[i][0] = __builtin_amdgcn_mfma_f32_16x16x32_bf16(bf0, af[i], acc2[i][0], 0, 0, 0);
                acc2[i][1] = __builtin_amdgcn_mfma_f32_16x16x32_bf16(bf1, af[i], acc2[i][1], 0, 0, 0);
            }
        }
        __builtin_amdgcn_s_setprio(0);
    }

    // ======== LN2 ========
#pragma unroll
    for (int j = 0; j < 2; ++j)
        sh2[j] = *(const float4*)&b2[w * 32 + j * 16 + quad * 4];

#pragma unroll
    for (int i = 0; i < 4; ++i) { s_[i] = 0.f; ss_[i] = 0.f; }
#pragma unroll
    for (int i = 0; i < 4; ++i) {
#pragma unroll
        for (int j = 0; j < 2; ++j) {
            acc2[i][j][0] += sh2[j].x + oreg[i][j][0];
            acc2[i][j][1] += sh2[j].y + oreg[i][j][1];
            acc2[i][j][2] += sh2[j].z + oreg[i][j][2];
            acc2[i][j][3] += sh2[j].w + oreg[i][j][3];
#pragma unroll
            for (int e = 0; e < 4; ++e) {
                s_[i] += acc2[i][j][e];
                ss_[i] += acc2[i][j][e] * acc2[i][j][e];
            }
        }
    }
#pragma unroll
    for (int i = 0; i < 4; ++i) {
        s_[i] += __shfl_xor(s_[i], 16);  ss_[i] += __shfl_xor(ss_[i], 16);
        s_[i] += __shfl_xor(s_[i], 32);  ss_[i] += __shfl_xor(ss_[i], 32);
    }
    if (quad == 0) {
#pragma unroll
        for (int i = 0; i < 4; ++i) {
            red_s[w][i * 16 + r] = s_[i];
            red_ss[w][i * 16 + r] = ss_[i];
        }
    }
    __syncthreads();

#pragma unroll
    for (int i = 0; i < 4; ++i) {
        float S = 0.f, SS = 0.f;
#pragma unroll
        for (int w2 = 0; w2 < 8; ++w2) { S += red_s[w2][i * 16 + r]; SS += red_ss[w2][i * 16 + r]; }
        mean[i] = S * (1.0f / 256.0f);
        rstd[i] = rsqrtf(SS * (1.0f / 256.0f) - mean[i] * mean[i] + EPSV);
    }

    float4 g4[2], bt4[2];
#pragma unroll
    for (int j = 0; j < 2; ++j) {
        int colb = w * 32 + j * 16 + quad * 4;
        g4[j] = *(const float4*)&g2[colb];
        bt4[j] = *(const float4*)&be2[colb];
    }
#pragma unroll
    for (int i = 0; i < 4; ++i) {
        const int row = m0 + i * 16 + r;
#pragma unroll
        for (int j = 0; j < 2; ++j) {
            const int colb = w * 32 + j * 16 + quad * 4;
            float o0 = (acc2[i][j][0] - mean[i]) * rstd[i] * g4[j].x + bt4[j].x;
            float o1 = (acc2[i][j][1] - mean[i]) * rstd[i] * g4[j].y + bt4[j].y;
            float o2 = (acc2[i][j][2] - mean[i]) * rstd[i] * g4[j].z + bt4[j].z;
            float o3 = (acc2[i][j][3] - mean[i]) * rstd[i] * g4[j].w + bt4[j].w;
            oreg[i][j] = (f32x4){o0, o1, o2, o3};
            if (WRITEQ)
                *(float4*)&q[(size_t)row * DM + colb] = make_float4(o0, o1, o2, o3);
            *(uint2*)(q16 + (size_t)row * DM + colb) = make_uint2(pk2(o0, o1), pk2(o2, o3));
        }
    }

    // ======== OA tail ========
    if (OA) {
#pragma unroll
        for (int i = 0; i < 4; ++i) {
            const int mm = i * 16 + r;
#pragma unroll
            for (int j = 0; j < 2; ++j) {
                const int pp = (j * 2 + (quad >> 1)) ^ ((r >> 1) & 3);
                *(uint2*)(AqQ + w * 2048 + (mm * 4 + pp) * 8 + (quad & 1) * 4) =
                    make_uint2(pk2(oreg[i][j][0], oreg[i][j][1]),
                               pk2(oreg[i][j][2], oreg[i][j][3]));
            }
        }
        __syncthreads();
        f32x4 aoa[4];
#pragma unroll
        for (int i = 0; i < 4; ++i) aoa[i] = (f32x4){0.f, 0.f, 0.f, 0.f};
#pragma unroll
        for (int ks = 0; ks < 8; ++ks) {
            const u16* bp = woaF + ((size_t)(ks * 8 + w) * 64 + lane) * 8;
            bf16x8 bf = *(const bf16x8*)bp;
            bf16x8 af[4];
#pragma unroll
            for (int t = 0; t < 4; ++t) af[t] = *(const bf16x8*)(AqQ + ks * 2048 + aoff[t]);
#pragma unroll
            for (int i = 0; i < 4; ++i)
                aoa[i] = __builtin_amdgcn_mfma_f32_16x16x32_bf16(bf, af[i], aoa[i], 0, 0, 0);
        }
        const float4 bo4 = *(const float4*)&boa1[w * 16 + quad * 4];
#pragma unroll
        for (int i = 0; i < 4; ++i) {
            const int row = m0 + i * 16 + r;
            float4 o = {aoa[i][0] + bo4.x, aoa[i][1] + bo4.y, aoa[i][2] + bo4.z, aoa[i][3] + bo4.w};
            *(float4*)&offat[(size_t)row * 128 + w * 16 + quad * 4] = o;
        }
    }
}

// ================= weight prep =================
__device__ __attribute__((noinline)) void tconv_oa(const float* Woff, const float* Wattn, u16* dst, int tk, int tn)
{
    __shared__ float t[32][33];
    const int tx = threadIdx.x & 31, ty = threadIdx.x >> 5;
#pragma unroll
    for (int i = 0; i < 4; ++i) {
        int k = tk * 32 + ty + i * 8, n = tn * 32 + tx;
        float v = (n < 64) ? Woff[k * 64 + n] : ((n < 96) ? Wattn[k * 32 + n - 64] : 0.f);
        t[ty + i * 8][tx] = v;
    }
    __syncthreads();
#pragma unroll
    for (int i = 0; i < 4; ++i)
        dst[(size_t)(tn * 32 + ty + i * 8) * 256 + tk * 32 + tx] = f2b(t[tx][ty + i * 8]);
}

// W (K,N) fp32 -> fragment-ordered bf16: F[ks][nt][lane][e] = W[ks*32+(lane>>4)*8+e][nt*16+(lane&15)]
__device__ __attribute__((noinline)) void frag_prep(const float* W, u16* dst, int ks, int nc, int N)
{
    __shared__ float t[32][256];
    const int tid = threadIdx.x;
#pragma unroll
    for (int kk = 0; kk < 32; ++kk)
        t[kk][tid] = W[(size_t)(ks * 32 + kk) * N + nc * 256 + tid];
    __syncthreads();
    const int NT16 = N >> 4;
#pragma unroll
    for (int i = 0; i < 4; ++i) {
        int idx = tid + i * 256;
        int nt = idx >> 6, l = idx & 63;
        int n = nt * 16 + (l & 15);
        int kb = (l >> 4) * 8;
        u16 o[8];
#pragma unroll
        for (int e = 0; e < 8; ++e) o[e] = f2b(t[kb + e][n]);
        *(uint4*)(dst + ((size_t)(ks * NT16 + nc * 16 + nt) * 64 + l) * 8) = *(const uint4*)o;
    }
}

// W (N=256, K=512) row-major -> fragment order (for W_in).
__device__ __attribute__((noinline)) void frag_prep_t(const float* W, u16* dst, int ks)
{
    __shared__ float t[32][256];
    const int tid = threadIdx.x;
#pragma unroll
    for (int kk = 0; kk < 32; ++kk)
        t[kk][tid] = W[(size_t)tid * 512 + ks * 32 + kk];
    __syncthreads();
#pragma unroll
    for (int i = 0; i < 4; ++i) {
        int idx = tid + i * 256;
        int nt = idx >> 6, l = idx & 63;
        int n = nt * 16 + (l & 15);
        int kb = (l >> 4) * 8;
        u16 o[8];
#pragma unroll
        for (int e = 0; e < 8; ++e) o[e] = f2b(t[kb + e][n]);
        *(uint4*)(dst + ((size_t)(ks * 16 + nt) * 64 + l) * 8) = *(const uint4*)o;
    }
}

// Synth offat weight [Woff | Wattn | 0] (K=256, N=128) -> fragment order.
__device__ __attribute__((noinline)) void frag_prep_oa(const float* Woff, const float* Wattn, u16* dst, int ks)
{
    __shared__ float t[32][128];
    const int tid = threadIdx.x;
#pragma unroll
    for (int kk2 = 0; kk2 < 16; ++kk2) {
        int idx = tid + kk2 * 256;
        int row = idx >> 7, col = idx & 127;
        float v = (col < 64) ? Woff[(size_t)(ks * 32 + row) * 64 + col]
                 : ((col < 96) ? Wattn[(size_t)(ks * 32 + row) * 32 + col - 64] : 0.f);
        t[row][col] = v;
    }
    __syncthreads();
#pragma unroll
    for (int u2 = 0; u2 < 2; ++u2) {
        int unit = tid + u2 * 256;
        int nt = unit >> 6, l = unit & 63;
        int n = nt * 16 + (l & 15);
        int kb = (l >> 4) * 8;
        u16 o[8];
#pragma unroll
        for (int e = 0; e < 8; ++e) o[e] = f2b(t[kb + e][n]);
        *(uint4*)(dst + ((size_t)(ks * 8 + nt) * 64 + l) * 8) = *(const uint4*)o;
    }
}

__global__ __launch_bounds__(256) void prep_weights(
    const float* __restrict__ Wval, const float* __restrict__ Wo,
    const float* __restrict__ W1, const float* __restrict__ W2,
    const float* __restrict__ Woff, const float* __restrict__ Wattn,
    const float* __restrict__ boff, const float* __restrict__ battn,
    const float* __restrict__ W_in, const float* __restrict__ W_out,
    const float* __restrict__ bn1g, const float* __restrict__ bn1b,
    const float* __restrict__ bn1m, const float* __restrict__ bn1v,
    const float* __restrict__ bn2g, const float* __restrict__ bn2b,
    const float* __restrict__ bn2m, const float* __restrict__ bn2v,
    u16* __restrict__ wvalF, u16* __restrict__ woF, u16* __restrict__ w1F,
    u16* __restrict__ w2F, u16* __restrict__ woaT, u16* __restrict__ woaF,
    u16* __restrict__ winF, u16* __restrict__ woutC,
    float* __restrict__ bn1sc, float* __restrict__ bn1sh,
    float* __restrict__ bn2sc, float* __restrict__ bn2sh, float* __restrict__ boa)
{
    int bid = blockIdx.x;
    if (bid < 16) {                           // Wval fragments: 2 layers x 8 ks
        int l = bid >> 3, ks = bid & 7;
        frag_prep(Wval + l * 65536, wvalF + l * 65536, ks, 0, 256);
    } else if (bid < 48) {                    // Woff|Wattn transpose (layer 0): 32
        int r2 = bid - 16;
        tconv_oa(Woff, Wattn, woaT, r2 & 7, r2 >> 3);
    } else if (bid < 64) {                    // Wo fragments: 2 x 8 ks
        int i2 = bid - 48;
        frag_prep(Wo + (i2 >> 3) * 65536, woF + (i2 >> 3) * 65536, i2 & 7, 0, 256);
    } else if (bid < 128) {                   // W1 fragments: 2 x (8 ks x 4 nc)
        int i2 = bid - 64, l = i2 >> 5, r2 = i2 & 31;
        frag_prep(W1 + l * 262144, w1F + l * 262144, r2 >> 2, r2 & 3, 1024);
    } else if (bid < 192) {                   // W2 fragments: 2 x 32 ks
        int i2 = bid - 128;
        frag_prep(W2 + (i2 >> 5) * 262144, w2F + (i2 >> 5) * 262144, i2 & 31, 0, 256);
    } else if (bid < 200) {                   // Woa fragments (layer 1): 8 ks
        frag_prep_oa(Woff + 16384, Wattn + 8192, woaF, bid - 192);
    } else if (bid < 216) {                   // W_in fragments: 16 ks
        frag_prep_t(W_in, winF, bid - 200);
    } else if (bid < 248) {                   // W_out copy
        int g2 = bid - 216, base = g2 * 4096, t = threadIdx.x;
#pragma unroll
        for (int k = 0; k < 16; ++k) woutC[base + k * 256 + t] = f2b(W_out[base + k * 256 + t]);
    } else {
        int t = threadIdx.x;
        { float s = bn1g[t] * rsqrtf(bn1v[t] + EPSV); bn1sc[t] = s; bn1sh[t] = bn1b[t] - bn1m[t] * s; }
        for (int c = 0; c < 2; ++c) {
            int i = c * 256 + t;
            float s = bn2g[i] * rsqrtf(bn2v[i] + EPSV);
            bn2sc[i] = s; bn2sh[i] = bn2b[i] - bn2m[i] * s;
        }
        if (t < 128)
            for (int l = 0; l < 2; ++l)
                boa[l * 128 + t] = (t < 64) ? boff[l * 64 + t]
                                 : ((t < 96) ? battn[l * 32 + t - 64] : 0.f);
    }
}

// ================= x (B,C,HW) -> xT (B,HW,C) bf16 =================
__global__ __launch_bounds__(256) void transpose_x(const float* __restrict__ x, u16* __restrict__ xT)
{
    __shared__ float t[64][65];
    const int b = blockIdx.z, p0 = blockIdx.y << 6, c0 = blockIdx.x << 6;
    const int tx = threadIdx.x & 63, ty = threadIdx.x >> 6;
    const float* xb = x + ((size_t)b * CINC + c0) * HWTOT + p0;
#pragma unroll
    for (int i = 0; i < 16; ++i)
        t[ty + i * 4][tx] = xb[(size_t)(ty + i * 4) * HWTOT + tx];
    __syncthreads();
    u16* xo = xT + ((size_t)b * HWTOT + p0) * CINC + c0;
#pragma unroll
    for (int i = 0; i < 16; ++i)
        xo[(size_t)(ty + i * 4) * CINC + tx] = f2b(t[tx][ty + i * 4]);
}

// ================= deformable sampling: 8 queries/block, 32 lanes/query =================
struct IW { int eo; float w; };

__global__ __launch_bounds__(256) void sample_kernel(
    const u16* __restrict__ val,      // (B*HW, 512) bf16, layer cols [lofs, lofs+256)
    const float* __restrict__ oa,     // (rows, 128)
    u16* __restrict__ oms,            // (B*HW, 256) bf16
    int lofs, unsigned int mask)
{
    __shared__ float s_oa[8][96];
    __shared__ IW s_iw[8][32][5];
    const int t = threadIdx.x;
    const int bq0 = blockIdx.x << 3;
    const int b = blockIdx.x >> 9;

    {
        int qi = t >> 5, j = t & 31;
        if (j < 24)
            ((float4*)s_oa[qi])[j] = ((const float4*)oa)[((size_t)((bq0 + qi) & mask)) * 32 + j];
    }
    __syncthreads();

    {
        const int qi = t >> 5, hp = t & 31, h = hp >> 2, p = hp & 3;
        const float* so = s_oa[qi];
        float l0 = so[64 + h * 4 + 0], l1 = so[64 + h * 4 + 1];
        float l2 = so[64 + h * 4 + 2], l3 = so[64 + h * 4 + 3];
        float mx = fmaxf(fmaxf(l0, l1), fmaxf(l2, l3));
        float e0 = __expf(l0 - mx), e1 = __expf(l1 - mx), e2 = __expf(l2 - mx), e3 = __expf(l3 - mx);
        float inv = 1.0f / (e0 + e1 + e2 + e3);
        float aw = ((p == 0) ? e0 : (p == 1) ? e1 : (p == 2) ? e2 : e3) * inv;
        const int bq = bq0 + qi;
        float gx = (float)(bq & 63) + so[hp * 2 + 0];
        float gy = (float)((bq >> 6) & 63) + so[hp * 2 + 1];
        float x0f = floorf(gx), y0f = floorf(gy);
        float wx = gx - x0f, wy = gy - y0f;
        int x0 = (int)x0f, y0 = (int)y0f;
#pragma unroll
        for (int c = 0; c < 4; ++c) {
            int xi = x0 + (c & 1), yi = y0 + (c >> 1);
            bool ok = (xi >= 0) && (xi < 64) && (yi >= 0) && (yi < 64);
            float wgt = ((c & 1) ? wx : 1.0f - wx) * ((c >> 1) ? wy : 1.0f - wy);
            s_iw[qi][hp][c].eo = ok ? ((yi * 64 + xi) << 9) : 0;   // row stride 512
            s_iw[qi][hp][c].w = ok ? aw * wgt : 0.f;
        }
    }
    __syncthreads();

    {
        const int qi = t >> 5, l = t & 31, h = l >> 2, cc = l & 3;
        const u16* base = val + ((size_t)b << 21) + lofs + (h << 5) + (cc << 3);
        float a[8] = {0.f, 0.f, 0.f, 0.f, 0.f, 0.f, 0.f, 0.f};
#pragma unroll
        for (int p = 0; p < 4; ++p)
#pragma unroll
            for (int c = 0; c < 4; ++c) {
                IW iw = s_iw[qi][(h << 2) + p][c];
                uint4 v = *(const uint4*)(base + iw.eo);
                a[0] += iw.w * blo(v.x); a[1] += iw.w * bhi(v.x);
                a[2] += iw.w * blo(v.y); a[3] += iw.w * bhi(v.y);
                a[4] += iw.w * blo(v.z); a[5] += iw.w * bhi(v.z);
                a[6] += iw.w * blo(v.w); a[7] += iw.w * bhi(v.w);
            }
        uint4 o;
        o.x = (uint32_t)f2b(a[0]) | ((uint32_t)f2b(a[1]) << 16);
        o.y = (uint32_t)f2b(a[2]) | ((uint32_t)f2b(a[3]) << 16);
        o.z = (uint32_t)f2b(a[4]) | ((uint32_t)f2b(a[5]) << 16);
        o.w = (uint32_t)f2b(a[6]) | ((uint32_t)f2b(a[7]) << 16);
        *(uint4*)(oms + (size_t)(bq0 + qi) * 256 + (h << 5) + (cc << 3)) = o;
    }
}

__global__ __launch_bounds__(256) void bcast_q(
    const float4* __restrict__ qe, u16* __restrict__ q16)
{
    const int i = blockIdx.x * 256 + threadIdx.x;
    float4 v = qe[i];
    ((uint2*)q16)[i] = make_uint2(pk2(v.x, v.y), pk2(v.z, v.w));
}

extern "C" void kernel_launch(void* const* d_in, const int* in_sizes, int n_in,
                              void* d_out, int out_size, void* d_ws, size_t ws_size,
                              hipStream_t stream)
{
    (void)in_sizes; (void)n_in; (void)out_size; (void)ws_size;
    const float* x     = (const float*)d_in[0];
    const float* W_in  = (const float*)d_in[1];
    const float* bn1_g = (const float*)d_in[2];
    const float* bn1_b = (const float*)d_in[3];
    const float* bn1_m = (const float*)d_in[4];
    const float* bn1_v = (const float*)d_in[5];
    const float* qe    = (const float*)d_in[6];
    const float* Woff  = (const float*)d_in[7];
    const float* boff  = (const float*)d_in[8];
    const float* Wattn = (const float*)d_in[9];
    const float* battn = (const float*)d_in[10];
    const float* Wval  = (const float*)d_in[11];
    const float* bval  = (const float*)d_in[12];
    const float* Wo    = (const float*)d_in[13];
    const float* bo    = (const float*)d_in[14];
    const float* ln1_g = (const float*)d_in[15];
    const float* ln1_b = (const float*)d_in[16];
    const float* W1    = (const float*)d_in[17];
    const float* b1    = (const float*)d_in[18];
    const float* W2    = (const float*)d_in[19];
    const float* b2    = (const float*)d_in[20];
    const float* ln2_g = (const float*)d_in[21];
    const float* ln2_b = (const float*)d_in[22];
    const float* W_out = (const float*)d_in[23];
    const float* bn2_g = (const float*)d_in[24];
    const float* bn2_b = (const float*)d_in[25];
    const float* bn2_m = (const float*)d_in[26];
    const float* bn2_v = (const float*)d_in[27];
    float* out = (float*)d_out;

    char* w = (char*)d_ws;
    // pool (time-disjoint): xT (32MiB) aliases val16 (32MiB); offat (+32MiB) | oms (+48MiB)
    char* pool    = w;          w += 67108864;
    float* q      = (float*)w;  w += 33554432;
    u16*  q16     = (u16*)w;    w += 16777216;
    u16*  src16   = (u16*)w;    w += 16777216;
    u16*  wvalF   = (u16*)w;    w += 262144;
    u16*  woF     = (u16*)w;    w += 262144;
    u16*  w1F     = (u16*)w;    w += 1048576;
    u16*  w2F     = (u16*)w;    w += 1048576;
    u16*  woaT    = (u16*)w;    w += 65536;
    u16*  woaF    = (u16*)w;    w += 65536;
    u16*  winF    = (u16*)w;    w += 262144;
    u16*  woutC   = (u16*)w;    w += 262144;
    float* bn1sc  = (float*)w;  w += 1024;
    float* bn1sh  = (float*)w;  w += 1024;
    float* bn2sc  = (float*)w;  w += 2048;
    float* bn2sh  = (float*)w;  w += 2048;
    float* boa    = (float*)w;  w += 1024;

    u16*  xT     = (u16*)pool;                       // dead after proj_in
    u16*  val16  = (u16*)pool;                       // (B*HW, 512) both layers
    float* offat = (float*)(pool + 33554432);
    u16*  oms16  = (u16*)(pool + 50331648);

    prep_weights<<<dim3(249), 256, 0, stream>>>(
        Wval, Wo, W1, W2, Woff, Wattn, boff, battn, W_in, W_out,
        bn1_g, bn1_b, bn1_m, bn1_v, bn2_g, bn2_b, bn2_m, bn2_v,
        wvalF, woF, w1F, w2F, woaT, woaF, winF, woutC, bn1sc, bn1sh, bn2sc, bn2sh, boa);
    transpose_x<<<dim3(CINC / 64, HWTOT / 64, BBATCH), 256, 0, stream>>>(x, xT);
    bcast_q<<<dim3(1024), 256, 0, stream>>>((const float4*)qe, q16);

    // proj_in: (32768,512)@(256,512)^T -> bf16 src; A read once (full-N blocks)
    gemm_fullN<2, 16, 1><<<dim3(512), 512, 0, stream>>>(
        xT, winF, bn1sc, bn1sh, src16, 256, 0);

    // layer-0 offat: batch-periodic -> compute only M=4096 rows
    mfma_gemm<2><<<dim3(1, 32, 1), 256, 0, stream>>>(
        q16, woaT, nullptr, boa, offat, 4096, 128, 256, 128, 0, 0, 0, 1, 0);

    // both layers' val in one full-N GEMM: (32768,256)@(512,256)^T -> val16 ldc=512
    gemm_fullN<4, 8, 0><<<dim3(512), 512, 0, stream>>>(
        src16, wvalF, nullptr, bval, val16, 512, 65536);

    // layer 0: sample (periodic offat) -> fused layer (residual from qe; writes q, q16, next offat)
    sample_kernel<<<dim3(4096), 256, 0, stream>>>(val16, offat, oms16, 0, 4095u);
    fused_layer<1, 1, 1><<<dim3(512), 512, 0, stream>>>(
        oms16, woF, w1F, w2F, woaF, bo, b1, b2, boa + 128, qe, q, q16, offat,
        ln1_g, ln1_b, ln2_g, ln2_b);

    // layer 1: sample (full offat) -> fused layer (q16 only; q write dead)
    sample_kernel<<<dim3(4096), 256, 0, stream>>>(val16, offat, oms16, 256, 0xFFFFFFFFu);
    fused_layer<0, 0, 0><<<dim3(512), 512, 0, stream>>>(
        oms16, woF + 65536, w1F + 262144, w2F + 262144, nullptr,
        bo + 256, b1 + 1024, b2 + 256, nullptr, nullptr, q, q16, nullptr,
        ln1_g + 256, ln1_b + 256, ln2_g + 256, ln2_b + 256);

    // proj_out: per-batch (512,256)@(4096,256)^T -> fp32 out (B,C,HW)
    mfma_gemm<3><<<dim3(32, 4, BBATCH), 256, 0, stream>>>(
        woutC, q16, bn2sc, bn2sh, out, 512, 4096, 256, 4096,
        0, (long long)HWTOT * DM, (long long)CINC * HWTOT, 0, 0);
}